// Round 4
// baseline (2038.260 us; speedup 1.0000x reference)
//
#include <hip/hip_runtime.h>
#include <hip/hip_bf16.h>

// MAGCRN on MI355X — round 14: LLC-COHERENT SHARED BUFFERS, FENCELESS BARRIER.
//  * Round-13 counters: FETCH tripled to 759MB — the gbar acquire fence
//    invalidates the whole XCD L2 every phase, so constants re-stream and
//    prefetch-across-barrier backfires.
//  * Fix: inter-block shared buffers (sdiff/zs/zsdiff/xd/xout) accessed with
//    sc0 sc1 (device-coherent, L2-bypass) inline-asm loads/stores -> data
//    meets at the LLC; the grid barrier drops ALL cache fences (producer:
//    vmcnt(0) drain via __syncthreads + sc flag store; consumer: sc polls).
//    Constants (adjb, xin, weights) keep cached loads and stay hot in L2
//    across all barriers.
//  * Diffusion keeps the 3-slot rolling prefetch with manual counted vmcnt
//    (FIFO semantics make interleaved compiler loads safe: they only
//    over-drain). sched_barrier(0) after ALU-consumed waits (rule 18).
//  * Layer0 pre-loop tiles remapped to reuse each block's register apre.

using bf16 = __hip_bfloat16;
#define B2F(x) __bfloat162float(x)

#define NN 512
#define BBATCH 32
#define HHID 64
#define TT 12
#define EE 16

typedef __attribute__((ext_vector_type(4))) float f32x4;
typedef __attribute__((ext_vector_type(8))) short bf16x8;

__device__ inline float wsum(float x) {
#pragma unroll
  for (int off = 32; off > 0; off >>= 1) x += __shfl_xor(x, off, 64);
  return x;
}

// ---------------- LLC-coherent access helpers ------------------------------
__device__ inline uint4 llc_load4(const void* p) {
  uint4 r;
  asm volatile("global_load_dwordx4 %0, %1, off sc0 sc1" : "=v"(r) : "v"(p));
  return r;
}
__device__ inline uint2 llc_load2(const void* p) {
  uint2 r;
  asm volatile("global_load_dwordx2 %0, %1, off sc0 sc1" : "=v"(r) : "v"(p));
  return r;
}
__device__ inline unsigned llc_load1(const void* p) {
  unsigned r;
  asm volatile("global_load_dword %0, %1, off sc0 sc1" : "=v"(r) : "v"(p));
  return r;
}
__device__ inline void llc_store_bf(void* p, unsigned short v) {
  asm volatile("global_store_short %0, %1, off sc0 sc1" :: "v"(p), "v"((unsigned)v) : "memory");
}
__device__ inline void llc_store_u1(void* p, unsigned v) {
  asm volatile("global_store_dword %0, %1, off sc0 sc1" :: "v"(p), "v"(v) : "memory");
}
template <int N> __device__ inline void wait_vmcnt() {
  if constexpr (N == 0) asm volatile("s_waitcnt vmcnt(0)" ::: "memory");
  else if constexpr (N == 1) asm volatile("s_waitcnt vmcnt(1)" ::: "memory");
  else if constexpr (N == 2) asm volatile("s_waitcnt vmcnt(2)" ::: "memory");
  else asm volatile("s_waitcnt vmcnt(4)" ::: "memory");
}

// LDS-only barrier: waits DS ops, leaves global loads in flight.
__device__ inline void lds_barrier() {
  asm volatile("s_waitcnt lgkmcnt(0)" ::: "memory");
  __builtin_amdgcn_s_barrier();
  asm volatile("" ::: "memory");
}

// ---------------- grid barrier: fenceless flags + master + epoch -----------
__device__ inline void gbar(unsigned* __restrict__ bar, int& cnt) {
  cnt++;
  __syncthreads();  // drains vmcnt(0): all sc stores are at the LLC
  unsigned tgt = (unsigned)cnt;
  unsigned* flags = bar + 32;
  if (blockIdx.x == 0) {
    if (threadIdx.x < 64) {
      if (threadIdx.x == 0) llc_store_u1(flags, tgt);
      const unsigned* fp = flags + threadIdx.x * 8;
      bool ok;
      do {
        unsigned v0 = llc_load1(fp + 0), v1 = llc_load1(fp + 1),
                 v2 = llc_load1(fp + 2), v3 = llc_load1(fp + 3),
                 v4 = llc_load1(fp + 4), v5 = llc_load1(fp + 5),
                 v6 = llc_load1(fp + 6), v7 = llc_load1(fp + 7);
        wait_vmcnt<0>();
        __builtin_amdgcn_sched_barrier(0);
        ok = ((int)(v0 - tgt) >= 0) && ((int)(v1 - tgt) >= 0) &&
             ((int)(v2 - tgt) >= 0) && ((int)(v3 - tgt) >= 0) &&
             ((int)(v4 - tgt) >= 0) && ((int)(v5 - tgt) >= 0) &&
             ((int)(v6 - tgt) >= 0) && ((int)(v7 - tgt) >= 0);
      } while (!__all(ok));
      if (threadIdx.x == 0) llc_store_u1(bar, tgt);
    }
  } else if (threadIdx.x == 0) {
    llc_store_u1(flags + blockIdx.x, tgt);
    for (;;) {
      unsigned e = llc_load1(bar);
      wait_vmcnt<0>();
      __builtin_amdgcn_sched_barrier(0);
      if ((int)(e - tgt) >= 0) break;
      __builtin_amdgcn_s_sleep(2);
    }
  }
  __syncthreads();
}

__global__ __launch_bounds__(256) void zero_f32_kernel(float* __restrict__ p, int n) {
  int i = blockIdx.x * 256 + threadIdx.x;
  if (i < n) p[i] = 0.0f;
}

// ---------------- setup kernels ----------------

__global__ __launch_bounds__(256) void adj_kernel(const float* __restrict__ emb,
                                                  bf16* __restrict__ adjb) {
  __shared__ float embAll[NN * EE];
  __shared__ float red[256];
  int tid = threadIdx.x, n = blockIdx.x;
  for (int i = tid; i < NN * EE; i += 256) embAll[i] = emb[i];
  __syncthreads();
  float v[2];
#pragma unroll
  for (int j = 0; j < 2; j++) {
    int m = tid + j * 256;
    float s = 0.f;
#pragma unroll
    for (int e = 0; e < EE; e++) s += embAll[n * EE + e] * embAll[m * EE + e];
    v[j] = fmaxf(s, 0.0f);
  }
  float mx = fmaxf(v[0], v[1]);
  red[tid] = mx; __syncthreads();
  for (int s = 128; s > 0; s >>= 1) { if (tid < s) red[tid] = fmaxf(red[tid], red[tid + s]); __syncthreads(); }
  mx = red[0]; __syncthreads();
  float e0 = expf(v[0] - mx), e1 = expf(v[1] - mx);
  red[tid] = e0 + e1; __syncthreads();
  for (int s = 128; s > 0; s >>= 1) { if (tid < s) red[tid] += red[tid + s]; __syncthreads(); }
  float inv = 1.0f / red[0];
  adjb[n * NN + tid] = __float2bfloat16(e0 * inv);
  adjb[n * NN + tid + 256] = __float2bfloat16(e1 * inv);
}

__global__ __launch_bounds__(256) void wgen_kernel(const float* __restrict__ pool,
                                                   const float* __restrict__ emb,
                                                   float* __restrict__ out, int J) {
  __shared__ float embL[128 * EE];
  int tid = threadIdx.x;
  int n0 = blockIdx.y * 128;
  for (int i = tid; i < 128 * EE; i += 256) embL[i] = emb[n0 * EE + i];
  __syncthreads();
  int j = blockIdx.x * 256 + tid;
  if (j >= J) return;
  float pw[EE];
#pragma unroll
  for (int e = 0; e < EE; e++) pw[e] = pool[e * J + j];
#pragma unroll 4
  for (int nn = 0; nn < 128; nn++) {
    float s = 0.f;
#pragma unroll
    for (int e = 0; e < EE; e++) s += embL[nn * EE + e] * pw[e];
    out[(size_t)(n0 + nn) * J + j] = s;
  }
}

__global__ __launch_bounds__(256) void wgen_t_kernel(const float* __restrict__ pool,
                                                     const float* __restrict__ emb,
                                                     bf16* __restrict__ out, int J,
                                                     int lgO, int KCP) {
  __shared__ float embL[128 * EE];
  int tid = threadIdx.x;
  int n0 = blockIdx.y * 128;
  for (int i = tid; i < 128 * EE; i += 256) embL[i] = emb[n0 * EE + i];
  __syncthreads();
  int j = blockIdx.x * 256 + tid;
  if (j >= J) return;
  int O = 1 << lgO;
  int kc = j >> lgO, o = j & (O - 1);
  float pw[EE];
#pragma unroll
  for (int e = 0; e < EE; e++) pw[e] = pool[e * J + j];
  size_t SN = (size_t)KCP << lgO;
#pragma unroll 4
  for (int nn = 0; nn < 128; nn++) {
    float s = 0.f;
#pragma unroll
    for (int e = 0; e < EE; e++) s += embL[nn * EE + e] * pw[e];
    out[(size_t)(n0 + nn) * SN + (size_t)o * KCP + kc] = __float2bfloat16(s);
  }
}

__global__ __launch_bounds__(256) void pw_kernel(const float* __restrict__ upool,
                                                 const float* __restrict__ hypW,
                                                 float* __restrict__ PW) {
  __shared__ float red[256];
  int j = blockIdx.x, e = blockIdx.y, tid = threadIdx.x;
  float s = 0.f;
#pragma unroll 4
  for (int p = tid; p < 16384; p += 256) s += upool[e * 16384 + p] * hypW[p * 48 + j];
  red[tid] = s; __syncthreads();
  for (int t = 128; t > 0; t >>= 1) { if (tid < t) red[tid] += red[tid + t]; __syncthreads(); }
  if (tid == 0) PW[e * 48 + j] = red[0];
}

__global__ __launch_bounds__(256) void fs_kernel(const float* __restrict__ emb,
                                                 const float* __restrict__ PW,
                                                 const float* __restrict__ hypb,
                                                 float* __restrict__ fs) {
  int id = blockIdx.x * 256 + threadIdx.x;
  if (id >= NN * TT) return;
  int n = id / TT, t = id % TT;
  float s = 0.f;
#pragma unroll
  for (int f = 0; f < 4; f++) {
    int j = t * 4 + f;
    float h = hypb[j];
#pragma unroll
    for (int e = 0; e < EE; e++) h += emb[n * EE + e] * PW[e * 48 + j];
    s += h;
  }
  fs[id] = s;
}

__global__ __launch_bounds__(256) void cvt_src_kernel(const float* __restrict__ src,
                                                      bf16* __restrict__ x) {
  int id = blockIdx.x * 256 + threadIdx.x;  // < 393216
  int c = id & 1, b = (id >> 1) & 31, n = (id >> 6) & 511, t = id >> 15;
  x[id] = __float2bfloat16(src[((b * TT + t) * NN + n) * 2 + c]);
}

// ---------------- diffusion: pipelined, LLC-coherent, counted waits --------
#define DBUF 4672

__device__ inline void xsT_wr8(unsigned short* xsT, int base, int q0l, int k, uint4 v) {
  union { uint4 u; unsigned short h[8]; } cv; cv.u = v;
#pragma unroll
  for (int qq = 0; qq < 8; qq++) {
    int q = q0l + qq;
    xsT[base + q * 72 + (q >> 3) * 8 + k] = cv.h[qq];
  }
}

template <int QW>
__device__ inline void diffuse_tileP(const bf16x8* __restrict__ apre,
                                     const bf16* __restrict__ X, bf16* __restrict__ Y,
                                     int Q, int n0, int q0, char* smraw, int tid) {
  constexpr int LPC = QW / 32;
  constexpr int NCT = QW / 16;
  unsigned short* xsT = (unsigned short*)smraw;
  int w = tid >> 6, lane = tid & 63;
  int col = lane & 15, quad = lane >> 4;
  int kr, ql;
  if constexpr (QW == 64) { kr = tid >> 3; ql = (tid & 7) * 8; }
  else                    { kr = tid >> 2; ql = (tid & 3) * 8; }
  f32x4 acc[NCT];
#pragma unroll
  for (int ct = 0; ct < NCT; ct++) acc[ct] = (f32x4){0.f, 0.f, 0.f, 0.f};
  const bf16* Xb = X + q0 + ql;
  uint4 pre[3][LPC];
#pragma unroll
  for (int d = 0; d < 3; d++) {
    pre[d][0] = llc_load4(Xb + (size_t)(d * 64 + kr) * Q);
    if constexpr (QW == 64)
      pre[d][1] = llc_load4(Xb + (size_t)(d * 64 + 32 + kr) * Q);
  }
  wait_vmcnt<2 * LPC>();
  xsT_wr8(xsT, 0, ql, kr, pre[0][0]);
  if constexpr (QW == 64) xsT_wr8(xsT, 0, ql, 32 + kr, pre[0][1]);
  pre[0][0] = llc_load4(Xb + (size_t)(3 * 64 + kr) * Q);
  if constexpr (QW == 64)
    pre[0][1] = llc_load4(Xb + (size_t)(3 * 64 + 32 + kr) * Q);
  lds_barrier();
#pragma unroll
  for (int c = 0; c < 8; c++) {
    int sl = (c + 1) % 3;
    if (c < 7) {
      if (c < 5) wait_vmcnt<2 * LPC>();
      else if (c == 5) wait_vmcnt<LPC>();
      else wait_vmcnt<0>();
      int nb = ((c + 1) & 1) * DBUF;
      xsT_wr8(xsT, nb, ql, kr, pre[sl][0]);
      if constexpr (QW == 64) xsT_wr8(xsT, nb, ql, 32 + kr, pre[sl][1]);
    }
    int base = (c & 1) * DBUF;
#pragma unroll
    for (int ki = 0; ki < 2; ki++) {
      bf16x8 a = apre[c * 2 + ki];
#pragma unroll
      for (int ct = 0; ct < NCT; ct++) {
        int q = ct * 16 + col;
        bf16x8 b = *(const bf16x8*)&xsT[base + q * 72 + (q >> 3) * 8 + ki * 32 + quad * 8];
        acc[ct] = __builtin_amdgcn_mfma_f32_16x16x32_bf16(a, b, acc[ct], 0, 0, 0);
      }
    }
    if (c + 4 < 8) {
      pre[sl][0] = llc_load4(Xb + (size_t)((c + 4) * 64 + kr) * Q);
      if constexpr (QW == 64)
        pre[sl][1] = llc_load4(Xb + (size_t)((c + 4) * 64 + 32 + kr) * Q);
    }
    lds_barrier();
  }
#pragma unroll
  for (int ct = 0; ct < NCT; ct++)
#pragma unroll
    for (int r = 0; r < 4; r++) {
      int row = n0 + w * 16 + quad * 4 + r;
      bf16 hb = __float2bfloat16(acc[ct][r]);
      llc_store_bf(Y + (size_t)row * Q + q0 + ct * 16 + col, *(unsigned short*)&hb);
    }
}

// ---------------- fallback-path shared functions ---------------------------

template <int C>
__device__ inline void stage_A(int n, int tid, unsigned short* xinb,
    const bf16* __restrict__ xt, const bf16* __restrict__ xd,
    const bf16* __restrict__ sa, const bf16* __restrict__ sad) {
  constexpr int cc = C + HHID, KC = 2 * cc, KCP = (KC + 31) & ~31, PIT = KCP + 8;
  __syncthreads();
  for (int i = tid; i < 32 * KCP; i += 256) {
    int b = i / KCP, kc = i - b * KCP;
    unsigned short v = 0;
    if (kc < C)            v = *(const unsigned short*)&xt[(n * 32 + b) * C + kc];
    else if (kc < cc)      v = *(const unsigned short*)&sa[(n * 32 + b) * HHID + kc - C];
    else if (kc < cc + C)  v = *(const unsigned short*)&xd[(n * 32 + b) * C + kc - cc];
    else if (kc < KC)      v = *(const unsigned short*)&sad[(n * 32 + b) * HHID + kc - cc - C];
    xinb[b * PIT + kc] = v;
  }
  __syncthreads();
}

template <int C>
__device__ inline void gate_epilogue(int n, int w, int col, int quad,
    f32x4 acc[2][2], const float* __restrict__ gb, const float* __restrict__ state,
    bf16* __restrict__ zs, bf16* __restrict__ rbuf) {
#pragma unroll
  for (int i = 0; i < 2; i++) {
    int o = (w + i * 4) * 16 + col;
    float bv = gb[n * 128 + o];
#pragma unroll
    for (int mt = 0; mt < 2; mt++)
#pragma unroll
      for (int r = 0; r < 4; r++) {
        int m = mt * 16 + quad * 4 + r;
        float zr = 1.0f / (1.0f + expf(-(acc[i][mt][r] + bv)));
        int idx = (n * 32 + m) * HHID + (o & 63);
        if (o < HHID) zs[idx] = __float2bfloat16(zr * state[idx]);
        else          rbuf[idx] = __float2bfloat16(zr);
      }
  }
}

template <int C>
__device__ inline void upd_epilogue(int n, int w, int col, int quad,
    f32x4 acc[2], const float* __restrict__ ub, float* __restrict__ state,
    bf16* __restrict__ sb, const bf16* __restrict__ rbuf, bf16* __restrict__ xo) {
  int o = w * 16 + col;
  float bv = ub[n * 64 + o];
#pragma unroll
  for (int mt = 0; mt < 2; mt++)
#pragma unroll
    for (int r = 0; r < 4; r++) {
      int m = mt * 16 + quad * 4 + r;
      int idx = (n * 32 + m) * HHID + o;
      float hc = tanhf(acc[mt][r] + bv);
      float rr = B2F(rbuf[idx]);
      float st = state[idx];
      float h = rr * st + (1.0f - rr) * hc;
      state[idx] = h;
      bf16 hb = __float2bfloat16(h);
      sb[idx] = hb;
      xo[idx] = hb;
    }
}

template <int C>
__device__ inline void gate_mfma(int n, int tid, const unsigned short* xinb,
    const bf16* __restrict__ gWt, const float* __restrict__ gb,
    const float* __restrict__ state, bf16* __restrict__ zs, bf16* __restrict__ rbuf) {
  constexpr int KC = 2 * (C + HHID), KCP = (KC + 31) & ~31, PIT = KCP + 8;
  int w = tid >> 6, lane = tid & 63, col = lane & 15, quad = lane >> 4;
  f32x4 acc[2][2];
#pragma unroll
  for (int i = 0; i < 2; i++)
#pragma unroll
    for (int mt = 0; mt < 2; mt++) acc[i][mt] = (f32x4){0.f, 0.f, 0.f, 0.f};
  const bf16* Wn = gWt + (size_t)n * KCP * 128;
#pragma unroll 2
  for (int k0 = 0; k0 < KCP; k0 += 32) {
    int ko = k0 + quad * 8;
    bf16x8 a0 = *(const bf16x8*)&xinb[col * PIT + ko];
    bf16x8 a1 = *(const bf16x8*)&xinb[(16 + col) * PIT + ko];
#pragma unroll
    for (int i = 0; i < 2; i++) {
      int o = (w + i * 4) * 16 + col;
      bf16x8 bf = *(const bf16x8*)(Wn + (size_t)o * KCP + ko);
      acc[i][0] = __builtin_amdgcn_mfma_f32_16x16x32_bf16(a0, bf, acc[i][0], 0, 0, 0);
      acc[i][1] = __builtin_amdgcn_mfma_f32_16x16x32_bf16(a1, bf, acc[i][1], 0, 0, 0);
    }
  }
  gate_epilogue<C>(n, w, col, quad, acc, gb, state, zs, rbuf);
}

template <int C>
__device__ inline void upd_mfma(int n, int tid, const unsigned short* xinb,
    const bf16* __restrict__ uWt, const float* __restrict__ ub,
    float* __restrict__ state, bf16* __restrict__ sb,
    const bf16* __restrict__ rbuf, bf16* __restrict__ xo) {
  constexpr int KC = 2 * (C + HHID), KCP = (KC + 31) & ~31, PIT = KCP + 8;
  int w = tid >> 6, lane = tid & 63, col = lane & 15, quad = lane >> 4;
  f32x4 acc[2];
  acc[0] = (f32x4){0.f, 0.f, 0.f, 0.f};
  acc[1] = (f32x4){0.f, 0.f, 0.f, 0.f};
  const bf16* Wn = uWt + (size_t)n * KCP * 64;
  int o = w * 16 + col;
#pragma unroll 2
  for (int k0 = 0; k0 < KCP; k0 += 32) {
    int ko = k0 + quad * 8;
    bf16x8 a0 = *(const bf16x8*)&xinb[col * PIT + ko];
    bf16x8 a1 = *(const bf16x8*)&xinb[(16 + col) * PIT + ko];
    bf16x8 bf = *(const bf16x8*)(Wn + (size_t)o * KCP + ko);
    acc[0] = __builtin_amdgcn_mfma_f32_16x16x32_bf16(a0, bf, acc[0], 0, 0, 0);
    acc[1] = __builtin_amdgcn_mfma_f32_16x16x32_bf16(a1, bf, acc[1], 0, 0, 0);
  }
  upd_epilogue<C>(n, w, col, quad, acc, ub, state, sb, rbuf, xo);
}

// ---------------- cooperative recurrence -----------------------------------

template <int C>
__global__ __launch_bounds__(256, 2) void recur_kernel(
    const bf16* __restrict__ adjb, const bf16* __restrict__ xin,
    const bf16* __restrict__ gWt, const float* __restrict__ gb,
    const bf16* __restrict__ uWt, const float* __restrict__ ub,
    bf16* __restrict__ zs, bf16* __restrict__ sdiff, bf16* __restrict__ zsdiff,
    bf16* __restrict__ xd, bf16* __restrict__ xout, unsigned* __restrict__ bar) {
  constexpr int KC = 2 * (C + HHID), KCP = (KC + 31) & ~31, PIT = KCP + 8;
  constexpr int NK = KCP / 32;
  constexpr int QX = 32 * C;
  __shared__ __align__(16) char dsm[2 * DBUF * 2];
  __shared__ __align__(16) unsigned short xinb[32 * PIT];
  int bid = blockIdx.x, tid = threadIdx.x;   // grid is exactly 512 blocks
  int w = tid >> 6, lane = tid & 63, col = lane & 15, quad = lane >> 4;
  int bcnt = 0;

  bf16x8 apre[16];
  {
    int n0p = ((bid & 255) >> 5) * 64;
    const bf16* ar = adjb + (size_t)(n0p + w * 16 + col) * NN;
#pragma unroll
    for (int c = 0; c < 8; c++)
#pragma unroll
      for (int ki = 0; ki < 2; ki++)
        apre[c * 2 + ki] = *(const bf16x8*)(ar + c * 64 + ki * 32 + quad * 8);
  }
  bf16x8 fg[2 * NK];
  {
    const bf16* Wn = gWt + (size_t)bid * KCP * 128;
#pragma unroll
    for (int i = 0; i < 2; i++) {
      int o = (w + i * 4) * 16 + col;
#pragma unroll
      for (int kk = 0; kk < NK; kk++)
        fg[i * NK + kk] = *(const bf16x8*)(Wn + (size_t)o * KCP + kk * 32 + quad * 8);
    }
  }
  bf16x8 fu[NK];
  {
    const bf16* Wn = uWt + (size_t)bid * KCP * 64;
    int o = w * 16 + col;
#pragma unroll
    for (int kk = 0; kk < NK; kk++)
      fu[kk] = *(const bf16x8*)(Wn + (size_t)o * KCP + kk * 32 + quad * 8);
  }
  float gbv0 = gb[bid * 128 + w * 16 + col];
  float gbv1 = gb[bid * 128 + 64 + w * 16 + col];
  float ubv  = ub[bid * 64 + w * 16 + col];

  for (int i = tid; i < 32 * PIT; i += 256) xinb[i] = 0;
  __syncthreads();

  int r2 = tid >> 3, ch = tid & 7;
  uint4 vxt; unsigned sxt = 0, sxd = 0;
  if constexpr (C == 64) {
    vxt = *(const uint4*)(xin + (size_t)(bid * 32 + r2) * 64 + ch * 8);
  } else {
    if (tid < 32) sxt = *(const unsigned*)(xin + (size_t)(bid * 32 + tid) * 2);
  }

  float st[2][4], rr_[2][4];
#pragma unroll
  for (int mt = 0; mt < 2; mt++)
#pragma unroll
    for (int r4 = 0; r4 < 4; r4++) st[mt][r4] = 0.f;

  // pre-loop diffusion (uses this block's apre rows)
  if constexpr (C == 2) {
    int wg = (bid & 31) | ((bid >> 8) << 5);
    if (wg < TT)
      diffuse_tileP<64>(apre, xin + (size_t)wg * NN * QX, xd + (size_t)wg * NN * QX,
                        QX, ((bid & 255) >> 5) * 64, 0, dsm, tid);
  } else {
    if (bid >= 256)
      diffuse_tileP<64>(apre, xin, xd, 2048, ((bid & 255) >> 5) * 64,
                        (bid & 31) * 64, dsm, tid);
  }
  gbar(bar, bcnt);

  for (int t = 0; t < TT; t++) {
    const bf16* xt = xin + (size_t)t * NN * QX;
    const bf16* xdt = (C == 2) ? (xd + (size_t)t * NN * QX) : xd;
    bf16* xo = xout + (size_t)t * NN * 32 * HHID;
    if (t > 0) {
      const bf16* sbp = xout + (size_t)(t - 1) * NN * 32 * HHID;
      if constexpr (C == 64) {
        if (bid < 256)
          diffuse_tileP<64>(apre, sbp, sdiff, 2048, (bid >> 5) * 64,
                            (bid & 31) * 64, dsm, tid);
        else
          diffuse_tileP<64>(apre, xt, xd, 2048, ((bid & 255) >> 5) * 64,
                            (bid & 31) * 64, dsm, tid);
      } else {
        int cs = (bid & 31) | ((bid >> 8) << 5);
        diffuse_tileP<32>(apre, sbp, sdiff, 2048, ((bid & 255) >> 5) * 64,
                          cs * 32, dsm, tid);
      }
      gbar(bar, bcnt);
    }
    // ---- P2 stage ----
    if constexpr (C == 64) {
      *(uint4*)&xinb[r2 * PIT + ch * 8] = vxt;
      uint4 v1 = llc_load4(xdt + (size_t)(bid * 32 + r2) * 64 + ch * 8);
      uint4 v2;
      if (t > 0) v2 = llc_load4(sdiff + (size_t)(bid * 32 + r2) * 64 + ch * 8);
      wait_vmcnt<0>();
      *(uint4*)&xinb[r2 * PIT + 128 + ch * 8] = v1;
      if (t > 0) *(uint4*)&xinb[r2 * PIT + 192 + ch * 8] = v2;
    } else {
      if (tid < 32) *(unsigned*)&xinb[tid * PIT] = sxt;
      if (t == 0) {
        if (tid < 32) {
          unsigned v = llc_load1(xdt + (size_t)(bid * 32 + tid) * 2);
          wait_vmcnt<0>();
          *(unsigned*)&xinb[tid * PIT + 66] = v;
        }
      } else {
        if (tid >= 32 && tid < 64) *(unsigned*)&xinb[(tid - 32) * PIT + 66] = sxd;
        int r2a = tid >> 4, c4 = tid & 15;
        uint2 va = llc_load2(sdiff + (size_t)(bid * 32 + r2a) * 64 + c4 * 4);
        uint2 vb = llc_load2(sdiff + (size_t)(bid * 32 + 16 + r2a) * 64 + c4 * 4);
        wait_vmcnt<0>();
        *(uint2*)&xinb[r2a * PIT + 68 + c4 * 4] = va;
        *(uint2*)&xinb[(16 + r2a) * PIT + 68 + c4 * 4] = vb;
      }
    }
    __syncthreads();
    // ---- P2 gate MFMA ----
    {
      f32x4 acc[2][2];
#pragma unroll
      for (int i = 0; i < 2; i++)
#pragma unroll
        for (int mt = 0; mt < 2; mt++) acc[i][mt] = (f32x4){0.f, 0.f, 0.f, 0.f};
#pragma unroll
      for (int kk = 0; kk < NK; kk++) {
        int ko = kk * 32 + quad * 8;
        bf16x8 a0 = *(const bf16x8*)&xinb[col * PIT + ko];
        bf16x8 a1 = *(const bf16x8*)&xinb[(16 + col) * PIT + ko];
#pragma unroll
        for (int i = 0; i < 2; i++) {
          acc[i][0] = __builtin_amdgcn_mfma_f32_16x16x32_bf16(a0, fg[i * NK + kk], acc[i][0], 0, 0, 0);
          acc[i][1] = __builtin_amdgcn_mfma_f32_16x16x32_bf16(a1, fg[i * NK + kk], acc[i][1], 0, 0, 0);
        }
      }
      __syncthreads();
#pragma unroll
      for (int mt = 0; mt < 2; mt++)
#pragma unroll
        for (int r4 = 0; r4 < 4; r4++) {
          int m = mt * 16 + quad * 4 + r4;
          float z = 1.0f / (1.0f + expf(-(acc[0][mt][r4] + gbv0)));
          float rv = 1.0f / (1.0f + expf(-(acc[1][mt][r4] + gbv1)));
          rr_[mt][r4] = rv;
          bf16 zb = __float2bfloat16(z * st[mt][r4]);
          xinb[m * PIT + C + w * 16 + col] = *(unsigned short*)&zb;
          llc_store_bf(zs + (size_t)(bid * 32 + m) * 64 + w * 16 + col,
                       *(unsigned short*)&zb);
        }
    }
    if (t > 0) {
      gbar(bar, bcnt);
      {
        int cs = (bid & 31) | ((bid >> 8) << 5);
        diffuse_tileP<32>(apre, zs, zsdiff, 2048, ((bid & 255) >> 5) * 64,
                          cs * 32, dsm, tid);
      }
      gbar(bar, bcnt);
      if constexpr (C == 64) {
        uint4 v = llc_load4(zsdiff + (size_t)(bid * 32 + r2) * 64 + ch * 8);
        wait_vmcnt<0>();
        *(uint4*)&xinb[r2 * PIT + 192 + ch * 8] = v;
      } else {
        int r2a = tid >> 4, c4 = tid & 15;
        uint2 va = llc_load2(zsdiff + (size_t)(bid * 32 + r2a) * 64 + c4 * 4);
        uint2 vb = llc_load2(zsdiff + (size_t)(bid * 32 + 16 + r2a) * 64 + c4 * 4);
        wait_vmcnt<0>();
        *(uint2*)&xinb[r2a * PIT + 68 + c4 * 4] = va;
        *(uint2*)&xinb[(16 + r2a) * PIT + 68 + c4 * 4] = vb;
      }
    }
    __syncthreads();
    // ---- P4 update MFMA ----
    {
      f32x4 acc[2];
      acc[0] = (f32x4){0.f, 0.f, 0.f, 0.f};
      acc[1] = (f32x4){0.f, 0.f, 0.f, 0.f};
#pragma unroll
      for (int kk = 0; kk < NK; kk++) {
        int ko = kk * 32 + quad * 8;
        bf16x8 a0 = *(const bf16x8*)&xinb[col * PIT + ko];
        bf16x8 a1 = *(const bf16x8*)&xinb[(16 + col) * PIT + ko];
        acc[0] = __builtin_amdgcn_mfma_f32_16x16x32_bf16(a0, fu[kk], acc[0], 0, 0, 0);
        acc[1] = __builtin_amdgcn_mfma_f32_16x16x32_bf16(a1, fu[kk], acc[1], 0, 0, 0);
      }
      __syncthreads();
      if (t + 1 < TT) {
        if constexpr (C == 64) {
          vxt = *(const uint4*)(xin + (size_t)(t + 1) * NN * QX +
                                (size_t)(bid * 32 + r2) * 64 + ch * 8);
        } else {
          if (tid < 32)
            sxt = *(const unsigned*)(xin + (size_t)(t + 1) * NN * QX +
                                     (size_t)(bid * 32 + tid) * 2);
          else if (tid < 64)
            sxd = *(const unsigned*)(xd + (size_t)(t + 1) * NN * QX +
                                     (size_t)(bid * 32 + (tid - 32)) * 2);
        }
      }
#pragma unroll
      for (int mt = 0; mt < 2; mt++)
#pragma unroll
        for (int r4 = 0; r4 < 4; r4++) {
          int m = mt * 16 + quad * 4 + r4;
          float hc = tanhf(acc[mt][r4] + ubv);
          float rv = rr_[mt][r4];
          float h = rv * st[mt][r4] + (1.0f - rv) * hc;
          st[mt][r4] = h;
          bf16 hb = __float2bfloat16(h);
          xinb[m * PIT + C + w * 16 + col] = *(unsigned short*)&hb;
          llc_store_bf(xo + (size_t)(bid * 32 + m) * 64 + w * 16 + col,
                       *(unsigned short*)&hb);
        }
    }
    gbar(bar, bcnt);
  }
}

// ---------------- fallback per-phase kernels (same math) ----------------

__global__ __launch_bounds__(256, 2) void diffuse0_kernel(const bf16* __restrict__ adjb,
                                                          const bf16* __restrict__ X,
                                                          bf16* __restrict__ Y) {
  __shared__ __align__(16) char smraw[2 * DBUF * 2];
  int bid = blockIdx.x, tid = threadIdx.x;  // 96
  int t = bid >> 3, n0 = (bid & 7) * 64;
  int w = tid >> 6, lane = tid & 63, col = lane & 15, quad = lane >> 4;
  bf16x8 ap[16];
  const bf16* ar = adjb + (size_t)(n0 + w * 16 + col) * NN;
#pragma unroll
  for (int c = 0; c < 8; c++)
#pragma unroll
    for (int ki = 0; ki < 2; ki++)
      ap[c * 2 + ki] = *(const bf16x8*)(ar + c * 64 + ki * 32 + quad * 8);
  diffuse_tileP<64>(ap, X + (size_t)t * NN * 64, Y + (size_t)t * NN * 64,
                    64, n0, 0, smraw, tid);
}

__global__ __launch_bounds__(256, 2) void diffuse1_kernel(const bf16* __restrict__ adjb,
                                                          const bf16* __restrict__ X,
                                                          bf16* __restrict__ Y) {
  __shared__ __align__(16) char smraw[2 * DBUF * 2];
  int bid = blockIdx.x, tid = threadIdx.x;  // 256
  int n0 = (bid >> 5) * 64;
  int w = tid >> 6, lane = tid & 63, col = lane & 15, quad = lane >> 4;
  bf16x8 ap[16];
  const bf16* ar = adjb + (size_t)(n0 + w * 16 + col) * NN;
#pragma unroll
  for (int c = 0; c < 8; c++)
#pragma unroll
    for (int ki = 0; ki < 2; ki++)
      ap[c * 2 + ki] = *(const bf16x8*)(ar + c * 64 + ki * 32 + quad * 8);
  diffuse_tileP<64>(ap, X, Y, 2048, n0, (bid & 31) * 64, smraw, tid);
}

template <int C>
__global__ __launch_bounds__(256, 2) void gate_wrap(
    const bf16* xt, const bf16* xdt, const bf16* sa, const bf16* sad,
    const bf16* gWt, const float* gb, const float* state, bf16* zs, bf16* rbuf) {
  constexpr int KC = 2 * (C + HHID), KCP = (KC + 31) & ~31, PIT = KCP + 8;
  __shared__ __align__(16) unsigned short xinb[32 * PIT];
  stage_A<C>(blockIdx.x, threadIdx.x, xinb, xt, xdt, sa, sad);
  gate_mfma<C>(blockIdx.x, threadIdx.x, xinb, gWt, gb, state, zs, rbuf);
}

template <int C>
__global__ __launch_bounds__(256, 2) void upd_wrap(
    const bf16* xt, const bf16* xdt, const bf16* sa, const bf16* sad,
    const bf16* uWt, const float* ub, float* state, bf16* sb,
    const bf16* rbuf, bf16* xo) {
  constexpr int KC = 2 * (C + HHID), KCP = (KC + 31) & ~31, PIT = KCP + 8;
  __shared__ __align__(16) unsigned short xinb[32 * PIT];
  stage_A<C>(blockIdx.x, threadIdx.x, xinb, xt, xdt, sa, sad);
  upd_mfma<C>(blockIdx.x, threadIdx.x, xinb, uWt, ub, state, sb, rbuf, xo);
}

// ---------------- epilogue kernels (unchanged, passing) ----------------

#define TP 68

__global__ __launch_bounds__(256, 4) void attn1_kernel(
    const bf16* __restrict__ x1, const float* __restrict__ fsb,
    const float* __restrict__ Wq, const float* __restrict__ bq,
    const float* __restrict__ Wk, const float* __restrict__ bk,
    const float* __restrict__ Wv, const float* __restrict__ bv,
    const float* __restrict__ ln1g, const float* __restrict__ ln1b,
    bf16* __restrict__ val) {
  __shared__ bf16 Wq_s[4096], Wk_s[4096], Wv_s[4096];
  __shared__ float X[TT * TP], qs[TT * TP], ks[TT * TP];
  __shared__ float A[2 * TT * TT];
  __shared__ float ovv[64], fss[TT];
  __shared__ float bqs[64], bks[64], bvs[64], g1s[64], b1s[64];
  int tid = threadIdx.x;
  for (int i = tid; i < 4096; i += 256) {
    Wq_s[i] = __float2bfloat16(Wq[i]);
    Wk_s[i] = __float2bfloat16(Wk[i]);
    Wv_s[i] = __float2bfloat16(Wv[i]);
  }
  if (tid < 64) {
    bqs[tid] = bq[tid]; bks[tid] = bk[tid]; bvs[tid] = bv[tid];
    g1s[tid] = ln1g[tid]; b1s[tid] = ln1b[tid];
  }
  __syncthreads();
  for (int g = 0; g < 8; g++) {
    int p = blockIdx.x * 8 + g;
    int b = p >> 9, n = p & 511;
    for (int i = tid; i < TT * 64; i += 256) {
      int t = i >> 6, j = i & 63;
      X[t * TP + j] = B2F(x1[(((size_t)t * NN + n) * BBATCH + b) * HHID + j]);
    }
    if (tid < TT) fss[tid] = fsb[n * TT + tid];
    __syncthreads();
    for (int i = tid; i < TT * 64; i += 256) {
      int t = i >> 6, h = i & 63;
      float aq = bqs[h], ak = bks[h];
#pragma unroll 8
      for (int j = 0; j < 64; j++) {
        float xv = X[t * TP + j];
        aq += xv * B2F(Wq_s[j * 64 + h]);
        ak += xv * B2F(Wk_s[j * 64 + h]);
      }
      qs[t * TP + h] = aq; ks[t * TP + h] = ak;
    }
    if (tid < 64) {
      float s = 0.f;
#pragma unroll 8
      for (int j = 0; j < 64; j++) s += X[11 * TP + j] * B2F(Wv_s[j * 64 + tid]);
      ovv[tid] = s;
    }
    __syncthreads();
    for (int i = tid; i < 2 * TT * TT; i += 256) {
      int hd = i / (TT * TT), ts = i % (TT * TT), t = ts / TT, s = ts % TT;
      float acc = 0.f;
#pragma unroll
      for (int d = 0; d < 32; d++) acc += qs[t * TP + hd * 32 + d] * ks[s * TP + hd * 32 + d];
      A[i] = acc * 0.17677669529663687f;
    }
    __syncthreads();
    if (tid < 2 * TT) {
      int hd = tid / TT, t = tid % TT;
      float* row = &A[hd * TT * TT + t * TT];
      float m = row[0];
      for (int s = 1; s < TT; s++) m = fmaxf(m, row[s]);
      float sm = 0.f;
      for (int s = 0; s < TT; s++) { float e = expf(row[s] - m); row[s] = e; sm += e; }
      float inv = 1.0f / sm;
      for (int s = 0; s < TT; s++) row[s] *= inv;
    }
    __syncthreads();
#pragma unroll
    for (int it = 0; it < 3; it++) {
      int i = it * 256 + tid;
      int t = i >> 6, h = i & 63, hd = h >> 5;
      float afs = 0.f;
#pragma unroll
      for (int s = 0; s < TT; s++) afs += A[hd * TT * TT + t * TT + s] * fss[s];
      float o = ovv[h] * afs + bvs[h];
      float x = o + X[t * TP + h];
      float mu = wsum(x) * (1.0f / 64.0f);
      float d = x - mu;
      float var = wsum(d * d) * (1.0f / 64.0f);
      float v = d * rsqrtf(var + 1e-5f) * g1s[h] + b1s[h];
      val[((size_t)(b * TT + t) * NN + n) * HHID + h] = __float2bfloat16(v);
    }
    __syncthreads();
  }
}

__global__ __launch_bounds__(256, 4) void ffn_kernel(
    const bf16* __restrict__ val, const float* __restrict__ W1, const float* __restrict__ b1,
    const float* __restrict__ W2, const float* __restrict__ b2,
    const float* __restrict__ ln2g, const float* __restrict__ ln2b,
    const float* __restrict__ fcW, const float* __restrict__ fcb,
    float* __restrict__ out, int rows_per_block) {
  __shared__ bf16 W1s[4096], W2s[4096];
  __shared__ float b1s[64], b2s[64], g2s[64], bb2[64], fcs[64];
  __shared__ float vrow[256], grow[256];
  int tid = threadIdx.x;
  for (int i = tid; i < 4096; i += 256) {
    W1s[i] = __float2bfloat16(W1[i]);
    W2s[i] = __float2bfloat16(W2[i]);
  }
  if (tid < 64) {
    b1s[tid] = b1[tid]; b2s[tid] = b2[tid];
    g2s[tid] = ln2g[tid]; bb2[tid] = ln2b[tid]; fcs[tid] = fcW[tid];
  }
  __syncthreads();
  float fcbv = fcb[0];
  int rl = tid >> 6, h = tid & 63;
  for (int c = 0; c < rows_per_block; c += 4) {
    int r = blockIdx.x * rows_per_block + c + rl;
    float x = B2F(val[(size_t)r * 64 + h]);
    vrow[rl * 64 + h] = x;
    float gacc = b1s[h];
#pragma unroll 8
    for (int j = 0; j < 64; j++) gacc += vrow[rl * 64 + j] * B2F(W1s[j * 64 + h]);
    gacc = fmaxf(gacc, 0.0f);
    grow[rl * 64 + h] = gacc;
    float f = b2s[h];
#pragma unroll 8
    for (int j = 0; j < 64; j++) f += grow[rl * 64 + j] * B2F(W2s[j * 64 + h]);
    float y = f + x;
    float mu = wsum(y) * (1.0f / 64.0f);
    float d = y - mu;
    float var = wsum(d * d) * (1.0f / 64.0f);
    float oh = d * rsqrtf(var + 1e-5f) * g2s[h] + bb2[h];
    float contrib = wsum(oh * fcs[h]);
    if (h == 0) out[r] = contrib + fcbv;
  }
}

extern "C" void kernel_launch(void* const* d_in, const int* in_sizes, int n_in,
                              void* d_out, int out_size, void* d_ws, size_t ws_size,
                              hipStream_t stream) {
  const float* src = (const float*)d_in[0];
  const float* emb = (const float*)d_in[2];
  const float* gwp[2] = {(const float*)d_in[3], (const float*)d_in[7]};
  const float* gbp[2] = {(const float*)d_in[4], (const float*)d_in[8]};
  const float* uwp[2] = {(const float*)d_in[5], (const float*)d_in[9]};
  const float* ubp[2] = {(const float*)d_in[6], (const float*)d_in[10]};
  const float* hypW = (const float*)d_in[11];
  const float* hypb = (const float*)d_in[12];
  const float *Wq, *Wk, *Wv, *ffW1, *ffW2, *bq, *bk, *bv, *ffb1, *ffb2;
  const float *ln1g, *ln1b, *ln2g, *ln2b, *fcW, *fcb;
  if (in_sizes[14] == 4096) {
    Wq = (const float*)d_in[13]; Wk = (const float*)d_in[14]; Wv = (const float*)d_in[15];
    ffW1 = (const float*)d_in[16]; ffW2 = (const float*)d_in[17];
    bq = (const float*)d_in[18]; bk = (const float*)d_in[19]; bv = (const float*)d_in[20];
    ffb1 = (const float*)d_in[21]; ffb2 = (const float*)d_in[22];
    ln1g = (const float*)d_in[23]; ln1b = (const float*)d_in[24];
    ln2g = (const float*)d_in[25]; ln2b = (const float*)d_in[26];
    fcW = (const float*)d_in[27]; fcb = (const float*)d_in[28];
  } else {
    Wq = (const float*)d_in[13]; bq = (const float*)d_in[14];
    Wk = (const float*)d_in[15]; bk = (const float*)d_in[16];
    Wv = (const float*)d_in[17]; bv = (const float*)d_in[18];
    ln1g = (const float*)d_in[19]; ln1b = (const float*)d_in[20];
    ffW1 = (const float*)d_in[21]; ffb1 = (const float*)d_in[22];
    ffW2 = (const float*)d_in[23]; ffb2 = (const float*)d_in[24];
    ln2g = (const float*)d_in[25]; ln2b = (const float*)d_in[26];
    fcW = (const float*)d_in[27]; fcb = (const float*)d_in[28];
  }
  float* outp = (float*)d_out;

  char* ws = (char*)d_ws;
  size_t off = 0;
  auto alloc = [&](size_t bytes) {
    void* p = ws + off;
    off += (bytes + 255) & ~(size_t)255;
    return p;
  };
  bf16* adjb = (bf16*)alloc((size_t)512 * 512 * 2);
  bf16* gWb = (bf16*)alloc((size_t)512 * 32768 * 2);
  bf16* uWb = (bf16*)alloc((size_t)512 * 16384 * 2);
  float* gb = (float*)alloc((size_t)512 * 128 * 4);
  float* ub = (float*)alloc((size_t)512 * 64 * 4);
  bf16* xin0 = (bf16*)alloc((size_t)12 * 512 * 32 * 2 * 2);
  bf16* x0 = (bf16*)alloc((size_t)12 * 512 * 32 * 64 * 2);
  bf16* xd0 = (bf16*)alloc((size_t)12 * 512 * 32 * 2 * 2);
  bf16* xdL1 = (bf16*)alloc((size_t)512 * 32 * 64 * 2);
  float* state = (float*)alloc((size_t)512 * 32 * 64 * 4);
  bf16* sb = (bf16*)alloc((size_t)512 * 32 * 64 * 2);
  bf16* sdiff = (bf16*)alloc((size_t)512 * 32 * 64 * 2);
  bf16* zs = (bf16*)alloc((size_t)512 * 32 * 64 * 2);
  bf16* zsdiff = (bf16*)alloc((size_t)512 * 32 * 64 * 2);
  bf16* rbuf = (bf16*)alloc((size_t)512 * 32 * 64 * 2);
  float* PW = (float*)alloc((size_t)16 * 48 * 4);
  float* fsb = (float*)alloc((size_t)512 * 12 * 4);
  unsigned* bar = (unsigned*)alloc((size_t)544 * 4);
  bf16* val = gWb;

  adj_kernel<<<512, 256, 0, stream>>>(emb, adjb);
  pw_kernel<<<dim3(48, 16), 256, 0, stream>>>(uwp[1], hypW, PW);
  fs_kernel<<<24, 256, 0, stream>>>(emb, PW, hypb, fsb);
  cvt_src_kernel<<<1536, 256, 0, stream>>>(src, xin0);

  int occ0 = 0, occ1 = 0;
  hipOccupancyMaxActiveBlocksPerMultiprocessor(&occ0, recur_kernel<2>, 256, 0);
  hipOccupancyMaxActiveBlocksPerMultiprocessor(&occ1, recur_kernel<64>, 256, 0);

  for (int l = 0; l < 2; l++) {
    int C = (l == 0) ? 2 : 64;
    int KC = 2 * (C + 64);
    int KCP = (KC + 31) & ~31;
    int JG = KC * 128, JU = KC * 64;
    if (KCP != KC) {
      zero_f32_kernel<<<(512 * KCP * 128 / 2 + 255) / 256, 256, 0, stream>>>(
          (float*)gWb, 512 * KCP * 128 / 2);
      zero_f32_kernel<<<(512 * KCP * 64 / 2 + 255) / 256, 256, 0, stream>>>(
          (float*)uWb, 512 * KCP * 64 / 2);
    }
    wgen_t_kernel<<<dim3((JG + 255) / 256, 4), 256, 0, stream>>>(gwp[l], emb, gWb, JG, 7, KCP);
    wgen_t_kernel<<<dim3((JU + 255) / 256, 4), 256, 0, stream>>>(uwp[l], emb, uWb, JU, 6, KCP);
    wgen_kernel<<<dim3(1, 4), 256, 0, stream>>>(gbp[l], emb, gb, 128);
    wgen_kernel<<<dim3(1, 4), 256, 0, stream>>>(ubp[l], emb, ub, 64);
    zero_f32_kernel<<<3, 256, 0, stream>>>((float*)bar, 544);

    const bf16* xin = (l == 0) ? xin0 : x0;
    bf16* xd = (l == 0) ? xd0 : xdL1;
    int occ = (l == 0) ? occ0 : occ1;
    hipError_t ce = hipErrorInvalidValue;
    if (occ >= 2) {
      void* args[12];
      args[0] = &adjb; args[1] = &xin; args[2] = &gWb; args[3] = &gb;
      args[4] = &uWb; args[5] = &ub; args[6] = &zs; args[7] = &sdiff;
      args[8] = &zsdiff; args[9] = &xd; args[10] = &x0; args[11] = &bar;
      if (l == 0)
        ce = hipLaunchCooperativeKernel(reinterpret_cast<void*>(recur_kernel<2>),
                                        dim3(512), dim3(256), args, 0, stream);
      else
        ce = hipLaunchCooperativeKernel(reinterpret_cast<void*>(recur_kernel<64>),
                                        dim3(512), dim3(256), args, 0, stream);
    }
    if (ce != hipSuccess) {
      (void)hipGetLastError();
      zero_f32_kernel<<<4096, 256, 0, stream>>>(state, 512 * 32 * 64);
      zero_f32_kernel<<<2048, 256, 0, stream>>>((float*)sb, 512 * 32 * 64 / 2);
      if (l == 0) diffuse0_kernel<<<96, 256, 0, stream>>>(adjb, xin, xd);
      for (int t = 0; t < 12; t++) {
        const bf16* xt = xin + (size_t)t * 512 * 32 * C;
        const bf16* xdt = (l == 0) ? (xd + (size_t)t * 512 * 32 * C) : xd;
        bf16* xo = x0 + (size_t)t * 512 * 32 * 64;
        if (l == 1) diffuse1_kernel<<<256, 256, 0, stream>>>(adjb, xt, xd);
        diffuse1_kernel<<<256, 256, 0, stream>>>(adjb, sb, sdiff);
        if (l == 0)
          gate_wrap<2><<<512, 256, 0, stream>>>(xt, xdt, sb, sdiff, gWb, gb, state, zs, rbuf);
        else
          gate_wrap<64><<<512, 256, 0, stream>>>(xt, xdt, sb, sdiff, gWb, gb, state, zs, rbuf);
        diffuse1_kernel<<<256, 256, 0, stream>>>(adjb, zs, zsdiff);
        if (l == 0)
          upd_wrap<2><<<512, 256, 0, stream>>>(xt, xdt, zs, zsdiff, uWb, ub, state, sb, rbuf, xo);
        else
          upd_wrap<64><<<512, 256, 0, stream>>>(xt, xdt, zs, zsdiff, uWb, ub, state, sb, rbuf, xo);
      }
    }
  }

  attn1_kernel<<<2048, 256, 0, stream>>>(x0, fsb, Wq, bq, Wk, bk, Wv, bv, ln1g, ln1b, val);
  ffn_kernel<<<2048, 256, 0, stream>>>(val, ffW1, ffb1, ffW2, ffb2, ln2g, ln2b, fcW, fcb,
                                       outp, 96);
}

// Round 6
// 1651.504 us; speedup vs baseline: 1.2342x; 1.2342x over previous
//
#include <hip/hip_runtime.h>
#include <hip/hip_bf16.h>

// MAGCRN on MI355X — round 16 (= round 15 resubmit; container infra failure,
// source audited: no OOB / no divergent-barrier / LDS fits / MFMA layouts
// match the verified diffuse mapping).
//  * wgen_t v2: thread = output position -> contiguous stores; pad zeroed
//    inline (zero_f32 pre-passes removed).
//  * attn1 v2: q/k projections via mfma_16x16x32_bf16.
//  * ffn v2: both 64x64 layers via MFMA; h1 split into bf16 hi+lo pairs.
//  * recur/diffusion/barrier unchanged from round 14 (passed).

using bf16 = __hip_bfloat16;
#define B2F(x) __bfloat162float(x)

#define NN 512
#define BBATCH 32
#define HHID 64
#define TT 12
#define EE 16

typedef __attribute__((ext_vector_type(4))) float f32x4;
typedef __attribute__((ext_vector_type(8))) short bf16x8;

__device__ inline float wsum(float x) {
#pragma unroll
  for (int off = 32; off > 0; off >>= 1) x += __shfl_xor(x, off, 64);
  return x;
}

// ---------------- LLC-coherent access helpers ------------------------------
__device__ inline uint4 llc_load4(const void* p) {
  uint4 r;
  asm volatile("global_load_dwordx4 %0, %1, off sc0 sc1" : "=v"(r) : "v"(p));
  return r;
}
__device__ inline uint2 llc_load2(const void* p) {
  uint2 r;
  asm volatile("global_load_dwordx2 %0, %1, off sc0 sc1" : "=v"(r) : "v"(p));
  return r;
}
__device__ inline unsigned llc_load1(const void* p) {
  unsigned r;
  asm volatile("global_load_dword %0, %1, off sc0 sc1" : "=v"(r) : "v"(p));
  return r;
}
__device__ inline void llc_store_bf(void* p, unsigned short v) {
  asm volatile("global_store_short %0, %1, off sc0 sc1" :: "v"(p), "v"((unsigned)v) : "memory");
}
__device__ inline void llc_store_u1(void* p, unsigned v) {
  asm volatile("global_store_dword %0, %1, off sc0 sc1" :: "v"(p), "v"(v) : "memory");
}
template <int N> __device__ inline void wait_vmcnt() {
  if constexpr (N == 0) asm volatile("s_waitcnt vmcnt(0)" ::: "memory");
  else if constexpr (N == 1) asm volatile("s_waitcnt vmcnt(1)" ::: "memory");
  else if constexpr (N == 2) asm volatile("s_waitcnt vmcnt(2)" ::: "memory");
  else asm volatile("s_waitcnt vmcnt(4)" ::: "memory");
}

// LDS-only barrier: waits DS ops, leaves global loads in flight.
__device__ inline void lds_barrier() {
  asm volatile("s_waitcnt lgkmcnt(0)" ::: "memory");
  __builtin_amdgcn_s_barrier();
  asm volatile("" ::: "memory");
}

// ---------------- grid barrier: fenceless flags + master + epoch -----------
__device__ inline void gbar(unsigned* __restrict__ bar, int& cnt) {
  cnt++;
  __syncthreads();  // drains vmcnt(0): all sc stores are at the LLC
  unsigned tgt = (unsigned)cnt;
  unsigned* flags = bar + 32;
  if (blockIdx.x == 0) {
    if (threadIdx.x < 64) {
      if (threadIdx.x == 0) llc_store_u1(flags, tgt);
      const unsigned* fp = flags + threadIdx.x * 8;
      bool ok;
      do {
        unsigned v0 = llc_load1(fp + 0), v1 = llc_load1(fp + 1),
                 v2 = llc_load1(fp + 2), v3 = llc_load1(fp + 3),
                 v4 = llc_load1(fp + 4), v5 = llc_load1(fp + 5),
                 v6 = llc_load1(fp + 6), v7 = llc_load1(fp + 7);
        wait_vmcnt<0>();
        __builtin_amdgcn_sched_barrier(0);
        ok = ((int)(v0 - tgt) >= 0) && ((int)(v1 - tgt) >= 0) &&
             ((int)(v2 - tgt) >= 0) && ((int)(v3 - tgt) >= 0) &&
             ((int)(v4 - tgt) >= 0) && ((int)(v5 - tgt) >= 0) &&
             ((int)(v6 - tgt) >= 0) && ((int)(v7 - tgt) >= 0);
      } while (!__all(ok));
      if (threadIdx.x == 0) llc_store_u1(bar, tgt);
    }
  } else if (threadIdx.x == 0) {
    llc_store_u1(flags + blockIdx.x, tgt);
    for (;;) {
      unsigned e = llc_load1(bar);
      wait_vmcnt<0>();
      __builtin_amdgcn_sched_barrier(0);
      if ((int)(e - tgt) >= 0) break;
      __builtin_amdgcn_s_sleep(2);
    }
  }
  __syncthreads();
}

__global__ __launch_bounds__(256) void zero_f32_kernel(float* __restrict__ p, int n) {
  int i = blockIdx.x * 256 + threadIdx.x;
  if (i < n) p[i] = 0.0f;
}

// ---------------- setup kernels ----------------

__global__ __launch_bounds__(256) void adj_kernel(const float* __restrict__ emb,
                                                  bf16* __restrict__ adjb) {
  __shared__ float embAll[NN * EE];
  __shared__ float red[256];
  int tid = threadIdx.x, n = blockIdx.x;
  for (int i = tid; i < NN * EE; i += 256) embAll[i] = emb[i];
  __syncthreads();
  float v[2];
#pragma unroll
  for (int j = 0; j < 2; j++) {
    int m = tid + j * 256;
    float s = 0.f;
#pragma unroll
    for (int e = 0; e < EE; e++) s += embAll[n * EE + e] * embAll[m * EE + e];
    v[j] = fmaxf(s, 0.0f);
  }
  float mx = fmaxf(v[0], v[1]);
  red[tid] = mx; __syncthreads();
  for (int s = 128; s > 0; s >>= 1) { if (tid < s) red[tid] = fmaxf(red[tid], red[tid + s]); __syncthreads(); }
  mx = red[0]; __syncthreads();
  float e0 = expf(v[0] - mx), e1 = expf(v[1] - mx);
  red[tid] = e0 + e1; __syncthreads();
  for (int s = 128; s > 0; s >>= 1) { if (tid < s) red[tid] += red[tid + s]; __syncthreads(); }
  float inv = 1.0f / red[0];
  adjb[n * NN + tid] = __float2bfloat16(e0 * inv);
  adjb[n * NN + tid + 256] = __float2bfloat16(e1 * inv);
}

__global__ __launch_bounds__(256) void wgen_kernel(const float* __restrict__ pool,
                                                   const float* __restrict__ emb,
                                                   float* __restrict__ out, int J) {
  __shared__ float embL[128 * EE];
  int tid = threadIdx.x;
  int n0 = blockIdx.y * 128;
  for (int i = tid; i < 128 * EE; i += 256) embL[i] = emb[n0 * EE + i];
  __syncthreads();
  int j = blockIdx.x * 256 + tid;
  if (j >= J) return;
  float pw[EE];
#pragma unroll
  for (int e = 0; e < EE; e++) pw[e] = pool[e * J + j];
#pragma unroll 4
  for (int nn = 0; nn < 128; nn++) {
    float s = 0.f;
#pragma unroll
    for (int e = 0; e < EE; e++) s += embL[nn * EE + e] * pw[e];
    out[(size_t)(n0 + nn) * J + j] = s;
  }
}

// coalesced transposed weight generator: thread p = output position
// out[n][p], p = o*KCP + kc; value from pool col j = kc*O + o; pad -> 0.
__global__ __launch_bounds__(256) void wgen_t_kernel(const float* __restrict__ pool,
                                                     const float* __restrict__ emb,
                                                     bf16* __restrict__ out, int J,
                                                     int O, int KCP, int KC) {
  __shared__ float embL[128 * EE];
  int tid = threadIdx.x;
  int n0 = blockIdx.y * 128;
  for (int i = tid; i < 128 * EE; i += 256) embL[i] = emb[n0 * EE + i];
  __syncthreads();
  int p = blockIdx.x * 256 + tid;
  unsigned kc = (unsigned)p % (unsigned)KCP;
  unsigned o = (unsigned)p / (unsigned)KCP;
  size_t P = (size_t)KCP * O;
  if (kc >= (unsigned)KC) {
    bf16 z = __float2bfloat16(0.f);
    for (int nn = 0; nn < 128; nn++) out[(size_t)(n0 + nn) * P + p] = z;
    return;
  }
  int jp = (int)kc * O + (int)o;
  float pw[EE];
#pragma unroll
  for (int e = 0; e < EE; e++) pw[e] = pool[e * J + jp];
#pragma unroll 4
  for (int nn = 0; nn < 128; nn++) {
    float s = 0.f;
#pragma unroll
    for (int e = 0; e < EE; e++) s += embL[nn * EE + e] * pw[e];
    out[(size_t)(n0 + nn) * P + p] = __float2bfloat16(s);
  }
}

__global__ __launch_bounds__(256) void pw_kernel(const float* __restrict__ upool,
                                                 const float* __restrict__ hypW,
                                                 float* __restrict__ PW) {
  __shared__ float red[256];
  int j = blockIdx.x, e = blockIdx.y, tid = threadIdx.x;
  float s = 0.f;
#pragma unroll 4
  for (int p = tid; p < 16384; p += 256) s += upool[e * 16384 + p] * hypW[p * 48 + j];
  red[tid] = s; __syncthreads();
  for (int t = 128; t > 0; t >>= 1) { if (tid < t) red[tid] += red[tid + t]; __syncthreads(); }
  if (tid == 0) PW[e * 48 + j] = red[0];
}

__global__ __launch_bounds__(256) void fs_kernel(const float* __restrict__ emb,
                                                 const float* __restrict__ PW,
                                                 const float* __restrict__ hypb,
                                                 float* __restrict__ fs) {
  int id = blockIdx.x * 256 + threadIdx.x;
  if (id >= NN * TT) return;
  int n = id / TT, t = id % TT;
  float s = 0.f;
#pragma unroll
  for (int f = 0; f < 4; f++) {
    int j = t * 4 + f;
    float h = hypb[j];
#pragma unroll
    for (int e = 0; e < EE; e++) h += emb[n * EE + e] * PW[e * 48 + j];
    s += h;
  }
  fs[id] = s;
}

__global__ __launch_bounds__(256) void cvt_src_kernel(const float* __restrict__ src,
                                                      bf16* __restrict__ x) {
  int id = blockIdx.x * 256 + threadIdx.x;  // < 393216
  int c = id & 1, b = (id >> 1) & 31, n = (id >> 6) & 511, t = id >> 15;
  x[id] = __float2bfloat16(src[((b * TT + t) * NN + n) * 2 + c]);
}

// ---------------- diffusion: pipelined, LLC-coherent, counted waits --------
#define DBUF 4672

__device__ inline void xsT_wr8(unsigned short* xsT, int base, int q0l, int k, uint4 v) {
  union { uint4 u; unsigned short h[8]; } cv; cv.u = v;
#pragma unroll
  for (int qq = 0; qq < 8; qq++) {
    int q = q0l + qq;
    xsT[base + q * 72 + (q >> 3) * 8 + k] = cv.h[qq];
  }
}

template <int QW>
__device__ inline void diffuse_tileP(const bf16x8* __restrict__ apre,
                                     const bf16* __restrict__ X, bf16* __restrict__ Y,
                                     int Q, int n0, int q0, char* smraw, int tid) {
  constexpr int LPC = QW / 32;
  constexpr int NCT = QW / 16;
  unsigned short* xsT = (unsigned short*)smraw;
  int w = tid >> 6, lane = tid & 63;
  int col = lane & 15, quad = lane >> 4;
  int kr, ql;
  if constexpr (QW == 64) { kr = tid >> 3; ql = (tid & 7) * 8; }
  else                    { kr = tid >> 2; ql = (tid & 3) * 8; }
  f32x4 acc[NCT];
#pragma unroll
  for (int ct = 0; ct < NCT; ct++) acc[ct] = (f32x4){0.f, 0.f, 0.f, 0.f};
  const bf16* Xb = X + q0 + ql;
  uint4 pre[3][LPC];
#pragma unroll
  for (int d = 0; d < 3; d++) {
    pre[d][0] = llc_load4(Xb + (size_t)(d * 64 + kr) * Q);
    if constexpr (QW == 64)
      pre[d][1] = llc_load4(Xb + (size_t)(d * 64 + 32 + kr) * Q);
  }
  wait_vmcnt<2 * LPC>();
  xsT_wr8(xsT, 0, ql, kr, pre[0][0]);
  if constexpr (QW == 64) xsT_wr8(xsT, 0, ql, 32 + kr, pre[0][1]);
  pre[0][0] = llc_load4(Xb + (size_t)(3 * 64 + kr) * Q);
  if constexpr (QW == 64)
    pre[0][1] = llc_load4(Xb + (size_t)(3 * 64 + 32 + kr) * Q);
  lds_barrier();
#pragma unroll
  for (int c = 0; c < 8; c++) {
    int sl = (c + 1) % 3;
    if (c < 7) {
      if (c < 5) wait_vmcnt<2 * LPC>();
      else if (c == 5) wait_vmcnt<LPC>();
      else wait_vmcnt<0>();
      int nb = ((c + 1) & 1) * DBUF;
      xsT_wr8(xsT, nb, ql, kr, pre[sl][0]);
      if constexpr (QW == 64) xsT_wr8(xsT, nb, ql, 32 + kr, pre[sl][1]);
    }
    int base = (c & 1) * DBUF;
#pragma unroll
    for (int ki = 0; ki < 2; ki++) {
      bf16x8 a = apre[c * 2 + ki];
#pragma unroll
      for (int ct = 0; ct < NCT; ct++) {
        int q = ct * 16 + col;
        bf16x8 b = *(const bf16x8*)&xsT[base + q * 72 + (q >> 3) * 8 + ki * 32 + quad * 8];
        acc[ct] = __builtin_amdgcn_mfma_f32_16x16x32_bf16(a, b, acc[ct], 0, 0, 0);
      }
    }
    if (c + 4 < 8) {
      pre[sl][0] = llc_load4(Xb + (size_t)((c + 4) * 64 + kr) * Q);
      if constexpr (QW == 64)
        pre[sl][1] = llc_load4(Xb + (size_t)((c + 4) * 64 + 32 + kr) * Q);
    }
    lds_barrier();
  }
#pragma unroll
  for (int ct = 0; ct < NCT; ct++)
#pragma unroll
    for (int r = 0; r < 4; r++) {
      int row = n0 + w * 16 + quad * 4 + r;
      bf16 hb = __float2bfloat16(acc[ct][r]);
      llc_store_bf(Y + (size_t)row * Q + q0 + ct * 16 + col, *(unsigned short*)&hb);
    }
}

// ---------------- fallback-path shared functions ---------------------------

template <int C>
__device__ inline void stage_A(int n, int tid, unsigned short* xinb,
    const bf16* __restrict__ xt, const bf16* __restrict__ xd,
    const bf16* __restrict__ sa, const bf16* __restrict__ sad) {
  constexpr int cc = C + HHID, KC = 2 * cc, KCP = (KC + 31) & ~31, PIT = KCP + 8;
  __syncthreads();
  for (int i = tid; i < 32 * KCP; i += 256) {
    int b = i / KCP, kc = i - b * KCP;
    unsigned short v = 0;
    if (kc < C)            v = *(const unsigned short*)&xt[(n * 32 + b) * C + kc];
    else if (kc < cc)      v = *(const unsigned short*)&sa[(n * 32 + b) * HHID + kc - C];
    else if (kc < cc + C)  v = *(const unsigned short*)&xd[(n * 32 + b) * C + kc - cc];
    else if (kc < KC)      v = *(const unsigned short*)&sad[(n * 32 + b) * HHID + kc - cc - C];
    xinb[b * PIT + kc] = v;
  }
  __syncthreads();
}

template <int C>
__device__ inline void gate_epilogue(int n, int w, int col, int quad,
    f32x4 acc[2][2], const float* __restrict__ gb, const float* __restrict__ state,
    bf16* __restrict__ zs, bf16* __restrict__ rbuf) {
#pragma unroll
  for (int i = 0; i < 2; i++) {
    int o = (w + i * 4) * 16 + col;
    float bv = gb[n * 128 + o];
#pragma unroll
    for (int mt = 0; mt < 2; mt++)
#pragma unroll
      for (int r = 0; r < 4; r++) {
        int m = mt * 16 + quad * 4 + r;
        float zr = 1.0f / (1.0f + expf(-(acc[i][mt][r] + bv)));
        int idx = (n * 32 + m) * HHID + (o & 63);
        if (o < HHID) zs[idx] = __float2bfloat16(zr * state[idx]);
        else          rbuf[idx] = __float2bfloat16(zr);
      }
  }
}

template <int C>
__device__ inline void upd_epilogue(int n, int w, int col, int quad,
    f32x4 acc[2], const float* __restrict__ ub, float* __restrict__ state,
    bf16* __restrict__ sb, const bf16* __restrict__ rbuf, bf16* __restrict__ xo) {
  int o = w * 16 + col;
  float bv = ub[n * 64 + o];
#pragma unroll
  for (int mt = 0; mt < 2; mt++)
#pragma unroll
    for (int r = 0; r < 4; r++) {
      int m = mt * 16 + quad * 4 + r;
      int idx = (n * 32 + m) * HHID + o;
      float hc = tanhf(acc[mt][r] + bv);
      float rr = B2F(rbuf[idx]);
      float st = state[idx];
      float h = rr * st + (1.0f - rr) * hc;
      state[idx] = h;
      bf16 hb = __float2bfloat16(h);
      sb[idx] = hb;
      xo[idx] = hb;
    }
}

template <int C>
__device__ inline void gate_mfma(int n, int tid, const unsigned short* xinb,
    const bf16* __restrict__ gWt, const float* __restrict__ gb,
    const float* __restrict__ state, bf16* __restrict__ zs, bf16* __restrict__ rbuf) {
  constexpr int KC = 2 * (C + HHID), KCP = (KC + 31) & ~31, PIT = KCP + 8;
  int w = tid >> 6, lane = tid & 63, col = lane & 15, quad = lane >> 4;
  f32x4 acc[2][2];
#pragma unroll
  for (int i = 0; i < 2; i++)
#pragma unroll
    for (int mt = 0; mt < 2; mt++) acc[i][mt] = (f32x4){0.f, 0.f, 0.f, 0.f};
  const bf16* Wn = gWt + (size_t)n * KCP * 128;
#pragma unroll 2
  for (int k0 = 0; k0 < KCP; k0 += 32) {
    int ko = k0 + quad * 8;
    bf16x8 a0 = *(const bf16x8*)&xinb[col * PIT + ko];
    bf16x8 a1 = *(const bf16x8*)&xinb[(16 + col) * PIT + ko];
#pragma unroll
    for (int i = 0; i < 2; i++) {
      int o = (w + i * 4) * 16 + col;
      bf16x8 bf = *(const bf16x8*)(Wn + (size_t)o * KCP + ko);
      acc[i][0] = __builtin_amdgcn_mfma_f32_16x16x32_bf16(a0, bf, acc[i][0], 0, 0, 0);
      acc[i][1] = __builtin_amdgcn_mfma_f32_16x16x32_bf16(a1, bf, acc[i][1], 0, 0, 0);
    }
  }
  gate_epilogue<C>(n, w, col, quad, acc, gb, state, zs, rbuf);
}

template <int C>
__device__ inline void upd_mfma(int n, int tid, const unsigned short* xinb,
    const bf16* __restrict__ uWt, const float* __restrict__ ub,
    float* __restrict__ state, bf16* __restrict__ sb,
    const bf16* __restrict__ rbuf, bf16* __restrict__ xo) {
  constexpr int KC = 2 * (C + HHID), KCP = (KC + 31) & ~31, PIT = KCP + 8;
  int w = tid >> 6, lane = tid & 63, col = lane & 15, quad = lane >> 4;
  f32x4 acc[2];
  acc[0] = (f32x4){0.f, 0.f, 0.f, 0.f};
  acc[1] = (f32x4){0.f, 0.f, 0.f, 0.f};
  const bf16* Wn = uWt + (size_t)n * KCP * 64;
  int o = w * 16 + col;
#pragma unroll 2
  for (int k0 = 0; k0 < KCP; k0 += 32) {
    int ko = k0 + quad * 8;
    bf16x8 a0 = *(const bf16x8*)&xinb[col * PIT + ko];
    bf16x8 a1 = *(const bf16x8*)&xinb[(16 + col) * PIT + ko];
    bf16x8 bf = *(const bf16x8*)(Wn + (size_t)o * KCP + ko);
    acc[0] = __builtin_amdgcn_mfma_f32_16x16x32_bf16(a0, bf, acc[0], 0, 0, 0);
    acc[1] = __builtin_amdgcn_mfma_f32_16x16x32_bf16(a1, bf, acc[1], 0, 0, 0);
  }
  upd_epilogue<C>(n, w, col, quad, acc, ub, state, sb, rbuf, xo);
}

// ---------------- cooperative recurrence -----------------------------------

template <int C>
__global__ __launch_bounds__(256, 2) void recur_kernel(
    const bf16* __restrict__ adjb, const bf16* __restrict__ xin,
    const bf16* __restrict__ gWt, const float* __restrict__ gb,
    const bf16* __restrict__ uWt, const float* __restrict__ ub,
    bf16* __restrict__ zs, bf16* __restrict__ sdiff, bf16* __restrict__ zsdiff,
    bf16* __restrict__ xd, bf16* __restrict__ xout, unsigned* __restrict__ bar) {
  constexpr int KC = 2 * (C + HHID), KCP = (KC + 31) & ~31, PIT = KCP + 8;
  constexpr int NK = KCP / 32;
  constexpr int QX = 32 * C;
  __shared__ __align__(16) char dsm[2 * DBUF * 2];
  __shared__ __align__(16) unsigned short xinb[32 * PIT];
  int bid = blockIdx.x, tid = threadIdx.x;   // grid is exactly 512 blocks
  int w = tid >> 6, lane = tid & 63, col = lane & 15, quad = lane >> 4;
  int bcnt = 0;

  bf16x8 apre[16];
  {
    int n0p = ((bid & 255) >> 5) * 64;
    const bf16* ar = adjb + (size_t)(n0p + w * 16 + col) * NN;
#pragma unroll
    for (int c = 0; c < 8; c++)
#pragma unroll
      for (int ki = 0; ki < 2; ki++)
        apre[c * 2 + ki] = *(const bf16x8*)(ar + c * 64 + ki * 32 + quad * 8);
  }
  bf16x8 fg[2 * NK];
  {
    const bf16* Wn = gWt + (size_t)bid * KCP * 128;
#pragma unroll
    for (int i = 0; i < 2; i++) {
      int o = (w + i * 4) * 16 + col;
#pragma unroll
      for (int kk = 0; kk < NK; kk++)
        fg[i * NK + kk] = *(const bf16x8*)(Wn + (size_t)o * KCP + kk * 32 + quad * 8);
    }
  }
  bf16x8 fu[NK];
  {
    const bf16* Wn = uWt + (size_t)bid * KCP * 64;
    int o = w * 16 + col;
#pragma unroll
    for (int kk = 0; kk < NK; kk++)
      fu[kk] = *(const bf16x8*)(Wn + (size_t)o * KCP + kk * 32 + quad * 8);
  }
  float gbv0 = gb[bid * 128 + w * 16 + col];
  float gbv1 = gb[bid * 128 + 64 + w * 16 + col];
  float ubv  = ub[bid * 64 + w * 16 + col];

  for (int i = tid; i < 32 * PIT; i += 256) xinb[i] = 0;
  __syncthreads();

  int r2 = tid >> 3, ch = tid & 7;
  uint4 vxt; unsigned sxt = 0, sxd = 0;
  if constexpr (C == 64) {
    vxt = *(const uint4*)(xin + (size_t)(bid * 32 + r2) * 64 + ch * 8);
  } else {
    if (tid < 32) sxt = *(const unsigned*)(xin + (size_t)(bid * 32 + tid) * 2);
  }

  float st[2][4], rr_[2][4];
#pragma unroll
  for (int mt = 0; mt < 2; mt++)
#pragma unroll
    for (int r4 = 0; r4 < 4; r4++) st[mt][r4] = 0.f;

  // pre-loop diffusion (uses this block's apre rows)
  if constexpr (C == 2) {
    int wg = (bid & 31) | ((bid >> 8) << 5);
    if (wg < TT)
      diffuse_tileP<64>(apre, xin + (size_t)wg * NN * QX, xd + (size_t)wg * NN * QX,
                        QX, ((bid & 255) >> 5) * 64, 0, dsm, tid);
  } else {
    if (bid >= 256)
      diffuse_tileP<64>(apre, xin, xd, 2048, ((bid & 255) >> 5) * 64,
                        (bid & 31) * 64, dsm, tid);
  }
  gbar(bar, bcnt);

  for (int t = 0; t < TT; t++) {
    const bf16* xt = xin + (size_t)t * NN * QX;
    const bf16* xdt = (C == 2) ? (xd + (size_t)t * NN * QX) : xd;
    bf16* xo = xout + (size_t)t * NN * 32 * HHID;
    if (t > 0) {
      const bf16* sbp = xout + (size_t)(t - 1) * NN * 32 * HHID;
      if constexpr (C == 64) {
        if (bid < 256)
          diffuse_tileP<64>(apre, sbp, sdiff, 2048, (bid >> 5) * 64,
                            (bid & 31) * 64, dsm, tid);
        else
          diffuse_tileP<64>(apre, xt, xd, 2048, ((bid & 255) >> 5) * 64,
                            (bid & 31) * 64, dsm, tid);
      } else {
        int cs = (bid & 31) | ((bid >> 8) << 5);
        diffuse_tileP<32>(apre, sbp, sdiff, 2048, ((bid & 255) >> 5) * 64,
                          cs * 32, dsm, tid);
      }
      gbar(bar, bcnt);
    }
    // ---- P2 stage ----
    if constexpr (C == 64) {
      *(uint4*)&xinb[r2 * PIT + ch * 8] = vxt;
      uint4 v1 = llc_load4(xdt + (size_t)(bid * 32 + r2) * 64 + ch * 8);
      uint4 v2;
      if (t > 0) v2 = llc_load4(sdiff + (size_t)(bid * 32 + r2) * 64 + ch * 8);
      wait_vmcnt<0>();
      *(uint4*)&xinb[r2 * PIT + 128 + ch * 8] = v1;
      if (t > 0) *(uint4*)&xinb[r2 * PIT + 192 + ch * 8] = v2;
    } else {
      if (tid < 32) *(unsigned*)&xinb[tid * PIT] = sxt;
      if (t == 0) {
        if (tid < 32) {
          unsigned v = llc_load1(xdt + (size_t)(bid * 32 + tid) * 2);
          wait_vmcnt<0>();
          *(unsigned*)&xinb[tid * PIT + 66] = v;
        }
      } else {
        if (tid >= 32 && tid < 64) *(unsigned*)&xinb[(tid - 32) * PIT + 66] = sxd;
        int r2a = tid >> 4, c4 = tid & 15;
        uint2 va = llc_load2(sdiff + (size_t)(bid * 32 + r2a) * 64 + c4 * 4);
        uint2 vb = llc_load2(sdiff + (size_t)(bid * 32 + 16 + r2a) * 64 + c4 * 4);
        wait_vmcnt<0>();
        *(uint2*)&xinb[r2a * PIT + 68 + c4 * 4] = va;
        *(uint2*)&xinb[(16 + r2a) * PIT + 68 + c4 * 4] = vb;
      }
    }
    __syncthreads();
    // ---- P2 gate MFMA ----
    {
      f32x4 acc[2][2];
#pragma unroll
      for (int i = 0; i < 2; i++)
#pragma unroll
        for (int mt = 0; mt < 2; mt++) acc[i][mt] = (f32x4){0.f, 0.f, 0.f, 0.f};
#pragma unroll
      for (int kk = 0; kk < NK; kk++) {
        int ko = kk * 32 + quad * 8;
        bf16x8 a0 = *(const bf16x8*)&xinb[col * PIT + ko];
        bf16x8 a1 = *(const bf16x8*)&xinb[(16 + col) * PIT + ko];
#pragma unroll
        for (int i = 0; i < 2; i++) {
          acc[i][0] = __builtin_amdgcn_mfma_f32_16x16x32_bf16(a0, fg[i * NK + kk], acc[i][0], 0, 0, 0);
          acc[i][1] = __builtin_amdgcn_mfma_f32_16x16x32_bf16(a1, fg[i * NK + kk], acc[i][1], 0, 0, 0);
        }
      }
      __syncthreads();
#pragma unroll
      for (int mt = 0; mt < 2; mt++)
#pragma unroll
        for (int r4 = 0; r4 < 4; r4++) {
          int m = mt * 16 + quad * 4 + r4;
          float z = 1.0f / (1.0f + expf(-(acc[0][mt][r4] + gbv0)));
          float rv = 1.0f / (1.0f + expf(-(acc[1][mt][r4] + gbv1)));
          rr_[mt][r4] = rv;
          bf16 zb = __float2bfloat16(z * st[mt][r4]);
          xinb[m * PIT + C + w * 16 + col] = *(unsigned short*)&zb;
          llc_store_bf(zs + (size_t)(bid * 32 + m) * 64 + w * 16 + col,
                       *(unsigned short*)&zb);
        }
    }
    if (t > 0) {
      gbar(bar, bcnt);
      {
        int cs = (bid & 31) | ((bid >> 8) << 5);
        diffuse_tileP<32>(apre, zs, zsdiff, 2048, ((bid & 255) >> 5) * 64,
                          cs * 32, dsm, tid);
      }
      gbar(bar, bcnt);
      if constexpr (C == 64) {
        uint4 v = llc_load4(zsdiff + (size_t)(bid * 32 + r2) * 64 + ch * 8);
        wait_vmcnt<0>();
        *(uint4*)&xinb[r2 * PIT + 192 + ch * 8] = v;
      } else {
        int r2a = tid >> 4, c4 = tid & 15;
        uint2 va = llc_load2(zsdiff + (size_t)(bid * 32 + r2a) * 64 + c4 * 4);
        uint2 vb = llc_load2(zsdiff + (size_t)(bid * 32 + 16 + r2a) * 64 + c4 * 4);
        wait_vmcnt<0>();
        *(uint2*)&xinb[r2a * PIT + 68 + c4 * 4] = va;
        *(uint2*)&xinb[(16 + r2a) * PIT + 68 + c4 * 4] = vb;
      }
    }
    __syncthreads();
    // ---- P4 update MFMA ----
    {
      f32x4 acc[2];
      acc[0] = (f32x4){0.f, 0.f, 0.f, 0.f};
      acc[1] = (f32x4){0.f, 0.f, 0.f, 0.f};
#pragma unroll
      for (int kk = 0; kk < NK; kk++) {
        int ko = kk * 32 + quad * 8;
        bf16x8 a0 = *(const bf16x8*)&xinb[col * PIT + ko];
        bf16x8 a1 = *(const bf16x8*)&xinb[(16 + col) * PIT + ko];
        acc[0] = __builtin_amdgcn_mfma_f32_16x16x32_bf16(a0, fu[kk], acc[0], 0, 0, 0);
        acc[1] = __builtin_amdgcn_mfma_f32_16x16x32_bf16(a1, fu[kk], acc[1], 0, 0, 0);
      }
      __syncthreads();
      if (t + 1 < TT) {
        if constexpr (C == 64) {
          vxt = *(const uint4*)(xin + (size_t)(t + 1) * NN * QX +
                                (size_t)(bid * 32 + r2) * 64 + ch * 8);
        } else {
          if (tid < 32)
            sxt = *(const unsigned*)(xin + (size_t)(t + 1) * NN * QX +
                                     (size_t)(bid * 32 + tid) * 2);
          else if (tid < 64)
            sxd = *(const unsigned*)(xd + (size_t)(t + 1) * NN * QX +
                                     (size_t)(bid * 32 + (tid - 32)) * 2);
        }
      }
#pragma unroll
      for (int mt = 0; mt < 2; mt++)
#pragma unroll
        for (int r4 = 0; r4 < 4; r4++) {
          int m = mt * 16 + quad * 4 + r4;
          float hc = tanhf(acc[mt][r4] + ubv);
          float rv = rr_[mt][r4];
          float h = rv * st[mt][r4] + (1.0f - rv) * hc;
          st[mt][r4] = h;
          bf16 hb = __float2bfloat16(h);
          xinb[m * PIT + C + w * 16 + col] = *(unsigned short*)&hb;
          llc_store_bf(xo + (size_t)(bid * 32 + m) * 64 + w * 16 + col,
                       *(unsigned short*)&hb);
        }
    }
    gbar(bar, bcnt);
  }
}

// ---------------- fallback per-phase kernels (same math) ----------------

__global__ __launch_bounds__(256, 2) void diffuse0_kernel(const bf16* __restrict__ adjb,
                                                          const bf16* __restrict__ X,
                                                          bf16* __restrict__ Y) {
  __shared__ __align__(16) char smraw[2 * DBUF * 2];
  int bid = blockIdx.x, tid = threadIdx.x;  // 96
  int t = bid >> 3, n0 = (bid & 7) * 64;
  int w = tid >> 6, lane = tid & 63, col = lane & 15, quad = lane >> 4;
  bf16x8 ap[16];
  const bf16* ar = adjb + (size_t)(n0 + w * 16 + col) * NN;
#pragma unroll
  for (int c = 0; c < 8; c++)
#pragma unroll
    for (int ki = 0; ki < 2; ki++)
      ap[c * 2 + ki] = *(const bf16x8*)(ar + c * 64 + ki * 32 + quad * 8);
  diffuse_tileP<64>(ap, X + (size_t)t * NN * 64, Y + (size_t)t * NN * 64,
                    64, n0, 0, smraw, tid);
}

__global__ __launch_bounds__(256, 2) void diffuse1_kernel(const bf16* __restrict__ adjb,
                                                          const bf16* __restrict__ X,
                                                          bf16* __restrict__ Y) {
  __shared__ __align__(16) char smraw[2 * DBUF * 2];
  int bid = blockIdx.x, tid = threadIdx.x;  // 256
  int n0 = (bid >> 5) * 64;
  int w = tid >> 6, lane = tid & 63, col = lane & 15, quad = lane >> 4;
  bf16x8 ap[16];
  const bf16* ar = adjb + (size_t)(n0 + w * 16 + col) * NN;
#pragma unroll
  for (int c = 0; c < 8; c++)
#pragma unroll
    for (int ki = 0; ki < 2; ki++)
      ap[c * 2 + ki] = *(const bf16x8*)(ar + c * 64 + ki * 32 + quad * 8);
  diffuse_tileP<64>(ap, X, Y, 2048, n0, (bid & 31) * 64, smraw, tid);
}

template <int C>
__global__ __launch_bounds__(256, 2) void gate_wrap(
    const bf16* xt, const bf16* xdt, const bf16* sa, const bf16* sad,
    const bf16* gWt, const float* gb, const float* state, bf16* zs, bf16* rbuf) {
  constexpr int KC = 2 * (C + HHID), KCP = (KC + 31) & ~31, PIT = KCP + 8;
  __shared__ __align__(16) unsigned short xinb[32 * PIT];
  stage_A<C>(blockIdx.x, threadIdx.x, xinb, xt, xdt, sa, sad);
  gate_mfma<C>(blockIdx.x, threadIdx.x, xinb, gWt, gb, state, zs, rbuf);
}

template <int C>
__global__ __launch_bounds__(256, 2) void upd_wrap(
    const bf16* xt, const bf16* xdt, const bf16* sa, const bf16* sad,
    const bf16* uWt, const float* ub, float* state, bf16* sb,
    const bf16* rbuf, bf16* xo) {
  constexpr int KC = 2 * (C + HHID), KCP = (KC + 31) & ~31, PIT = KCP + 8;
  __shared__ __align__(16) unsigned short xinb[32 * PIT];
  stage_A<C>(blockIdx.x, threadIdx.x, xinb, xt, xdt, sa, sad);
  upd_mfma<C>(blockIdx.x, threadIdx.x, xinb, uWt, ub, state, sb, rbuf, xo);
}

// ---------------- epilogue kernels: MFMA attention + FFN -------------------

#define TP 68  // padded fp32 row stride (conflict-free)

__global__ __launch_bounds__(256, 4) void attn1_kernel(
    const bf16* __restrict__ x1, const float* __restrict__ fsb,
    const float* __restrict__ Wq, const float* __restrict__ bq,
    const float* __restrict__ Wk, const float* __restrict__ bk,
    const float* __restrict__ Wv, const float* __restrict__ bv,
    const float* __restrict__ ln1g, const float* __restrict__ ln1b,
    bf16* __restrict__ val) {
  __shared__ bf16 WqT[4096], WkT[4096];   // [h_out][h_in] bf16 (transposed)
  __shared__ bf16 Wv_s[4096];             // [h_in][h_out]
  __shared__ bf16 Xb[16 * 72];            // [t][h] bf16, rows 12..15 zero
  __shared__ float qs[TT * TP], ks[TT * TP];
  __shared__ float A[2 * TT * TT];
  __shared__ float ovv[64], fss[TT];
  __shared__ float bqs[64], bks[64], bvs[64], g1s[64], b1s[64];
  int tid = threadIdx.x;
  int w = tid >> 6, lane = tid & 63, col = lane & 15, quad = lane >> 4;
  // transposed weight staging: coalesced global read, LDS scatter (once)
#pragma unroll
  for (int i = 0; i < 16; i++) {
    int e = tid * 16 + i;
    int hi = e >> 6, ho = e & 63;
    WqT[ho * 64 + hi] = __float2bfloat16(Wq[e]);
    WkT[ho * 64 + hi] = __float2bfloat16(Wk[e]);
  }
  for (int i = tid; i < 4096; i += 256) Wv_s[i] = __float2bfloat16(Wv[i]);
  for (int i = tid; i < 16 * 72; i += 256) Xb[i] = __float2bfloat16(0.f);
  if (tid < 64) {
    bqs[tid] = bq[tid]; bks[tid] = bk[tid]; bvs[tid] = bv[tid];
    g1s[tid] = ln1g[tid]; b1s[tid] = ln1b[tid];
  }
  __syncthreads();
  for (int g = 0; g < 8; g++) {
    int p = blockIdx.x * 8 + g;
    int b = p >> 9, n = p & 511;
    for (int i = tid; i < TT * 64; i += 256) {
      int t = i >> 6, j = i & 63;
      Xb[t * 72 + j] = x1[(((size_t)t * NN + n) * BBATCH + b) * HHID + j];
    }
    if (tid < TT) fss[tid] = fsb[n * TT + tid];
    __syncthreads();
    // q/k projections via MFMA: [16x64] @ [64x64], wave w owns col-tile w
    {
      f32x4 aq = (f32x4){0.f, 0.f, 0.f, 0.f};
      f32x4 ak = (f32x4){0.f, 0.f, 0.f, 0.f};
#pragma unroll
      for (int ki = 0; ki < 2; ki++) {
        bf16x8 af = *(const bf16x8*)&Xb[col * 72 + ki * 32 + quad * 8];
        bf16x8 bqf = *(const bf16x8*)&WqT[(w * 16 + col) * 64 + ki * 32 + quad * 8];
        bf16x8 bkf = *(const bf16x8*)&WkT[(w * 16 + col) * 64 + ki * 32 + quad * 8];
        aq = __builtin_amdgcn_mfma_f32_16x16x32_bf16(af, bqf, aq, 0, 0, 0);
        ak = __builtin_amdgcn_mfma_f32_16x16x32_bf16(af, bkf, ak, 0, 0, 0);
      }
#pragma unroll
      for (int r = 0; r < 4; r++) {
        int t = quad * 4 + r;
        if (t < TT) {
          int h = w * 16 + col;
          qs[t * TP + h] = aq[r] + bqs[h];
          ks[t * TP + h] = ak[r] + bks[h];
        }
      }
    }
    if (tid < 64) {  // v projection: only last hidden row matters
      float s = 0.f;
#pragma unroll 8
      for (int j = 0; j < 64; j++)
        s += B2F(Xb[11 * 72 + j]) * B2F(Wv_s[j * 64 + tid]);
      ovv[tid] = s;
    }
    __syncthreads();
    for (int i = tid; i < 2 * TT * TT; i += 256) {
      int hd = i / (TT * TT), ts = i % (TT * TT), t = ts / TT, s = ts % TT;
      float acc = 0.f;
#pragma unroll
      for (int d = 0; d < 32; d++) acc += qs[t * TP + hd * 32 + d] * ks[s * TP + hd * 32 + d];
      A[i] = acc * 0.17677669529663687f;
    }
    __syncthreads();
    if (tid < 2 * TT) {
      int hd = tid / TT, t = tid % TT;
      float* row = &A[hd * TT * TT + t * TT];
      float m = row[0];
      for (int s = 1; s < TT; s++) m = fmaxf(m, row[s]);
      float sm = 0.f;
      for (int s = 0; s < TT; s++) { float e = expf(row[s] - m); row[s] = e; sm += e; }
      float inv = 1.0f / sm;
      for (int s = 0; s < TT; s++) row[s] *= inv;
    }
    __syncthreads();
#pragma unroll
    for (int it = 0; it < 3; it++) {
      int i = it * 256 + tid;
      int t = i >> 6, h = i & 63, hd = h >> 5;
      float afs = 0.f;
#pragma unroll
      for (int s = 0; s < TT; s++) afs += A[hd * TT * TT + t * TT + s] * fss[s];
      float o = ovv[h] * afs + bvs[h];
      float x = o + B2F(Xb[t * 72 + h]);
      float mu = wsum(x) * (1.0f / 64.0f);
      float d = x - mu;
      float var = wsum(d * d) * (1.0f / 64.0f);
      float v = d * rsqrtf(var + 1e-5f) * g1s[h] + b1s[h];
      val[((size_t)(b * TT + t) * NN + n) * HHID + h] = __float2bfloat16(v);
    }
    __syncthreads();
  }
}

__global__ __launch_bounds__(256, 4) void ffn_kernel(
    const bf16* __restrict__ val, const float* __restrict__ W1, const float* __restrict__ b1,
    const float* __restrict__ W2, const float* __restrict__ b2,
    const float* __restrict__ ln2g, const float* __restrict__ ln2b,
    const float* __restrict__ fcW, const float* __restrict__ fcb,
    float* __restrict__ out, int rows_per_block) {
  __shared__ bf16 W1T[4096], W2T[4096];   // [h_out][h_in] bf16
  __shared__ bf16 Ab[16 * 72];            // 16 input rows bf16
  __shared__ bf16 Hh[16 * 72], Hl[16 * 72];  // hidden hi/lo split
  __shared__ float fout[16 * 68];
  __shared__ float b1s[64], b2s[64], g2s[64], bb2[64], fcs[64];
  int tid = threadIdx.x;
  int w = tid >> 6, lane = tid & 63, col = lane & 15, quad = lane >> 4;
#pragma unroll
  for (int i = 0; i < 16; i++) {
    int e = tid * 16 + i;
    int hi = e >> 6, ho = e & 63;
    W1T[ho * 64 + hi] = __float2bfloat16(W1[e]);
    W2T[ho * 64 + hi] = __float2bfloat16(W2[e]);
  }
  if (tid < 64) {
    b1s[tid] = b1[tid]; b2s[tid] = b2[tid];
    g2s[tid] = ln2g[tid]; bb2[tid] = ln2b[tid]; fcs[tid] = fcW[tid];
  }
  __syncthreads();
  float fcbv = fcb[0];
  for (int c0 = 0; c0 < rows_per_block; c0 += 16) {
    size_t r0 = (size_t)blockIdx.x * rows_per_block + c0;
    for (int i = tid; i < 1024; i += 256) {
      int rr = i >> 6, j = i & 63;
      Ab[rr * 72 + j] = val[(r0 + rr) * 64 + j];
    }
    __syncthreads();
    // layer 1: h = relu(A @ W1 + b1), split to bf16 hi+lo
    {
      f32x4 a1 = (f32x4){0.f, 0.f, 0.f, 0.f};
#pragma unroll
      for (int ki = 0; ki < 2; ki++) {
        bf16x8 af = *(const bf16x8*)&Ab[col * 72 + ki * 32 + quad * 8];
        bf16x8 bf1 = *(const bf16x8*)&W1T[(w * 16 + col) * 64 + ki * 32 + quad * 8];
        a1 = __builtin_amdgcn_mfma_f32_16x16x32_bf16(af, bf1, a1, 0, 0, 0);
      }
#pragma unroll
      for (int r = 0; r < 4; r++) {
        int m = quad * 4 + r, h = w * 16 + col;
        float hv = fmaxf(a1[r] + b1s[h], 0.0f);
        bf16 hb = __float2bfloat16(hv);
        float lo = hv - B2F(hb);
        Hh[m * 72 + h] = hb;
        Hl[m * 72 + h] = __float2bfloat16(lo);
      }
    }
    __syncthreads();
    // layer 2: f = (Hh + Hl) @ W2 + b2 + residual
    {
      f32x4 a2 = (f32x4){0.f, 0.f, 0.f, 0.f};
#pragma unroll
      for (int ki = 0; ki < 2; ki++) {
        bf16x8 ah = *(const bf16x8*)&Hh[col * 72 + ki * 32 + quad * 8];
        bf16x8 al = *(const bf16x8*)&Hl[col * 72 + ki * 32 + quad * 8];
        bf16x8 bf2 = *(const bf16x8*)&W2T[(w * 16 + col) * 64 + ki * 32 + quad * 8];
        a2 = __builtin_amdgcn_mfma_f32_16x16x32_bf16(ah, bf2, a2, 0, 0, 0);
        a2 = __builtin_amdgcn_mfma_f32_16x16x32_bf16(al, bf2, a2, 0, 0, 0);
      }
#pragma unroll
      for (int r = 0; r < 4; r++) {
        int m = quad * 4 + r, h = w * 16 + col;
        fout[m * 68 + h] = a2[r] + b2s[h] + B2F(Ab[m * 72 + h]);
      }
    }
    __syncthreads();
    // LN + fc per row: wave w handles rows {w, w+4, w+8, w+12}
#pragma unroll
    for (int p4 = 0; p4 < 4; p4++) {
      int m = p4 * 4 + w;
      float y = fout[m * 68 + lane];
      float mu = wsum(y) * (1.0f / 64.0f);
      float d = y - mu;
      float var = wsum(d * d) * (1.0f / 64.0f);
      float oh = d * rsqrtf(var + 1e-5f) * g2s[lane] + bb2[lane];
      float contrib = wsum(oh * fcs[lane]);
      if (lane == 0) out[r0 + m] = contrib + fcbv;
    }
    __syncthreads();
  }
}

extern "C" void kernel_launch(void* const* d_in, const int* in_sizes, int n_in,
                              void* d_out, int out_size, void* d_ws, size_t ws_size,
                              hipStream_t stream) {
  const float* src = (const float*)d_in[0];
  const float* emb = (const float*)d_in[2];
  const float* gwp[2] = {(const float*)d_in[3], (const float*)d_in[7]};
  const float* gbp[2] = {(const float*)d_in[4], (const float*)d_in[8]};
  const float* uwp[2] = {(const float*)d_in[5], (const float*)d_in[9]};
  const float* ubp[2] = {(const float*)d_in[6], (const float*)d_in[10]};
  const float* hypW = (const float*)d_in[11];
  const float* hypb = (const float*)d_in[12];
  const float *Wq, *Wk, *Wv, *ffW1, *ffW2, *bq, *bk, *bv, *ffb1, *ffb2;
  const float *ln1g, *ln1b, *ln2g, *ln2b, *fcW, *fcb;
  if (in_sizes[14] == 4096) {
    Wq = (const float*)d_in[13]; Wk = (const float*)d_in[14]; Wv = (const float*)d_in[15];
    ffW1 = (const float*)d_in[16]; ffW2 = (const float*)d_in[17];
    bq = (const float*)d_in[18]; bk = (const float*)d_in[19]; bv = (const float*)d_in[20];
    ffb1 = (const float*)d_in[21]; ffb2 = (const float*)d_in[22];
    ln1g = (const float*)d_in[23]; ln1b = (const float*)d_in[24];
    ln2g = (const float*)d_in[25]; ln2b = (const float*)d_in[26];
    fcW = (const float*)d_in[27]; fcb = (const float*)d_in[28];
  } else {
    Wq = (const float*)d_in[13]; bq = (const float*)d_in[14];
    Wk = (const float*)d_in[15]; bk = (const float*)d_in[16];
    Wv = (const float*)d_in[17]; bv = (const float*)d_in[18];
    ln1g = (const float*)d_in[19]; ln1b = (const float*)d_in[20];
    ffW1 = (const float*)d_in[21]; ffb1 = (const float*)d_in[22];
    ffW2 = (const float*)d_in[23]; ffb2 = (const float*)d_in[24];
    ln2g = (const float*)d_in[25]; ln2b = (const float*)d_in[26];
    fcW = (const float*)d_in[27]; fcb = (const float*)d_in[28];
  }
  float* outp = (float*)d_out;

  char* ws = (char*)d_ws;
  size_t off = 0;
  auto alloc = [&](size_t bytes) {
    void* p = ws + off;
    off += (bytes + 255) & ~(size_t)255;
    return p;
  };
  bf16* adjb = (bf16*)alloc((size_t)512 * 512 * 2);
  bf16* gWb = (bf16*)alloc((size_t)512 * 32768 * 2);
  bf16* uWb = (bf16*)alloc((size_t)512 * 16384 * 2);
  float* gb = (float*)alloc((size_t)512 * 128 * 4);
  float* ub = (float*)alloc((size_t)512 * 64 * 4);
  bf16* xin0 = (bf16*)alloc((size_t)12 * 512 * 32 * 2 * 2);
  bf16* x0 = (bf16*)alloc((size_t)12 * 512 * 32 * 64 * 2);
  bf16* xd0 = (bf16*)alloc((size_t)12 * 512 * 32 * 2 * 2);
  bf16* xdL1 = (bf16*)alloc((size_t)512 * 32 * 64 * 2);
  float* state = (float*)alloc((size_t)512 * 32 * 64 * 4);
  bf16* sb = (bf16*)alloc((size_t)512 * 32 * 64 * 2);
  bf16* sdiff = (bf16*)alloc((size_t)512 * 32 * 64 * 2);
  bf16* zs = (bf16*)alloc((size_t)512 * 32 * 64 * 2);
  bf16* zsdiff = (bf16*)alloc((size_t)512 * 32 * 64 * 2);
  bf16* rbuf = (bf16*)alloc((size_t)512 * 32 * 64 * 2);
  float* PW = (float*)alloc((size_t)16 * 48 * 4);
  float* fsb = (float*)alloc((size_t)512 * 12 * 4);
  unsigned* bar = (unsigned*)alloc((size_t)544 * 4);
  bf16* val = gWb;

  adj_kernel<<<512, 256, 0, stream>>>(emb, adjb);
  pw_kernel<<<dim3(48, 16), 256, 0, stream>>>(uwp[1], hypW, PW);
  fs_kernel<<<24, 256, 0, stream>>>(emb, PW, hypb, fsb);
  cvt_src_kernel<<<1536, 256, 0, stream>>>(src, xin0);

  int occ0 = 0, occ1 = 0;
  hipOccupancyMaxActiveBlocksPerMultiprocessor(&occ0, recur_kernel<2>, 256, 0);
  hipOccupancyMaxActiveBlocksPerMultiprocessor(&occ1, recur_kernel<64>, 256, 0);

  for (int l = 0; l < 2; l++) {
    int C = (l == 0) ? 2 : 64;
    int KC = 2 * (C + 64);
    int KCP = (KC + 31) & ~31;  // 160 or 256
    int JG = KC * 128, JU = KC * 64;
    // coalesced wgen_t writes the full padded region incl. zeros
    wgen_t_kernel<<<dim3(KCP * 128 / 256, 4), 256, 0, stream>>>(
        gwp[l], emb, gWb, JG, 128, KCP, KC);
    wgen_t_kernel<<<dim3(KCP * 64 / 256, 4), 256, 0, stream>>>(
        uwp[l], emb, uWb, JU, 64, KCP, KC);
    wgen_kernel<<<dim3(1, 4), 256, 0, stream>>>(gbp[l], emb, gb, 128);
    wgen_kernel<<<dim3(1, 4), 256, 0, stream>>>(ubp[l], emb, ub, 64);
    zero_f32_kernel<<<3, 256, 0, stream>>>((float*)bar, 544);

    const bf16* xin = (l == 0) ? xin0 : x0;
    bf16* xd = (l == 0) ? xd0 : xdL1;
    int occ = (l == 0) ? occ0 : occ1;
    hipError_t ce = hipErrorInvalidValue;
    if (occ >= 2) {
      void* args[12];
      args[0] = &adjb; args[1] = &xin; args[2] = &gWb; args[3] = &gb;
      args[4] = &uWb; args[5] = &ub; args[6] = &zs; args[7] = &sdiff;
      args[8] = &zsdiff; args[9] = &xd; args[10] = &x0; args[11] = &bar;
      if (l == 0)
        ce = hipLaunchCooperativeKernel(reinterpret_cast<void*>(recur_kernel<2>),
                                        dim3(512), dim3(256), args, 0, stream);
      else
        ce = hipLaunchCooperativeKernel(reinterpret_cast<void*>(recur_kernel<64>),
                                        dim3(512), dim3(256), args, 0, stream);
    }
    if (ce != hipSuccess) {
      (void)hipGetLastError();
      zero_f32_kernel<<<4096, 256, 0, stream>>>(state, 512 * 32 * 64);
      zero_f32_kernel<<<2048, 256, 0, stream>>>((float*)sb, 512 * 32 * 64 / 2);
      if (l == 0) diffuse0_kernel<<<96, 256, 0, stream>>>(adjb, xin, xd);
      for (int t = 0; t < 12; t++) {
        const bf16* xt = xin + (size_t)t * 512 * 32 * C;
        const bf16* xdt = (l == 0) ? (xd + (size_t)t * 512 * 32 * C) : xd;
        bf16* xo = x0 + (size_t)t * 512 * 32 * 64;
        if (l == 1) diffuse1_kernel<<<256, 256, 0, stream>>>(adjb, xt, xd);
        diffuse1_kernel<<<256, 256, 0, stream>>>(adjb, sb, sdiff);
        if (l == 0)
          gate_wrap<2><<<512, 256, 0, stream>>>(xt, xdt, sb, sdiff, gWb, gb, state, zs, rbuf);
        else
          gate_wrap<64><<<512, 256, 0, stream>>>(xt, xdt, sb, sdiff, gWb, gb, state, zs, rbuf);
        diffuse1_kernel<<<256, 256, 0, stream>>>(adjb, zs, zsdiff);
        if (l == 0)
          upd_wrap<2><<<512, 256, 0, stream>>>(xt, xdt, zs, zsdiff, uWb, ub, state, sb, rbuf, xo);
        else
          upd_wrap<64><<<512, 256, 0, stream>>>(xt, xdt, zs, zsdiff, uWb, ub, state, sb, rbuf, xo);
      }
    }
  }

  attn1_kernel<<<2048, 256, 0, stream>>>(x0, fsb, Wq, bq, Wk, bk, Wv, bv, ln1g, ln1b, val);
  ffn_kernel<<<2048, 256, 0, stream>>>(val, ffW1, ffb1, ffW2, ffb2, ln2g, ln2b, fcW, fcb,
                                       outp, 96);
}

// Round 7
// 1650.679 us; speedup vs baseline: 1.2348x; 1.0005x over previous
//
#include <hip/hip_runtime.h>
#include <hip/hip_bf16.h>

// MAGCRN on MI355X — round 17: GRAPH-CAPTURABLE PERSISTENT RECUR LAUNCH.
//  * Round-16 forensics: steady-state profiled recur is <57us/dispatch but
//    wall stayed 1651us, and wall has only ever responded to fallback-shared
//    changes -> hipLaunchCooperativeKernel fails under graph capture, so the
//    TIMED path was running the ~110-launch fallback while rocprof ran the
//    fast cooperative kernel.
//  * Fix: plain <<<512,256>>> launch (graph-capturable). Co-residency holds:
//    __launch_bounds__(256,2) verified occ>=2 -> 512 blocks <= 1024 slots on
//    an idle device (graph deps serialize nodes). Kernel/barrier/fallback
//    byte-identical to round 16 (passed).

using bf16 = __hip_bfloat16;
#define B2F(x) __bfloat162float(x)

#define NN 512
#define BBATCH 32
#define HHID 64
#define TT 12
#define EE 16

typedef __attribute__((ext_vector_type(4))) float f32x4;
typedef __attribute__((ext_vector_type(8))) short bf16x8;

__device__ inline float wsum(float x) {
#pragma unroll
  for (int off = 32; off > 0; off >>= 1) x += __shfl_xor(x, off, 64);
  return x;
}

// ---------------- LLC-coherent access helpers ------------------------------
__device__ inline uint4 llc_load4(const void* p) {
  uint4 r;
  asm volatile("global_load_dwordx4 %0, %1, off sc0 sc1" : "=v"(r) : "v"(p));
  return r;
}
__device__ inline uint2 llc_load2(const void* p) {
  uint2 r;
  asm volatile("global_load_dwordx2 %0, %1, off sc0 sc1" : "=v"(r) : "v"(p));
  return r;
}
__device__ inline unsigned llc_load1(const void* p) {
  unsigned r;
  asm volatile("global_load_dword %0, %1, off sc0 sc1" : "=v"(r) : "v"(p));
  return r;
}
__device__ inline void llc_store_bf(void* p, unsigned short v) {
  asm volatile("global_store_short %0, %1, off sc0 sc1" :: "v"(p), "v"((unsigned)v) : "memory");
}
__device__ inline void llc_store_u1(void* p, unsigned v) {
  asm volatile("global_store_dword %0, %1, off sc0 sc1" :: "v"(p), "v"(v) : "memory");
}
template <int N> __device__ inline void wait_vmcnt() {
  if constexpr (N == 0) asm volatile("s_waitcnt vmcnt(0)" ::: "memory");
  else if constexpr (N == 1) asm volatile("s_waitcnt vmcnt(1)" ::: "memory");
  else if constexpr (N == 2) asm volatile("s_waitcnt vmcnt(2)" ::: "memory");
  else asm volatile("s_waitcnt vmcnt(4)" ::: "memory");
}

// LDS-only barrier: waits DS ops, leaves global loads in flight.
__device__ inline void lds_barrier() {
  asm volatile("s_waitcnt lgkmcnt(0)" ::: "memory");
  __builtin_amdgcn_s_barrier();
  asm volatile("" ::: "memory");
}

// ---------------- grid barrier: fenceless flags + master + epoch -----------
__device__ inline void gbar(unsigned* __restrict__ bar, int& cnt) {
  cnt++;
  __syncthreads();  // drains vmcnt(0): all sc stores are at the LLC
  unsigned tgt = (unsigned)cnt;
  unsigned* flags = bar + 32;
  if (blockIdx.x == 0) {
    if (threadIdx.x < 64) {
      if (threadIdx.x == 0) llc_store_u1(flags, tgt);
      const unsigned* fp = flags + threadIdx.x * 8;
      bool ok;
      do {
        unsigned v0 = llc_load1(fp + 0), v1 = llc_load1(fp + 1),
                 v2 = llc_load1(fp + 2), v3 = llc_load1(fp + 3),
                 v4 = llc_load1(fp + 4), v5 = llc_load1(fp + 5),
                 v6 = llc_load1(fp + 6), v7 = llc_load1(fp + 7);
        wait_vmcnt<0>();
        __builtin_amdgcn_sched_barrier(0);
        ok = ((int)(v0 - tgt) >= 0) && ((int)(v1 - tgt) >= 0) &&
             ((int)(v2 - tgt) >= 0) && ((int)(v3 - tgt) >= 0) &&
             ((int)(v4 - tgt) >= 0) && ((int)(v5 - tgt) >= 0) &&
             ((int)(v6 - tgt) >= 0) && ((int)(v7 - tgt) >= 0);
      } while (!__all(ok));
      if (threadIdx.x == 0) llc_store_u1(bar, tgt);
    }
  } else if (threadIdx.x == 0) {
    llc_store_u1(flags + blockIdx.x, tgt);
    for (;;) {
      unsigned e = llc_load1(bar);
      wait_vmcnt<0>();
      __builtin_amdgcn_sched_barrier(0);
      if ((int)(e - tgt) >= 0) break;
      __builtin_amdgcn_s_sleep(2);
    }
  }
  __syncthreads();
}

__global__ __launch_bounds__(256) void zero_f32_kernel(float* __restrict__ p, int n) {
  int i = blockIdx.x * 256 + threadIdx.x;
  if (i < n) p[i] = 0.0f;
}

// ---------------- setup kernels ----------------

__global__ __launch_bounds__(256) void adj_kernel(const float* __restrict__ emb,
                                                  bf16* __restrict__ adjb) {
  __shared__ float embAll[NN * EE];
  __shared__ float red[256];
  int tid = threadIdx.x, n = blockIdx.x;
  for (int i = tid; i < NN * EE; i += 256) embAll[i] = emb[i];
  __syncthreads();
  float v[2];
#pragma unroll
  for (int j = 0; j < 2; j++) {
    int m = tid + j * 256;
    float s = 0.f;
#pragma unroll
    for (int e = 0; e < EE; e++) s += embAll[n * EE + e] * embAll[m * EE + e];
    v[j] = fmaxf(s, 0.0f);
  }
  float mx = fmaxf(v[0], v[1]);
  red[tid] = mx; __syncthreads();
  for (int s = 128; s > 0; s >>= 1) { if (tid < s) red[tid] = fmaxf(red[tid], red[tid + s]); __syncthreads(); }
  mx = red[0]; __syncthreads();
  float e0 = expf(v[0] - mx), e1 = expf(v[1] - mx);
  red[tid] = e0 + e1; __syncthreads();
  for (int s = 128; s > 0; s >>= 1) { if (tid < s) red[tid] += red[tid + s]; __syncthreads(); }
  float inv = 1.0f / red[0];
  adjb[n * NN + tid] = __float2bfloat16(e0 * inv);
  adjb[n * NN + tid + 256] = __float2bfloat16(e1 * inv);
}

__global__ __launch_bounds__(256) void wgen_kernel(const float* __restrict__ pool,
                                                   const float* __restrict__ emb,
                                                   float* __restrict__ out, int J) {
  __shared__ float embL[128 * EE];
  int tid = threadIdx.x;
  int n0 = blockIdx.y * 128;
  for (int i = tid; i < 128 * EE; i += 256) embL[i] = emb[n0 * EE + i];
  __syncthreads();
  int j = blockIdx.x * 256 + tid;
  if (j >= J) return;
  float pw[EE];
#pragma unroll
  for (int e = 0; e < EE; e++) pw[e] = pool[e * J + j];
#pragma unroll 4
  for (int nn = 0; nn < 128; nn++) {
    float s = 0.f;
#pragma unroll
    for (int e = 0; e < EE; e++) s += embL[nn * EE + e] * pw[e];
    out[(size_t)(n0 + nn) * J + j] = s;
  }
}

// coalesced transposed weight generator: thread p = output position
// out[n][p], p = o*KCP + kc; value from pool col j = kc*O + o; pad -> 0.
__global__ __launch_bounds__(256) void wgen_t_kernel(const float* __restrict__ pool,
                                                     const float* __restrict__ emb,
                                                     bf16* __restrict__ out, int J,
                                                     int O, int KCP, int KC) {
  __shared__ float embL[128 * EE];
  int tid = threadIdx.x;
  int n0 = blockIdx.y * 128;
  for (int i = tid; i < 128 * EE; i += 256) embL[i] = emb[n0 * EE + i];
  __syncthreads();
  int p = blockIdx.x * 256 + tid;
  unsigned kc = (unsigned)p % (unsigned)KCP;
  unsigned o = (unsigned)p / (unsigned)KCP;
  size_t P = (size_t)KCP * O;
  if (kc >= (unsigned)KC) {
    bf16 z = __float2bfloat16(0.f);
    for (int nn = 0; nn < 128; nn++) out[(size_t)(n0 + nn) * P + p] = z;
    return;
  }
  int jp = (int)kc * O + (int)o;
  float pw[EE];
#pragma unroll
  for (int e = 0; e < EE; e++) pw[e] = pool[e * J + jp];
#pragma unroll 4
  for (int nn = 0; nn < 128; nn++) {
    float s = 0.f;
#pragma unroll
    for (int e = 0; e < EE; e++) s += embL[nn * EE + e] * pw[e];
    out[(size_t)(n0 + nn) * P + p] = __float2bfloat16(s);
  }
}

__global__ __launch_bounds__(256) void pw_kernel(const float* __restrict__ upool,
                                                 const float* __restrict__ hypW,
                                                 float* __restrict__ PW) {
  __shared__ float red[256];
  int j = blockIdx.x, e = blockIdx.y, tid = threadIdx.x;
  float s = 0.f;
#pragma unroll 4
  for (int p = tid; p < 16384; p += 256) s += upool[e * 16384 + p] * hypW[p * 48 + j];
  red[tid] = s; __syncthreads();
  for (int t = 128; t > 0; t >>= 1) { if (tid < t) red[tid] += red[tid + t]; __syncthreads(); }
  if (tid == 0) PW[e * 48 + j] = red[0];
}

__global__ __launch_bounds__(256) void fs_kernel(const float* __restrict__ emb,
                                                 const float* __restrict__ PW,
                                                 const float* __restrict__ hypb,
                                                 float* __restrict__ fs) {
  int id = blockIdx.x * 256 + threadIdx.x;
  if (id >= NN * TT) return;
  int n = id / TT, t = id % TT;
  float s = 0.f;
#pragma unroll
  for (int f = 0; f < 4; f++) {
    int j = t * 4 + f;
    float h = hypb[j];
#pragma unroll
    for (int e = 0; e < EE; e++) h += emb[n * EE + e] * PW[e * 48 + j];
    s += h;
  }
  fs[id] = s;
}

__global__ __launch_bounds__(256) void cvt_src_kernel(const float* __restrict__ src,
                                                      bf16* __restrict__ x) {
  int id = blockIdx.x * 256 + threadIdx.x;  // < 393216
  int c = id & 1, b = (id >> 1) & 31, n = (id >> 6) & 511, t = id >> 15;
  x[id] = __float2bfloat16(src[((b * TT + t) * NN + n) * 2 + c]);
}

// ---------------- diffusion: pipelined, LLC-coherent, counted waits --------
#define DBUF 4672

__device__ inline void xsT_wr8(unsigned short* xsT, int base, int q0l, int k, uint4 v) {
  union { uint4 u; unsigned short h[8]; } cv; cv.u = v;
#pragma unroll
  for (int qq = 0; qq < 8; qq++) {
    int q = q0l + qq;
    xsT[base + q * 72 + (q >> 3) * 8 + k] = cv.h[qq];
  }
}

template <int QW>
__device__ inline void diffuse_tileP(const bf16x8* __restrict__ apre,
                                     const bf16* __restrict__ X, bf16* __restrict__ Y,
                                     int Q, int n0, int q0, char* smraw, int tid) {
  constexpr int LPC = QW / 32;
  constexpr int NCT = QW / 16;
  unsigned short* xsT = (unsigned short*)smraw;
  int w = tid >> 6, lane = tid & 63;
  int col = lane & 15, quad = lane >> 4;
  int kr, ql;
  if constexpr (QW == 64) { kr = tid >> 3; ql = (tid & 7) * 8; }
  else                    { kr = tid >> 2; ql = (tid & 3) * 8; }
  f32x4 acc[NCT];
#pragma unroll
  for (int ct = 0; ct < NCT; ct++) acc[ct] = (f32x4){0.f, 0.f, 0.f, 0.f};
  const bf16* Xb = X + q0 + ql;
  uint4 pre[3][LPC];
#pragma unroll
  for (int d = 0; d < 3; d++) {
    pre[d][0] = llc_load4(Xb + (size_t)(d * 64 + kr) * Q);
    if constexpr (QW == 64)
      pre[d][1] = llc_load4(Xb + (size_t)(d * 64 + 32 + kr) * Q);
  }
  wait_vmcnt<2 * LPC>();
  xsT_wr8(xsT, 0, ql, kr, pre[0][0]);
  if constexpr (QW == 64) xsT_wr8(xsT, 0, ql, 32 + kr, pre[0][1]);
  pre[0][0] = llc_load4(Xb + (size_t)(3 * 64 + kr) * Q);
  if constexpr (QW == 64)
    pre[0][1] = llc_load4(Xb + (size_t)(3 * 64 + 32 + kr) * Q);
  lds_barrier();
#pragma unroll
  for (int c = 0; c < 8; c++) {
    int sl = (c + 1) % 3;
    if (c < 7) {
      if (c < 5) wait_vmcnt<2 * LPC>();
      else if (c == 5) wait_vmcnt<LPC>();
      else wait_vmcnt<0>();
      int nb = ((c + 1) & 1) * DBUF;
      xsT_wr8(xsT, nb, ql, kr, pre[sl][0]);
      if constexpr (QW == 64) xsT_wr8(xsT, nb, ql, 32 + kr, pre[sl][1]);
    }
    int base = (c & 1) * DBUF;
#pragma unroll
    for (int ki = 0; ki < 2; ki++) {
      bf16x8 a = apre[c * 2 + ki];
#pragma unroll
      for (int ct = 0; ct < NCT; ct++) {
        int q = ct * 16 + col;
        bf16x8 b = *(const bf16x8*)&xsT[base + q * 72 + (q >> 3) * 8 + ki * 32 + quad * 8];
        acc[ct] = __builtin_amdgcn_mfma_f32_16x16x32_bf16(a, b, acc[ct], 0, 0, 0);
      }
    }
    if (c + 4 < 8) {
      pre[sl][0] = llc_load4(Xb + (size_t)((c + 4) * 64 + kr) * Q);
      if constexpr (QW == 64)
        pre[sl][1] = llc_load4(Xb + (size_t)((c + 4) * 64 + 32 + kr) * Q);
    }
    lds_barrier();
  }
#pragma unroll
  for (int ct = 0; ct < NCT; ct++)
#pragma unroll
    for (int r = 0; r < 4; r++) {
      int row = n0 + w * 16 + quad * 4 + r;
      bf16 hb = __float2bfloat16(acc[ct][r]);
      llc_store_bf(Y + (size_t)row * Q + q0 + ct * 16 + col, *(unsigned short*)&hb);
    }
}

// ---------------- fallback-path shared functions ---------------------------

template <int C>
__device__ inline void stage_A(int n, int tid, unsigned short* xinb,
    const bf16* __restrict__ xt, const bf16* __restrict__ xd,
    const bf16* __restrict__ sa, const bf16* __restrict__ sad) {
  constexpr int cc = C + HHID, KC = 2 * cc, KCP = (KC + 31) & ~31, PIT = KCP + 8;
  __syncthreads();
  for (int i = tid; i < 32 * KCP; i += 256) {
    int b = i / KCP, kc = i - b * KCP;
    unsigned short v = 0;
    if (kc < C)            v = *(const unsigned short*)&xt[(n * 32 + b) * C + kc];
    else if (kc < cc)      v = *(const unsigned short*)&sa[(n * 32 + b) * HHID + kc - C];
    else if (kc < cc + C)  v = *(const unsigned short*)&xd[(n * 32 + b) * C + kc - cc];
    else if (kc < KC)      v = *(const unsigned short*)&sad[(n * 32 + b) * HHID + kc - cc - C];
    xinb[b * PIT + kc] = v;
  }
  __syncthreads();
}

template <int C>
__device__ inline void gate_epilogue(int n, int w, int col, int quad,
    f32x4 acc[2][2], const float* __restrict__ gb, const float* __restrict__ state,
    bf16* __restrict__ zs, bf16* __restrict__ rbuf) {
#pragma unroll
  for (int i = 0; i < 2; i++) {
    int o = (w + i * 4) * 16 + col;
    float bv = gb[n * 128 + o];
#pragma unroll
    for (int mt = 0; mt < 2; mt++)
#pragma unroll
      for (int r = 0; r < 4; r++) {
        int m = mt * 16 + quad * 4 + r;
        float zr = 1.0f / (1.0f + expf(-(acc[i][mt][r] + bv)));
        int idx = (n * 32 + m) * HHID + (o & 63);
        if (o < HHID) zs[idx] = __float2bfloat16(zr * state[idx]);
        else          rbuf[idx] = __float2bfloat16(zr);
      }
  }
}

template <int C>
__device__ inline void upd_epilogue(int n, int w, int col, int quad,
    f32x4 acc[2], const float* __restrict__ ub, float* __restrict__ state,
    bf16* __restrict__ sb, const bf16* __restrict__ rbuf, bf16* __restrict__ xo) {
  int o = w * 16 + col;
  float bv = ub[n * 64 + o];
#pragma unroll
  for (int mt = 0; mt < 2; mt++)
#pragma unroll
    for (int r = 0; r < 4; r++) {
      int m = mt * 16 + quad * 4 + r;
      int idx = (n * 32 + m) * HHID + o;
      float hc = tanhf(acc[mt][r] + bv);
      float rr = B2F(rbuf[idx]);
      float st = state[idx];
      float h = rr * st + (1.0f - rr) * hc;
      state[idx] = h;
      bf16 hb = __float2bfloat16(h);
      sb[idx] = hb;
      xo[idx] = hb;
    }
}

template <int C>
__device__ inline void gate_mfma(int n, int tid, const unsigned short* xinb,
    const bf16* __restrict__ gWt, const float* __restrict__ gb,
    const float* __restrict__ state, bf16* __restrict__ zs, bf16* __restrict__ rbuf) {
  constexpr int KC = 2 * (C + HHID), KCP = (KC + 31) & ~31, PIT = KCP + 8;
  int w = tid >> 6, lane = tid & 63, col = lane & 15, quad = lane >> 4;
  f32x4 acc[2][2];
#pragma unroll
  for (int i = 0; i < 2; i++)
#pragma unroll
    for (int mt = 0; mt < 2; mt++) acc[i][mt] = (f32x4){0.f, 0.f, 0.f, 0.f};
  const bf16* Wn = gWt + (size_t)n * KCP * 128;
#pragma unroll 2
  for (int k0 = 0; k0 < KCP; k0 += 32) {
    int ko = k0 + quad * 8;
    bf16x8 a0 = *(const bf16x8*)&xinb[col * PIT + ko];
    bf16x8 a1 = *(const bf16x8*)&xinb[(16 + col) * PIT + ko];
#pragma unroll
    for (int i = 0; i < 2; i++) {
      int o = (w + i * 4) * 16 + col;
      bf16x8 bf = *(const bf16x8*)(Wn + (size_t)o * KCP + ko);
      acc[i][0] = __builtin_amdgcn_mfma_f32_16x16x32_bf16(a0, bf, acc[i][0], 0, 0, 0);
      acc[i][1] = __builtin_amdgcn_mfma_f32_16x16x32_bf16(a1, bf, acc[i][1], 0, 0, 0);
    }
  }
  gate_epilogue<C>(n, w, col, quad, acc, gb, state, zs, rbuf);
}

template <int C>
__device__ inline void upd_mfma(int n, int tid, const unsigned short* xinb,
    const bf16* __restrict__ uWt, const float* __restrict__ ub,
    float* __restrict__ state, bf16* __restrict__ sb,
    const bf16* __restrict__ rbuf, bf16* __restrict__ xo) {
  constexpr int KC = 2 * (C + HHID), KCP = (KC + 31) & ~31, PIT = KCP + 8;
  int w = tid >> 6, lane = tid & 63, col = lane & 15, quad = lane >> 4;
  f32x4 acc[2];
  acc[0] = (f32x4){0.f, 0.f, 0.f, 0.f};
  acc[1] = (f32x4){0.f, 0.f, 0.f, 0.f};
  const bf16* Wn = uWt + (size_t)n * KCP * 64;
  int o = w * 16 + col;
#pragma unroll 2
  for (int k0 = 0; k0 < KCP; k0 += 32) {
    int ko = k0 + quad * 8;
    bf16x8 a0 = *(const bf16x8*)&xinb[col * PIT + ko];
    bf16x8 a1 = *(const bf16x8*)&xinb[(16 + col) * PIT + ko];
    bf16x8 bf = *(const bf16x8*)(Wn + (size_t)o * KCP + ko);
    acc[0] = __builtin_amdgcn_mfma_f32_16x16x32_bf16(a0, bf, acc[0], 0, 0, 0);
    acc[1] = __builtin_amdgcn_mfma_f32_16x16x32_bf16(a1, bf, acc[1], 0, 0, 0);
  }
  upd_epilogue<C>(n, w, col, quad, acc, ub, state, sb, rbuf, xo);
}

// ---------------- cooperative recurrence -----------------------------------

template <int C>
__global__ __launch_bounds__(256, 2) void recur_kernel(
    const bf16* __restrict__ adjb, const bf16* __restrict__ xin,
    const bf16* __restrict__ gWt, const float* __restrict__ gb,
    const bf16* __restrict__ uWt, const float* __restrict__ ub,
    bf16* __restrict__ zs, bf16* __restrict__ sdiff, bf16* __restrict__ zsdiff,
    bf16* __restrict__ xd, bf16* __restrict__ xout, unsigned* __restrict__ bar) {
  constexpr int KC = 2 * (C + HHID), KCP = (KC + 31) & ~31, PIT = KCP + 8;
  constexpr int NK = KCP / 32;
  constexpr int QX = 32 * C;
  __shared__ __align__(16) char dsm[2 * DBUF * 2];
  __shared__ __align__(16) unsigned short xinb[32 * PIT];
  int bid = blockIdx.x, tid = threadIdx.x;   // grid is exactly 512 blocks
  int w = tid >> 6, lane = tid & 63, col = lane & 15, quad = lane >> 4;
  int bcnt = 0;

  bf16x8 apre[16];
  {
    int n0p = ((bid & 255) >> 5) * 64;
    const bf16* ar = adjb + (size_t)(n0p + w * 16 + col) * NN;
#pragma unroll
    for (int c = 0; c < 8; c++)
#pragma unroll
      for (int ki = 0; ki < 2; ki++)
        apre[c * 2 + ki] = *(const bf16x8*)(ar + c * 64 + ki * 32 + quad * 8);
  }
  bf16x8 fg[2 * NK];
  {
    const bf16* Wn = gWt + (size_t)bid * KCP * 128;
#pragma unroll
    for (int i = 0; i < 2; i++) {
      int o = (w + i * 4) * 16 + col;
#pragma unroll
      for (int kk = 0; kk < NK; kk++)
        fg[i * NK + kk] = *(const bf16x8*)(Wn + (size_t)o * KCP + kk * 32 + quad * 8);
    }
  }
  bf16x8 fu[NK];
  {
    const bf16* Wn = uWt + (size_t)bid * KCP * 64;
    int o = w * 16 + col;
#pragma unroll
    for (int kk = 0; kk < NK; kk++)
      fu[kk] = *(const bf16x8*)(Wn + (size_t)o * KCP + kk * 32 + quad * 8);
  }
  float gbv0 = gb[bid * 128 + w * 16 + col];
  float gbv1 = gb[bid * 128 + 64 + w * 16 + col];
  float ubv  = ub[bid * 64 + w * 16 + col];

  for (int i = tid; i < 32 * PIT; i += 256) xinb[i] = 0;
  __syncthreads();

  int r2 = tid >> 3, ch = tid & 7;
  uint4 vxt; unsigned sxt = 0, sxd = 0;
  if constexpr (C == 64) {
    vxt = *(const uint4*)(xin + (size_t)(bid * 32 + r2) * 64 + ch * 8);
  } else {
    if (tid < 32) sxt = *(const unsigned*)(xin + (size_t)(bid * 32 + tid) * 2);
  }

  float st[2][4], rr_[2][4];
#pragma unroll
  for (int mt = 0; mt < 2; mt++)
#pragma unroll
    for (int r4 = 0; r4 < 4; r4++) st[mt][r4] = 0.f;

  // pre-loop diffusion (uses this block's apre rows)
  if constexpr (C == 2) {
    int wg = (bid & 31) | ((bid >> 8) << 5);
    if (wg < TT)
      diffuse_tileP<64>(apre, xin + (size_t)wg * NN * QX, xd + (size_t)wg * NN * QX,
                        QX, ((bid & 255) >> 5) * 64, 0, dsm, tid);
  } else {
    if (bid >= 256)
      diffuse_tileP<64>(apre, xin, xd, 2048, ((bid & 255) >> 5) * 64,
                        (bid & 31) * 64, dsm, tid);
  }
  gbar(bar, bcnt);

  for (int t = 0; t < TT; t++) {
    const bf16* xt = xin + (size_t)t * NN * QX;
    const bf16* xdt = (C == 2) ? (xd + (size_t)t * NN * QX) : xd;
    bf16* xo = xout + (size_t)t * NN * 32 * HHID;
    if (t > 0) {
      const bf16* sbp = xout + (size_t)(t - 1) * NN * 32 * HHID;
      if constexpr (C == 64) {
        if (bid < 256)
          diffuse_tileP<64>(apre, sbp, sdiff, 2048, (bid >> 5) * 64,
                            (bid & 31) * 64, dsm, tid);
        else
          diffuse_tileP<64>(apre, xt, xd, 2048, ((bid & 255) >> 5) * 64,
                            (bid & 31) * 64, dsm, tid);
      } else {
        int cs = (bid & 31) | ((bid >> 8) << 5);
        diffuse_tileP<32>(apre, sbp, sdiff, 2048, ((bid & 255) >> 5) * 64,
                          cs * 32, dsm, tid);
      }
      gbar(bar, bcnt);
    }
    // ---- P2 stage ----
    if constexpr (C == 64) {
      *(uint4*)&xinb[r2 * PIT + ch * 8] = vxt;
      uint4 v1 = llc_load4(xdt + (size_t)(bid * 32 + r2) * 64 + ch * 8);
      uint4 v2;
      if (t > 0) v2 = llc_load4(sdiff + (size_t)(bid * 32 + r2) * 64 + ch * 8);
      wait_vmcnt<0>();
      *(uint4*)&xinb[r2 * PIT + 128 + ch * 8] = v1;
      if (t > 0) *(uint4*)&xinb[r2 * PIT + 192 + ch * 8] = v2;
    } else {
      if (tid < 32) *(unsigned*)&xinb[tid * PIT] = sxt;
      if (t == 0) {
        if (tid < 32) {
          unsigned v = llc_load1(xdt + (size_t)(bid * 32 + tid) * 2);
          wait_vmcnt<0>();
          *(unsigned*)&xinb[tid * PIT + 66] = v;
        }
      } else {
        if (tid >= 32 && tid < 64) *(unsigned*)&xinb[(tid - 32) * PIT + 66] = sxd;
        int r2a = tid >> 4, c4 = tid & 15;
        uint2 va = llc_load2(sdiff + (size_t)(bid * 32 + r2a) * 64 + c4 * 4);
        uint2 vb = llc_load2(sdiff + (size_t)(bid * 32 + 16 + r2a) * 64 + c4 * 4);
        wait_vmcnt<0>();
        *(uint2*)&xinb[r2a * PIT + 68 + c4 * 4] = va;
        *(uint2*)&xinb[(16 + r2a) * PIT + 68 + c4 * 4] = vb;
      }
    }
    __syncthreads();
    // ---- P2 gate MFMA ----
    {
      f32x4 acc[2][2];
#pragma unroll
      for (int i = 0; i < 2; i++)
#pragma unroll
        for (int mt = 0; mt < 2; mt++) acc[i][mt] = (f32x4){0.f, 0.f, 0.f, 0.f};
#pragma unroll
      for (int kk = 0; kk < NK; kk++) {
        int ko = kk * 32 + quad * 8;
        bf16x8 a0 = *(const bf16x8*)&xinb[col * PIT + ko];
        bf16x8 a1 = *(const bf16x8*)&xinb[(16 + col) * PIT + ko];
#pragma unroll
        for (int i = 0; i < 2; i++) {
          acc[i][0] = __builtin_amdgcn_mfma_f32_16x16x32_bf16(a0, fg[i * NK + kk], acc[i][0], 0, 0, 0);
          acc[i][1] = __builtin_amdgcn_mfma_f32_16x16x32_bf16(a1, fg[i * NK + kk], acc[i][1], 0, 0, 0);
        }
      }
      __syncthreads();
#pragma unroll
      for (int mt = 0; mt < 2; mt++)
#pragma unroll
        for (int r4 = 0; r4 < 4; r4++) {
          int m = mt * 16 + quad * 4 + r4;
          float z = 1.0f / (1.0f + expf(-(acc[0][mt][r4] + gbv0)));
          float rv = 1.0f / (1.0f + expf(-(acc[1][mt][r4] + gbv1)));
          rr_[mt][r4] = rv;
          bf16 zb = __float2bfloat16(z * st[mt][r4]);
          xinb[m * PIT + C + w * 16 + col] = *(unsigned short*)&zb;
          llc_store_bf(zs + (size_t)(bid * 32 + m) * 64 + w * 16 + col,
                       *(unsigned short*)&zb);
        }
    }
    if (t > 0) {
      gbar(bar, bcnt);
      {
        int cs = (bid & 31) | ((bid >> 8) << 5);
        diffuse_tileP<32>(apre, zs, zsdiff, 2048, ((bid & 255) >> 5) * 64,
                          cs * 32, dsm, tid);
      }
      gbar(bar, bcnt);
      if constexpr (C == 64) {
        uint4 v = llc_load4(zsdiff + (size_t)(bid * 32 + r2) * 64 + ch * 8);
        wait_vmcnt<0>();
        *(uint4*)&xinb[r2 * PIT + 192 + ch * 8] = v;
      } else {
        int r2a = tid >> 4, c4 = tid & 15;
        uint2 va = llc_load2(zsdiff + (size_t)(bid * 32 + r2a) * 64 + c4 * 4);
        uint2 vb = llc_load2(zsdiff + (size_t)(bid * 32 + 16 + r2a) * 64 + c4 * 4);
        wait_vmcnt<0>();
        *(uint2*)&xinb[r2a * PIT + 68 + c4 * 4] = va;
        *(uint2*)&xinb[(16 + r2a) * PIT + 68 + c4 * 4] = vb;
      }
    }
    __syncthreads();
    // ---- P4 update MFMA ----
    {
      f32x4 acc[2];
      acc[0] = (f32x4){0.f, 0.f, 0.f, 0.f};
      acc[1] = (f32x4){0.f, 0.f, 0.f, 0.f};
#pragma unroll
      for (int kk = 0; kk < NK; kk++) {
        int ko = kk * 32 + quad * 8;
        bf16x8 a0 = *(const bf16x8*)&xinb[col * PIT + ko];
        bf16x8 a1 = *(const bf16x8*)&xinb[(16 + col) * PIT + ko];
        acc[0] = __builtin_amdgcn_mfma_f32_16x16x32_bf16(a0, fu[kk], acc[0], 0, 0, 0);
        acc[1] = __builtin_amdgcn_mfma_f32_16x16x32_bf16(a1, fu[kk], acc[1], 0, 0, 0);
      }
      __syncthreads();
      if (t + 1 < TT) {
        if constexpr (C == 64) {
          vxt = *(const uint4*)(xin + (size_t)(t + 1) * NN * QX +
                                (size_t)(bid * 32 + r2) * 64 + ch * 8);
        } else {
          if (tid < 32)
            sxt = *(const unsigned*)(xin + (size_t)(t + 1) * NN * QX +
                                     (size_t)(bid * 32 + tid) * 2);
          else if (tid < 64)
            sxd = *(const unsigned*)(xd + (size_t)(t + 1) * NN * QX +
                                     (size_t)(bid * 32 + (tid - 32)) * 2);
        }
      }
#pragma unroll
      for (int mt = 0; mt < 2; mt++)
#pragma unroll
        for (int r4 = 0; r4 < 4; r4++) {
          int m = mt * 16 + quad * 4 + r4;
          float hc = tanhf(acc[mt][r4] + ubv);
          float rv = rr_[mt][r4];
          float h = rv * st[mt][r4] + (1.0f - rv) * hc;
          st[mt][r4] = h;
          bf16 hb = __float2bfloat16(h);
          xinb[m * PIT + C + w * 16 + col] = *(unsigned short*)&hb;
          llc_store_bf(xo + (size_t)(bid * 32 + m) * 64 + w * 16 + col,
                       *(unsigned short*)&hb);
        }
    }
    gbar(bar, bcnt);
  }
}

// ---------------- fallback per-phase kernels (same math) ----------------

__global__ __launch_bounds__(256, 2) void diffuse0_kernel(const bf16* __restrict__ adjb,
                                                          const bf16* __restrict__ X,
                                                          bf16* __restrict__ Y) {
  __shared__ __align__(16) char smraw[2 * DBUF * 2];
  int bid = blockIdx.x, tid = threadIdx.x;  // 96
  int t = bid >> 3, n0 = (bid & 7) * 64;
  int w = tid >> 6, lane = tid & 63, col = lane & 15, quad = lane >> 4;
  bf16x8 ap[16];
  const bf16* ar = adjb + (size_t)(n0 + w * 16 + col) * NN;
#pragma unroll
  for (int c = 0; c < 8; c++)
#pragma unroll
    for (int ki = 0; ki < 2; ki++)
      ap[c * 2 + ki] = *(const bf16x8*)(ar + c * 64 + ki * 32 + quad * 8);
  diffuse_tileP<64>(ap, X + (size_t)t * NN * 64, Y + (size_t)t * NN * 64,
                    64, n0, 0, smraw, tid);
}

__global__ __launch_bounds__(256, 2) void diffuse1_kernel(const bf16* __restrict__ adjb,
                                                          const bf16* __restrict__ X,
                                                          bf16* __restrict__ Y) {
  __shared__ __align__(16) char smraw[2 * DBUF * 2];
  int bid = blockIdx.x, tid = threadIdx.x;  // 256
  int n0 = (bid >> 5) * 64;
  int w = tid >> 6, lane = tid & 63, col = lane & 15, quad = lane >> 4;
  bf16x8 ap[16];
  const bf16* ar = adjb + (size_t)(n0 + w * 16 + col) * NN;
#pragma unroll
  for (int c = 0; c < 8; c++)
#pragma unroll
    for (int ki = 0; ki < 2; ki++)
      ap[c * 2 + ki] = *(const bf16x8*)(ar + c * 64 + ki * 32 + quad * 8);
  diffuse_tileP<64>(ap, X, Y, 2048, n0, (bid & 31) * 64, smraw, tid);
}

template <int C>
__global__ __launch_bounds__(256, 2) void gate_wrap(
    const bf16* xt, const bf16* xdt, const bf16* sa, const bf16* sad,
    const bf16* gWt, const float* gb, const float* state, bf16* zs, bf16* rbuf) {
  constexpr int KC = 2 * (C + HHID), KCP = (KC + 31) & ~31, PIT = KCP + 8;
  __shared__ __align__(16) unsigned short xinb[32 * PIT];
  stage_A<C>(blockIdx.x, threadIdx.x, xinb, xt, xdt, sa, sad);
  gate_mfma<C>(blockIdx.x, threadIdx.x, xinb, gWt, gb, state, zs, rbuf);
}

template <int C>
__global__ __launch_bounds__(256, 2) void upd_wrap(
    const bf16* xt, const bf16* xdt, const bf16* sa, const bf16* sad,
    const bf16* uWt, const float* ub, float* state, bf16* sb,
    const bf16* rbuf, bf16* xo) {
  constexpr int KC = 2 * (C + HHID), KCP = (KC + 31) & ~31, PIT = KCP + 8;
  __shared__ __align__(16) unsigned short xinb[32 * PIT];
  stage_A<C>(blockIdx.x, threadIdx.x, xinb, xt, xdt, sa, sad);
  upd_mfma<C>(blockIdx.x, threadIdx.x, xinb, uWt, ub, state, sb, rbuf, xo);
}

// ---------------- epilogue kernels: MFMA attention + FFN -------------------

#define TP 68  // padded fp32 row stride (conflict-free)

__global__ __launch_bounds__(256, 4) void attn1_kernel(
    const bf16* __restrict__ x1, const float* __restrict__ fsb,
    const float* __restrict__ Wq, const float* __restrict__ bq,
    const float* __restrict__ Wk, const float* __restrict__ bk,
    const float* __restrict__ Wv, const float* __restrict__ bv,
    const float* __restrict__ ln1g, const float* __restrict__ ln1b,
    bf16* __restrict__ val) {
  __shared__ bf16 WqT[4096], WkT[4096];   // [h_out][h_in] bf16 (transposed)
  __shared__ bf16 Wv_s[4096];             // [h_in][h_out]
  __shared__ bf16 Xb[16 * 72];            // [t][h] bf16, rows 12..15 zero
  __shared__ float qs[TT * TP], ks[TT * TP];
  __shared__ float A[2 * TT * TT];
  __shared__ float ovv[64], fss[TT];
  __shared__ float bqs[64], bks[64], bvs[64], g1s[64], b1s[64];
  int tid = threadIdx.x;
  int w = tid >> 6, lane = tid & 63, col = lane & 15, quad = lane >> 4;
  // transposed weight staging: coalesced global read, LDS scatter (once)
#pragma unroll
  for (int i = 0; i < 16; i++) {
    int e = tid * 16 + i;
    int hi = e >> 6, ho = e & 63;
    WqT[ho * 64 + hi] = __float2bfloat16(Wq[e]);
    WkT[ho * 64 + hi] = __float2bfloat16(Wk[e]);
  }
  for (int i = tid; i < 4096; i += 256) Wv_s[i] = __float2bfloat16(Wv[i]);
  for (int i = tid; i < 16 * 72; i += 256) Xb[i] = __float2bfloat16(0.f);
  if (tid < 64) {
    bqs[tid] = bq[tid]; bks[tid] = bk[tid]; bvs[tid] = bv[tid];
    g1s[tid] = ln1g[tid]; b1s[tid] = ln1b[tid];
  }
  __syncthreads();
  for (int g = 0; g < 8; g++) {
    int p = blockIdx.x * 8 + g;
    int b = p >> 9, n = p & 511;
    for (int i = tid; i < TT * 64; i += 256) {
      int t = i >> 6, j = i & 63;
      Xb[t * 72 + j] = x1[(((size_t)t * NN + n) * BBATCH + b) * HHID + j];
    }
    if (tid < TT) fss[tid] = fsb[n * TT + tid];
    __syncthreads();
    // q/k projections via MFMA: [16x64] @ [64x64], wave w owns col-tile w
    {
      f32x4 aq = (f32x4){0.f, 0.f, 0.f, 0.f};
      f32x4 ak = (f32x4){0.f, 0.f, 0.f, 0.f};
#pragma unroll
      for (int ki = 0; ki < 2; ki++) {
        bf16x8 af = *(const bf16x8*)&Xb[col * 72 + ki * 32 + quad * 8];
        bf16x8 bqf = *(const bf16x8*)&WqT[(w * 16 + col) * 64 + ki * 32 + quad * 8];
        bf16x8 bkf = *(const bf16x8*)&WkT[(w * 16 + col) * 64 + ki * 32 + quad * 8];
        aq = __builtin_amdgcn_mfma_f32_16x16x32_bf16(af, bqf, aq, 0, 0, 0);
        ak = __builtin_amdgcn_mfma_f32_16x16x32_bf16(af, bkf, ak, 0, 0, 0);
      }
#pragma unroll
      for (int r = 0; r < 4; r++) {
        int t = quad * 4 + r;
        if (t < TT) {
          int h = w * 16 + col;
          qs[t * TP + h] = aq[r] + bqs[h];
          ks[t * TP + h] = ak[r] + bks[h];
        }
      }
    }
    if (tid < 64) {  // v projection: only last hidden row matters
      float s = 0.f;
#pragma unroll 8
      for (int j = 0; j < 64; j++)
        s += B2F(Xb[11 * 72 + j]) * B2F(Wv_s[j * 64 + tid]);
      ovv[tid] = s;
    }
    __syncthreads();
    for (int i = tid; i < 2 * TT * TT; i += 256) {
      int hd = i / (TT * TT), ts = i % (TT * TT), t = ts / TT, s = ts % TT;
      float acc = 0.f;
#pragma unroll
      for (int d = 0; d < 32; d++) acc += qs[t * TP + hd * 32 + d] * ks[s * TP + hd * 32 + d];
      A[i] = acc * 0.17677669529663687f;
    }
    __syncthreads();
    if (tid < 2 * TT) {
      int hd = tid / TT, t = tid % TT;
      float* row = &A[hd * TT * TT + t * TT];
      float m = row[0];
      for (int s = 1; s < TT; s++) m = fmaxf(m, row[s]);
      float sm = 0.f;
      for (int s = 0; s < TT; s++) { float e = expf(row[s] - m); row[s] = e; sm += e; }
      float inv = 1.0f / sm;
      for (int s = 0; s < TT; s++) row[s] *= inv;
    }
    __syncthreads();
#pragma unroll
    for (int it = 0; it < 3; it++) {
      int i = it * 256 + tid;
      int t = i >> 6, h = i & 63, hd = h >> 5;
      float afs = 0.f;
#pragma unroll
      for (int s = 0; s < TT; s++) afs += A[hd * TT * TT + t * TT + s] * fss[s];
      float o = ovv[h] * afs + bvs[h];
      float x = o + B2F(Xb[t * 72 + h]);
      float mu = wsum(x) * (1.0f / 64.0f);
      float d = x - mu;
      float var = wsum(d * d) * (1.0f / 64.0f);
      float v = d * rsqrtf(var + 1e-5f) * g1s[h] + b1s[h];
      val[((size_t)(b * TT + t) * NN + n) * HHID + h] = __float2bfloat16(v);
    }
    __syncthreads();
  }
}

__global__ __launch_bounds__(256, 4) void ffn_kernel(
    const bf16* __restrict__ val, const float* __restrict__ W1, const float* __restrict__ b1,
    const float* __restrict__ W2, const float* __restrict__ b2,
    const float* __restrict__ ln2g, const float* __restrict__ ln2b,
    const float* __restrict__ fcW, const float* __restrict__ fcb,
    float* __restrict__ out, int rows_per_block) {
  __shared__ bf16 W1T[4096], W2T[4096];   // [h_out][h_in] bf16
  __shared__ bf16 Ab[16 * 72];            // 16 input rows bf16
  __shared__ bf16 Hh[16 * 72], Hl[16 * 72];  // hidden hi/lo split
  __shared__ float fout[16 * 68];
  __shared__ float b1s[64], b2s[64], g2s[64], bb2[64], fcs[64];
  int tid = threadIdx.x;
  int w = tid >> 6, lane = tid & 63, col = lane & 15, quad = lane >> 4;
#pragma unroll
  for (int i = 0; i < 16; i++) {
    int e = tid * 16 + i;
    int hi = e >> 6, ho = e & 63;
    W1T[ho * 64 + hi] = __float2bfloat16(W1[e]);
    W2T[ho * 64 + hi] = __float2bfloat16(W2[e]);
  }
  if (tid < 64) {
    b1s[tid] = b1[tid]; b2s[tid] = b2[tid];
    g2s[tid] = ln2g[tid]; bb2[tid] = ln2b[tid]; fcs[tid] = fcW[tid];
  }
  __syncthreads();
  float fcbv = fcb[0];
  for (int c0 = 0; c0 < rows_per_block; c0 += 16) {
    size_t r0 = (size_t)blockIdx.x * rows_per_block + c0;
    for (int i = tid; i < 1024; i += 256) {
      int rr = i >> 6, j = i & 63;
      Ab[rr * 72 + j] = val[(r0 + rr) * 64 + j];
    }
    __syncthreads();
    // layer 1: h = relu(A @ W1 + b1), split to bf16 hi+lo
    {
      f32x4 a1 = (f32x4){0.f, 0.f, 0.f, 0.f};
#pragma unroll
      for (int ki = 0; ki < 2; ki++) {
        bf16x8 af = *(const bf16x8*)&Ab[col * 72 + ki * 32 + quad * 8];
        bf16x8 bf1 = *(const bf16x8*)&W1T[(w * 16 + col) * 64 + ki * 32 + quad * 8];
        a1 = __builtin_amdgcn_mfma_f32_16x16x32_bf16(af, bf1, a1, 0, 0, 0);
      }
#pragma unroll
      for (int r = 0; r < 4; r++) {
        int m = quad * 4 + r, h = w * 16 + col;
        float hv = fmaxf(a1[r] + b1s[h], 0.0f);
        bf16 hb = __float2bfloat16(hv);
        float lo = hv - B2F(hb);
        Hh[m * 72 + h] = hb;
        Hl[m * 72 + h] = __float2bfloat16(lo);
      }
    }
    __syncthreads();
    // layer 2: f = (Hh + Hl) @ W2 + b2 + residual
    {
      f32x4 a2 = (f32x4){0.f, 0.f, 0.f, 0.f};
#pragma unroll
      for (int ki = 0; ki < 2; ki++) {
        bf16x8 ah = *(const bf16x8*)&Hh[col * 72 + ki * 32 + quad * 8];
        bf16x8 al = *(const bf16x8*)&Hl[col * 72 + ki * 32 + quad * 8];
        bf16x8 bf2 = *(const bf16x8*)&W2T[(w * 16 + col) * 64 + ki * 32 + quad * 8];
        a2 = __builtin_amdgcn_mfma_f32_16x16x32_bf16(ah, bf2, a2, 0, 0, 0);
        a2 = __builtin_amdgcn_mfma_f32_16x16x32_bf16(al, bf2, a2, 0, 0, 0);
      }
#pragma unroll
      for (int r = 0; r < 4; r++) {
        int m = quad * 4 + r, h = w * 16 + col;
        fout[m * 68 + h] = a2[r] + b2s[h] + B2F(Ab[m * 72 + h]);
      }
    }
    __syncthreads();
    // LN + fc per row: wave w handles rows {w, w+4, w+8, w+12}
#pragma unroll
    for (int p4 = 0; p4 < 4; p4++) {
      int m = p4 * 4 + w;
      float y = fout[m * 68 + lane];
      float mu = wsum(y) * (1.0f / 64.0f);
      float d = y - mu;
      float var = wsum(d * d) * (1.0f / 64.0f);
      float oh = d * rsqrtf(var + 1e-5f) * g2s[lane] + bb2[lane];
      float contrib = wsum(oh * fcs[lane]);
      if (lane == 0) out[r0 + m] = contrib + fcbv;
    }
    __syncthreads();
  }
}

extern "C" void kernel_launch(void* const* d_in, const int* in_sizes, int n_in,
                              void* d_out, int out_size, void* d_ws, size_t ws_size,
                              hipStream_t stream) {
  const float* src = (const float*)d_in[0];
  const float* emb = (const float*)d_in[2];
  const float* gwp[2] = {(const float*)d_in[3], (const float*)d_in[7]};
  const float* gbp[2] = {(const float*)d_in[4], (const float*)d_in[8]};
  const float* uwp[2] = {(const float*)d_in[5], (const float*)d_in[9]};
  const float* ubp[2] = {(const float*)d_in[6], (const float*)d_in[10]};
  const float* hypW = (const float*)d_in[11];
  const float* hypb = (const float*)d_in[12];
  const float *Wq, *Wk, *Wv, *ffW1, *ffW2, *bq, *bk, *bv, *ffb1, *ffb2;
  const float *ln1g, *ln1b, *ln2g, *ln2b, *fcW, *fcb;
  if (in_sizes[14] == 4096) {
    Wq = (const float*)d_in[13]; Wk = (const float*)d_in[14]; Wv = (const float*)d_in[15];
    ffW1 = (const float*)d_in[16]; ffW2 = (const float*)d_in[17];
    bq = (const float*)d_in[18]; bk = (const float*)d_in[19]; bv = (const float*)d_in[20];
    ffb1 = (const float*)d_in[21]; ffb2 = (const float*)d_in[22];
    ln1g = (const float*)d_in[23]; ln1b = (const float*)d_in[24];
    ln2g = (const float*)d_in[25]; ln2b = (const float*)d_in[26];
    fcW = (const float*)d_in[27]; fcb = (const float*)d_in[28];
  } else {
    Wq = (const float*)d_in[13]; bq = (const float*)d_in[14];
    Wk = (const float*)d_in[15]; bk = (const float*)d_in[16];
    Wv = (const float*)d_in[17]; bv = (const float*)d_in[18];
    ln1g = (const float*)d_in[19]; ln1b = (const float*)d_in[20];
    ffW1 = (const float*)d_in[21]; ffb1 = (const float*)d_in[22];
    ffW2 = (const float*)d_in[23]; ffb2 = (const float*)d_in[24];
    ln2g = (const float*)d_in[25]; ln2b = (const float*)d_in[26];
    fcW = (const float*)d_in[27]; fcb = (const float*)d_in[28];
  }
  float* outp = (float*)d_out;

  char* ws = (char*)d_ws;
  size_t off = 0;
  auto alloc = [&](size_t bytes) {
    void* p = ws + off;
    off += (bytes + 255) & ~(size_t)255;
    return p;
  };
  bf16* adjb = (bf16*)alloc((size_t)512 * 512 * 2);
  bf16* gWb = (bf16*)alloc((size_t)512 * 32768 * 2);
  bf16* uWb = (bf16*)alloc((size_t)512 * 16384 * 2);
  float* gb = (float*)alloc((size_t)512 * 128 * 4);
  float* ub = (float*)alloc((size_t)512 * 64 * 4);
  bf16* xin0 = (bf16*)alloc((size_t)12 * 512 * 32 * 2 * 2);
  bf16* x0 = (bf16*)alloc((size_t)12 * 512 * 32 * 64 * 2);
  bf16* xd0 = (bf16*)alloc((size_t)12 * 512 * 32 * 2 * 2);
  bf16* xdL1 = (bf16*)alloc((size_t)512 * 32 * 64 * 2);
  float* state = (float*)alloc((size_t)512 * 32 * 64 * 4);
  bf16* sb = (bf16*)alloc((size_t)512 * 32 * 64 * 2);
  bf16* sdiff = (bf16*)alloc((size_t)512 * 32 * 64 * 2);
  bf16* zs = (bf16*)alloc((size_t)512 * 32 * 64 * 2);
  bf16* zsdiff = (bf16*)alloc((size_t)512 * 32 * 64 * 2);
  bf16* rbuf = (bf16*)alloc((size_t)512 * 32 * 64 * 2);
  float* PW = (float*)alloc((size_t)16 * 48 * 4);
  float* fsb = (float*)alloc((size_t)512 * 12 * 4);
  unsigned* bar = (unsigned*)alloc((size_t)544 * 4);
  bf16* val = gWb;

  adj_kernel<<<512, 256, 0, stream>>>(emb, adjb);
  pw_kernel<<<dim3(48, 16), 256, 0, stream>>>(uwp[1], hypW, PW);
  fs_kernel<<<24, 256, 0, stream>>>(emb, PW, hypb, fsb);
  cvt_src_kernel<<<1536, 256, 0, stream>>>(src, xin0);

  int occ0 = 0, occ1 = 0;
  hipOccupancyMaxActiveBlocksPerMultiprocessor(&occ0, recur_kernel<2>, 256, 0);
  hipOccupancyMaxActiveBlocksPerMultiprocessor(&occ1, recur_kernel<64>, 256, 0);

  for (int l = 0; l < 2; l++) {
    int C = (l == 0) ? 2 : 64;
    int KC = 2 * (C + 64);
    int KCP = (KC + 31) & ~31;  // 160 or 256
    int JG = KC * 128, JU = KC * 64;
    // coalesced wgen_t writes the full padded region incl. zeros
    wgen_t_kernel<<<dim3(KCP * 128 / 256, 4), 256, 0, stream>>>(
        gwp[l], emb, gWb, JG, 128, KCP, KC);
    wgen_t_kernel<<<dim3(KCP * 64 / 256, 4), 256, 0, stream>>>(
        uwp[l], emb, uWb, JU, 64, KCP, KC);
    wgen_kernel<<<dim3(1, 4), 256, 0, stream>>>(gbp[l], emb, gb, 128);
    wgen_kernel<<<dim3(1, 4), 256, 0, stream>>>(ubp[l], emb, ub, 64);
    zero_f32_kernel<<<3, 256, 0, stream>>>((float*)bar, 544);

    const bf16* xin = (l == 0) ? xin0 : x0;
    bf16* xd = (l == 0) ? xd0 : xdL1;
    int occ = (l == 0) ? occ0 : occ1;
    if (occ >= 2) {
      // Plain (graph-capturable) launch: 512 blocks <= occ*256 CUs resident;
      // graph node deps guarantee an idle device at launch.
      if (l == 0)
        recur_kernel<2><<<512, 256, 0, stream>>>(adjb, xin, gWb, gb, uWb, ub,
                                                 zs, sdiff, zsdiff, xd, x0, bar);
      else
        recur_kernel<64><<<512, 256, 0, stream>>>(adjb, xin, gWb, gb, uWb, ub,
                                                  zs, sdiff, zsdiff, xd, x0, bar);
    } else {
      // ---- fallback: per-phase kernels (same math) ----
      zero_f32_kernel<<<4096, 256, 0, stream>>>(state, 512 * 32 * 64);
      zero_f32_kernel<<<2048, 256, 0, stream>>>((float*)sb, 512 * 32 * 64 / 2);
      if (l == 0) diffuse0_kernel<<<96, 256, 0, stream>>>(adjb, xin, xd);
      for (int t = 0; t < 12; t++) {
        const bf16* xt = xin + (size_t)t * 512 * 32 * C;
        const bf16* xdt = (l == 0) ? (xd + (size_t)t * 512 * 32 * C) : xd;
        bf16* xo = x0 + (size_t)t * 512 * 32 * 64;
        if (l == 1) diffuse1_kernel<<<256, 256, 0, stream>>>(adjb, xt, xd);
        diffuse1_kernel<<<256, 256, 0, stream>>>(adjb, sb, sdiff);
        if (l == 0)
          gate_wrap<2><<<512, 256, 0, stream>>>(xt, xdt, sb, sdiff, gWb, gb, state, zs, rbuf);
        else
          gate_wrap<64><<<512, 256, 0, stream>>>(xt, xdt, sb, sdiff, gWb, gb, state, zs, rbuf);
        diffuse1_kernel<<<256, 256, 0, stream>>>(adjb, zs, zsdiff);
        if (l == 0)
          upd_wrap<2><<<512, 256, 0, stream>>>(xt, xdt, zs, zsdiff, uWb, ub, state, sb, rbuf, xo);
        else
          upd_wrap<64><<<512, 256, 0, stream>>>(xt, xdt, zs, zsdiff, uWb, ub, state, sb, rbuf, xo);
      }
    }
  }

  attn1_kernel<<<2048, 256, 0, stream>>>(x0, fsb, Wq, bq, Wk, bk, Wv, bv, ln1g, ln1b, val);
  ffn_kernel<<<2048, 256, 0, stream>>>(val, ffW1, ffb1, ffW2, ffb2, ln2g, ln2b, fcW, fcb,
                                       outp, 96);
}

// Round 8
// 1624.185 us; speedup vs baseline: 1.2549x; 1.0163x over previous
//
#include <hip/hip_runtime.h>
#include <hip/hip_bf16.h>

// MAGCRN on MI355X — round 18: FULL-DEPTH DIFFUSION PREFETCH + COALESCED PW
// + PADDED WEIGHT TILES.
//  * Round-17: profile covers ONE invocation; pie = recur 903us (55%),
//    attn 109, ffn 71, pw 57, setup rest. Diffusion is latency-bound: the
//    3-slot rolling prefetch serializes ~8 LLC round trips per tile.
//  * Fix 1: issue ALL 8 c-iter panel loads in the prologue (no in-loop
//    loads -> exact FIFO vmcnt), wait vmcnt((6-c)*LPC) per iter. 8 serial
//    latencies -> ~1.
//  * Fix 2: hypW transposed once (coalesced LDS tiles); pw reads contiguous.
//  * Fix 3: WqT/WkT/W1T/W2T rows padded 64->72 shorts (stride 36 dwords) to
//    kill the 16-way bank conflict on MFMA B-fragment reads (5.2M counted).

using bf16 = __hip_bfloat16;
#define B2F(x) __bfloat162float(x)

#define NN 512
#define BBATCH 32
#define HHID 64
#define TT 12
#define EE 16

typedef __attribute__((ext_vector_type(4))) float f32x4;
typedef __attribute__((ext_vector_type(8))) short bf16x8;

__device__ inline float wsum(float x) {
#pragma unroll
  for (int off = 32; off > 0; off >>= 1) x += __shfl_xor(x, off, 64);
  return x;
}

// ---------------- LLC-coherent access helpers ------------------------------
__device__ inline uint4 llc_load4(const void* p) {
  uint4 r;
  asm volatile("global_load_dwordx4 %0, %1, off sc0 sc1" : "=v"(r) : "v"(p));
  return r;
}
__device__ inline uint2 llc_load2(const void* p) {
  uint2 r;
  asm volatile("global_load_dwordx2 %0, %1, off sc0 sc1" : "=v"(r) : "v"(p));
  return r;
}
__device__ inline unsigned llc_load1(const void* p) {
  unsigned r;
  asm volatile("global_load_dword %0, %1, off sc0 sc1" : "=v"(r) : "v"(p));
  return r;
}
__device__ inline void llc_store_bf(void* p, unsigned short v) {
  asm volatile("global_store_short %0, %1, off sc0 sc1" :: "v"(p), "v"((unsigned)v) : "memory");
}
__device__ inline void llc_store_u1(void* p, unsigned v) {
  asm volatile("global_store_dword %0, %1, off sc0 sc1" :: "v"(p), "v"(v) : "memory");
}
template <int N> __device__ inline void wait_vmcnt() {
  if constexpr (N <= 0)      asm volatile("s_waitcnt vmcnt(0)" ::: "memory");
  else if constexpr (N == 1) asm volatile("s_waitcnt vmcnt(1)" ::: "memory");
  else if constexpr (N == 2) asm volatile("s_waitcnt vmcnt(2)" ::: "memory");
  else if constexpr (N == 3) asm volatile("s_waitcnt vmcnt(3)" ::: "memory");
  else if constexpr (N == 4) asm volatile("s_waitcnt vmcnt(4)" ::: "memory");
  else if constexpr (N == 5) asm volatile("s_waitcnt vmcnt(5)" ::: "memory");
  else if constexpr (N == 6) asm volatile("s_waitcnt vmcnt(6)" ::: "memory");
  else if constexpr (N == 7) asm volatile("s_waitcnt vmcnt(7)" ::: "memory");
  else if constexpr (N == 8) asm volatile("s_waitcnt vmcnt(8)" ::: "memory");
  else if constexpr (N == 10) asm volatile("s_waitcnt vmcnt(10)" ::: "memory");
  else if constexpr (N == 12) asm volatile("s_waitcnt vmcnt(12)" ::: "memory");
  else                       asm volatile("s_waitcnt vmcnt(14)" ::: "memory");
}

// LDS-only barrier: waits DS ops, leaves global loads in flight.
__device__ inline void lds_barrier() {
  asm volatile("s_waitcnt lgkmcnt(0)" ::: "memory");
  __builtin_amdgcn_s_barrier();
  asm volatile("" ::: "memory");
}

// ---------------- grid barrier: fenceless flags + master + epoch -----------
__device__ inline void gbar(unsigned* __restrict__ bar, int& cnt) {
  cnt++;
  __syncthreads();  // drains vmcnt(0): all sc stores are at the LLC
  unsigned tgt = (unsigned)cnt;
  unsigned* flags = bar + 32;
  if (blockIdx.x == 0) {
    if (threadIdx.x < 64) {
      if (threadIdx.x == 0) llc_store_u1(flags, tgt);
      const unsigned* fp = flags + threadIdx.x * 8;
      bool ok;
      do {
        unsigned v0 = llc_load1(fp + 0), v1 = llc_load1(fp + 1),
                 v2 = llc_load1(fp + 2), v3 = llc_load1(fp + 3),
                 v4 = llc_load1(fp + 4), v5 = llc_load1(fp + 5),
                 v6 = llc_load1(fp + 6), v7 = llc_load1(fp + 7);
        wait_vmcnt<0>();
        __builtin_amdgcn_sched_barrier(0);
        ok = ((int)(v0 - tgt) >= 0) && ((int)(v1 - tgt) >= 0) &&
             ((int)(v2 - tgt) >= 0) && ((int)(v3 - tgt) >= 0) &&
             ((int)(v4 - tgt) >= 0) && ((int)(v5 - tgt) >= 0) &&
             ((int)(v6 - tgt) >= 0) && ((int)(v7 - tgt) >= 0);
      } while (!__all(ok));
      if (threadIdx.x == 0) llc_store_u1(bar, tgt);
    }
  } else if (threadIdx.x == 0) {
    llc_store_u1(flags + blockIdx.x, tgt);
    for (;;) {
      unsigned e = llc_load1(bar);
      wait_vmcnt<0>();
      __builtin_amdgcn_sched_barrier(0);
      if ((int)(e - tgt) >= 0) break;
      __builtin_amdgcn_s_sleep(2);
    }
  }
  __syncthreads();
}

__global__ __launch_bounds__(256) void zero_f32_kernel(float* __restrict__ p, int n) {
  int i = blockIdx.x * 256 + threadIdx.x;
  if (i < n) p[i] = 0.0f;
}

// ---------------- setup kernels ----------------

__global__ __launch_bounds__(256) void adj_kernel(const float* __restrict__ emb,
                                                  bf16* __restrict__ adjb) {
  __shared__ float embAll[NN * EE];
  __shared__ float red[256];
  int tid = threadIdx.x, n = blockIdx.x;
  for (int i = tid; i < NN * EE; i += 256) embAll[i] = emb[i];
  __syncthreads();
  float v[2];
#pragma unroll
  for (int j = 0; j < 2; j++) {
    int m = tid + j * 256;
    float s = 0.f;
#pragma unroll
    for (int e = 0; e < EE; e++) s += embAll[n * EE + e] * embAll[m * EE + e];
    v[j] = fmaxf(s, 0.0f);
  }
  float mx = fmaxf(v[0], v[1]);
  red[tid] = mx; __syncthreads();
  for (int s = 128; s > 0; s >>= 1) { if (tid < s) red[tid] = fmaxf(red[tid], red[tid + s]); __syncthreads(); }
  mx = red[0]; __syncthreads();
  float e0 = expf(v[0] - mx), e1 = expf(v[1] - mx);
  red[tid] = e0 + e1; __syncthreads();
  for (int s = 128; s > 0; s >>= 1) { if (tid < s) red[tid] += red[tid + s]; __syncthreads(); }
  float inv = 1.0f / red[0];
  adjb[n * NN + tid] = __float2bfloat16(e0 * inv);
  adjb[n * NN + tid + 256] = __float2bfloat16(e1 * inv);
}

__global__ __launch_bounds__(256) void wgen_kernel(const float* __restrict__ pool,
                                                   const float* __restrict__ emb,
                                                   float* __restrict__ out, int J) {
  __shared__ float embL[128 * EE];
  int tid = threadIdx.x;
  int n0 = blockIdx.y * 128;
  for (int i = tid; i < 128 * EE; i += 256) embL[i] = emb[n0 * EE + i];
  __syncthreads();
  int j = blockIdx.x * 256 + tid;
  if (j >= J) return;
  float pw[EE];
#pragma unroll
  for (int e = 0; e < EE; e++) pw[e] = pool[e * J + j];
#pragma unroll 4
  for (int nn = 0; nn < 128; nn++) {
    float s = 0.f;
#pragma unroll
    for (int e = 0; e < EE; e++) s += embL[nn * EE + e] * pw[e];
    out[(size_t)(n0 + nn) * J + j] = s;
  }
}

// coalesced transposed weight generator: thread p = output position
__global__ __launch_bounds__(256) void wgen_t_kernel(const float* __restrict__ pool,
                                                     const float* __restrict__ emb,
                                                     bf16* __restrict__ out, int J,
                                                     int O, int KCP, int KC) {
  __shared__ float embL[128 * EE];
  int tid = threadIdx.x;
  int n0 = blockIdx.y * 128;
  for (int i = tid; i < 128 * EE; i += 256) embL[i] = emb[n0 * EE + i];
  __syncthreads();
  int p = blockIdx.x * 256 + tid;
  unsigned kc = (unsigned)p % (unsigned)KCP;
  unsigned o = (unsigned)p / (unsigned)KCP;
  size_t P = (size_t)KCP * O;
  if (kc >= (unsigned)KC) {
    bf16 z = __float2bfloat16(0.f);
    for (int nn = 0; nn < 128; nn++) out[(size_t)(n0 + nn) * P + p] = z;
    return;
  }
  int jp = (int)kc * O + (int)o;
  float pw[EE];
#pragma unroll
  for (int e = 0; e < EE; e++) pw[e] = pool[e * J + jp];
#pragma unroll 4
  for (int nn = 0; nn < 128; nn++) {
    float s = 0.f;
#pragma unroll
    for (int e = 0; e < EE; e++) s += embL[nn * EE + e] * pw[e];
    out[(size_t)(n0 + nn) * P + p] = __float2bfloat16(s);
  }
}

// hypW[16384][48] -> hypWT[48][16384] (coalesced both sides via LDS tile)
__global__ __launch_bounds__(256) void hypwT_kernel(const float* __restrict__ hypW,
                                                    float* __restrict__ hypWT) {
  __shared__ float tile[48 * 33];
  int r0 = blockIdx.x * 32, tid = threadIdx.x;
  for (int i = tid; i < 32 * 48; i += 256) {
    int r = i / 48, c = i - r * 48;
    tile[c * 33 + r] = hypW[(size_t)(r0 + r) * 48 + c];
  }
  __syncthreads();
  for (int i = tid; i < 48 * 32; i += 256) {
    int c = i >> 5, r = i & 31;
    hypWT[(size_t)c * 16384 + r0 + r] = tile[c * 33 + r];
  }
}

__global__ __launch_bounds__(256) void pw_kernel(const float* __restrict__ upool,
                                                 const float* __restrict__ hypWT,
                                                 float* __restrict__ PW) {
  __shared__ float red[256];
  int j = blockIdx.x, e = blockIdx.y, tid = threadIdx.x;
  float s = 0.f;
#pragma unroll 4
  for (int p = tid; p < 16384; p += 256)
    s += upool[e * 16384 + p] * hypWT[(size_t)j * 16384 + p];
  red[tid] = s; __syncthreads();
  for (int t = 128; t > 0; t >>= 1) { if (tid < t) red[tid] += red[tid + t]; __syncthreads(); }
  if (tid == 0) PW[e * 48 + j] = red[0];
}

__global__ __launch_bounds__(256) void fs_kernel(const float* __restrict__ emb,
                                                 const float* __restrict__ PW,
                                                 const float* __restrict__ hypb,
                                                 float* __restrict__ fs) {
  int id = blockIdx.x * 256 + threadIdx.x;
  if (id >= NN * TT) return;
  int n = id / TT, t = id % TT;
  float s = 0.f;
#pragma unroll
  for (int f = 0; f < 4; f++) {
    int j = t * 4 + f;
    float h = hypb[j];
#pragma unroll
    for (int e = 0; e < EE; e++) h += emb[n * EE + e] * PW[e * 48 + j];
    s += h;
  }
  fs[id] = s;
}

__global__ __launch_bounds__(256) void cvt_src_kernel(const float* __restrict__ src,
                                                      bf16* __restrict__ x) {
  int id = blockIdx.x * 256 + threadIdx.x;  // < 393216
  int c = id & 1, b = (id >> 1) & 31, n = (id >> 6) & 511, t = id >> 15;
  x[id] = __float2bfloat16(src[((b * TT + t) * NN + n) * 2 + c]);
}

// ---------------- diffusion: FULL-DEPTH prefetch, LLC-coherent -------------
#define DBUF 4672

__device__ inline void xsT_wr8(unsigned short* xsT, int base, int q0l, int k, uint4 v) {
  union { uint4 u; unsigned short h[8]; } cv; cv.u = v;
#pragma unroll
  for (int qq = 0; qq < 8; qq++) {
    int q = q0l + qq;
    xsT[base + q * 72 + (q >> 3) * 8 + k] = cv.h[qq];
  }
}

// One pipeline step: stage next buffer (counted wait), MFMA current, barrier.
#define DIFF_STEP(cc)                                                         \
  {                                                                           \
    if constexpr ((cc) < 7) {                                                 \
      wait_vmcnt<(6 - (cc)) * LPC>();                                         \
      constexpr int nb = ((((cc) + 1) & 1)) * DBUF;                           \
      xsT_wr8(xsT, nb, ql, kr, pre[((cc) + 1) & 7][0]);                       \
      if constexpr (QW == 64)                                                 \
        xsT_wr8(xsT, nb, ql, 32 + kr, pre[((cc) + 1) & 7][1]);                \
    }                                                                         \
    constexpr int base = ((cc) & 1) * DBUF;                                   \
    _Pragma("unroll")                                                         \
    for (int ki = 0; ki < 2; ki++) {                                          \
      bf16x8 a = apre[(cc) * 2 + ki];                                         \
      _Pragma("unroll")                                                       \
      for (int ct = 0; ct < NCT; ct++) {                                      \
        int q = ct * 16 + col;                                                \
        bf16x8 b = *(const bf16x8*)&xsT[base + q * 72 + (q >> 3) * 8 +        \
                                        ki * 32 + quad * 8];                  \
        acc[ct] = __builtin_amdgcn_mfma_f32_16x16x32_bf16(a, b, acc[ct], 0, 0, 0); \
      }                                                                       \
    }                                                                         \
    lds_barrier();                                                            \
  }

template <int QW>
__device__ inline void diffuse_tileP(const bf16x8* __restrict__ apre,
                                     const bf16* __restrict__ X, bf16* __restrict__ Y,
                                     int Q, int n0, int q0, char* smraw, int tid) {
  constexpr int LPC = QW / 32;
  constexpr int NCT = QW / 16;
  unsigned short* xsT = (unsigned short*)smraw;
  int w = tid >> 6, lane = tid & 63;
  int col = lane & 15, quad = lane >> 4;
  int kr, ql;
  if constexpr (QW == 64) { kr = tid >> 3; ql = (tid & 7) * 8; }
  else                    { kr = tid >> 2; ql = (tid & 3) * 8; }
  f32x4 acc[NCT];
#pragma unroll
  for (int ct = 0; ct < NCT; ct++) acc[ct] = (f32x4){0.f, 0.f, 0.f, 0.f};
  const bf16* Xb = X + q0 + ql;
  uint4 pre[8][LPC];
#pragma unroll
  for (int c = 0; c < 8; c++) {
    pre[c][0] = llc_load4(Xb + (size_t)(c * 64 + kr) * Q);
    if constexpr (QW == 64)
      pre[c][1] = llc_load4(Xb + (size_t)(c * 64 + 32 + kr) * Q);
  }
  wait_vmcnt<7 * LPC>();  // oldest (c=0) loads complete
  xsT_wr8(xsT, 0, ql, kr, pre[0][0]);
  if constexpr (QW == 64) xsT_wr8(xsT, 0, ql, 32 + kr, pre[0][1]);
  lds_barrier();
  DIFF_STEP(0) DIFF_STEP(1) DIFF_STEP(2) DIFF_STEP(3)
  DIFF_STEP(4) DIFF_STEP(5) DIFF_STEP(6) DIFF_STEP(7)
#pragma unroll
  for (int ct = 0; ct < NCT; ct++)
#pragma unroll
    for (int r = 0; r < 4; r++) {
      int row = n0 + w * 16 + quad * 4 + r;
      bf16 hb = __float2bfloat16(acc[ct][r]);
      llc_store_bf(Y + (size_t)row * Q + q0 + ct * 16 + col, *(unsigned short*)&hb);
    }
}

// ---------------- fallback-path shared functions ---------------------------

template <int C>
__device__ inline void stage_A(int n, int tid, unsigned short* xinb,
    const bf16* __restrict__ xt, const bf16* __restrict__ xd,
    const bf16* __restrict__ sa, const bf16* __restrict__ sad) {
  constexpr int cc = C + HHID, KC = 2 * cc, KCP = (KC + 31) & ~31, PIT = KCP + 8;
  __syncthreads();
  for (int i = tid; i < 32 * KCP; i += 256) {
    int b = i / KCP, kc = i - b * KCP;
    unsigned short v = 0;
    if (kc < C)            v = *(const unsigned short*)&xt[(n * 32 + b) * C + kc];
    else if (kc < cc)      v = *(const unsigned short*)&sa[(n * 32 + b) * HHID + kc - C];
    else if (kc < cc + C)  v = *(const unsigned short*)&xd[(n * 32 + b) * C + kc - cc];
    else if (kc < KC)      v = *(const unsigned short*)&sad[(n * 32 + b) * HHID + kc - cc - C];
    xinb[b * PIT + kc] = v;
  }
  __syncthreads();
}

template <int C>
__device__ inline void gate_epilogue(int n, int w, int col, int quad,
    f32x4 acc[2][2], const float* __restrict__ gb, const float* __restrict__ state,
    bf16* __restrict__ zs, bf16* __restrict__ rbuf) {
#pragma unroll
  for (int i = 0; i < 2; i++) {
    int o = (w + i * 4) * 16 + col;
    float bv = gb[n * 128 + o];
#pragma unroll
    for (int mt = 0; mt < 2; mt++)
#pragma unroll
      for (int r = 0; r < 4; r++) {
        int m = mt * 16 + quad * 4 + r;
        float zr = 1.0f / (1.0f + expf(-(acc[i][mt][r] + bv)));
        int idx = (n * 32 + m) * HHID + (o & 63);
        if (o < HHID) zs[idx] = __float2bfloat16(zr * state[idx]);
        else          rbuf[idx] = __float2bfloat16(zr);
      }
  }
}

template <int C>
__device__ inline void upd_epilogue(int n, int w, int col, int quad,
    f32x4 acc[2], const float* __restrict__ ub, float* __restrict__ state,
    bf16* __restrict__ sb, const bf16* __restrict__ rbuf, bf16* __restrict__ xo) {
  int o = w * 16 + col;
  float bv = ub[n * 64 + o];
#pragma unroll
  for (int mt = 0; mt < 2; mt++)
#pragma unroll
    for (int r = 0; r < 4; r++) {
      int m = mt * 16 + quad * 4 + r;
      int idx = (n * 32 + m) * HHID + o;
      float hc = tanhf(acc[mt][r] + bv);
      float rr = B2F(rbuf[idx]);
      float st = state[idx];
      float h = rr * st + (1.0f - rr) * hc;
      state[idx] = h;
      bf16 hb = __float2bfloat16(h);
      sb[idx] = hb;
      xo[idx] = hb;
    }
}

template <int C>
__device__ inline void gate_mfma(int n, int tid, const unsigned short* xinb,
    const bf16* __restrict__ gWt, const float* __restrict__ gb,
    const float* __restrict__ state, bf16* __restrict__ zs, bf16* __restrict__ rbuf) {
  constexpr int KC = 2 * (C + HHID), KCP = (KC + 31) & ~31, PIT = KCP + 8;
  int w = tid >> 6, lane = tid & 63, col = lane & 15, quad = lane >> 4;
  f32x4 acc[2][2];
#pragma unroll
  for (int i = 0; i < 2; i++)
#pragma unroll
    for (int mt = 0; mt < 2; mt++) acc[i][mt] = (f32x4){0.f, 0.f, 0.f, 0.f};
  const bf16* Wn = gWt + (size_t)n * KCP * 128;
#pragma unroll 2
  for (int k0 = 0; k0 < KCP; k0 += 32) {
    int ko = k0 + quad * 8;
    bf16x8 a0 = *(const bf16x8*)&xinb[col * PIT + ko];
    bf16x8 a1 = *(const bf16x8*)&xinb[(16 + col) * PIT + ko];
#pragma unroll
    for (int i = 0; i < 2; i++) {
      int o = (w + i * 4) * 16 + col;
      bf16x8 bf = *(const bf16x8*)(Wn + (size_t)o * KCP + ko);
      acc[i][0] = __builtin_amdgcn_mfma_f32_16x16x32_bf16(a0, bf, acc[i][0], 0, 0, 0);
      acc[i][1] = __builtin_amdgcn_mfma_f32_16x16x32_bf16(a1, bf, acc[i][1], 0, 0, 0);
    }
  }
  gate_epilogue<C>(n, w, col, quad, acc, gb, state, zs, rbuf);
}

template <int C>
__device__ inline void upd_mfma(int n, int tid, const unsigned short* xinb,
    const bf16* __restrict__ uWt, const float* __restrict__ ub,
    float* __restrict__ state, bf16* __restrict__ sb,
    const bf16* __restrict__ rbuf, bf16* __restrict__ xo) {
  constexpr int KC = 2 * (C + HHID), KCP = (KC + 31) & ~31, PIT = KCP + 8;
  int w = tid >> 6, lane = tid & 63, col = lane & 15, quad = lane >> 4;
  f32x4 acc[2];
  acc[0] = (f32x4){0.f, 0.f, 0.f, 0.f};
  acc[1] = (f32x4){0.f, 0.f, 0.f, 0.f};
  const bf16* Wn = uWt + (size_t)n * KCP * 64;
  int o = w * 16 + col;
#pragma unroll 2
  for (int k0 = 0; k0 < KCP; k0 += 32) {
    int ko = k0 + quad * 8;
    bf16x8 a0 = *(const bf16x8*)&xinb[col * PIT + ko];
    bf16x8 a1 = *(const bf16x8*)&xinb[(16 + col) * PIT + ko];
    bf16x8 bf = *(const bf16x8*)(Wn + (size_t)o * KCP + ko);
    acc[0] = __builtin_amdgcn_mfma_f32_16x16x32_bf16(a0, bf, acc[0], 0, 0, 0);
    acc[1] = __builtin_amdgcn_mfma_f32_16x16x32_bf16(a1, bf, acc[1], 0, 0, 0);
  }
  upd_epilogue<C>(n, w, col, quad, acc, ub, state, sb, rbuf, xo);
}

// ---------------- cooperative recurrence -----------------------------------

template <int C>
__global__ __launch_bounds__(256, 2) void recur_kernel(
    const bf16* __restrict__ adjb, const bf16* __restrict__ xin,
    const bf16* __restrict__ gWt, const float* __restrict__ gb,
    const bf16* __restrict__ uWt, const float* __restrict__ ub,
    bf16* __restrict__ zs, bf16* __restrict__ sdiff, bf16* __restrict__ zsdiff,
    bf16* __restrict__ xd, bf16* __restrict__ xout, unsigned* __restrict__ bar) {
  constexpr int KC = 2 * (C + HHID), KCP = (KC + 31) & ~31, PIT = KCP + 8;
  constexpr int NK = KCP / 32;
  constexpr int QX = 32 * C;
  __shared__ __align__(16) char dsm[2 * DBUF * 2];
  __shared__ __align__(16) unsigned short xinb[32 * PIT];
  int bid = blockIdx.x, tid = threadIdx.x;   // grid is exactly 512 blocks
  int w = tid >> 6, lane = tid & 63, col = lane & 15, quad = lane >> 4;
  int bcnt = 0;

  bf16x8 apre[16];
  {
    int n0p = ((bid & 255) >> 5) * 64;
    const bf16* ar = adjb + (size_t)(n0p + w * 16 + col) * NN;
#pragma unroll
    for (int c = 0; c < 8; c++)
#pragma unroll
      for (int ki = 0; ki < 2; ki++)
        apre[c * 2 + ki] = *(const bf16x8*)(ar + c * 64 + ki * 32 + quad * 8);
  }
  bf16x8 fg[2 * NK];
  {
    const bf16* Wn = gWt + (size_t)bid * KCP * 128;
#pragma unroll
    for (int i = 0; i < 2; i++) {
      int o = (w + i * 4) * 16 + col;
#pragma unroll
      for (int kk = 0; kk < NK; kk++)
        fg[i * NK + kk] = *(const bf16x8*)(Wn + (size_t)o * KCP + kk * 32 + quad * 8);
    }
  }
  bf16x8 fu[NK];
  {
    const bf16* Wn = uWt + (size_t)bid * KCP * 64;
    int o = w * 16 + col;
#pragma unroll
    for (int kk = 0; kk < NK; kk++)
      fu[kk] = *(const bf16x8*)(Wn + (size_t)o * KCP + kk * 32 + quad * 8);
  }
  float gbv0 = gb[bid * 128 + w * 16 + col];
  float gbv1 = gb[bid * 128 + 64 + w * 16 + col];
  float ubv  = ub[bid * 64 + w * 16 + col];

  for (int i = tid; i < 32 * PIT; i += 256) xinb[i] = 0;
  __syncthreads();

  int r2 = tid >> 3, ch = tid & 7;
  uint4 vxt; unsigned sxt = 0, sxd = 0;
  if constexpr (C == 64) {
    vxt = *(const uint4*)(xin + (size_t)(bid * 32 + r2) * 64 + ch * 8);
  } else {
    if (tid < 32) sxt = *(const unsigned*)(xin + (size_t)(bid * 32 + tid) * 2);
  }

  float st[2][4], rr_[2][4];
#pragma unroll
  for (int mt = 0; mt < 2; mt++)
#pragma unroll
    for (int r4 = 0; r4 < 4; r4++) st[mt][r4] = 0.f;

  // pre-loop diffusion (uses this block's apre rows)
  if constexpr (C == 2) {
    int wg = (bid & 31) | ((bid >> 8) << 5);
    if (wg < TT)
      diffuse_tileP<64>(apre, xin + (size_t)wg * NN * QX, xd + (size_t)wg * NN * QX,
                        QX, ((bid & 255) >> 5) * 64, 0, dsm, tid);
  } else {
    if (bid >= 256)
      diffuse_tileP<64>(apre, xin, xd, 2048, ((bid & 255) >> 5) * 64,
                        (bid & 31) * 64, dsm, tid);
  }
  gbar(bar, bcnt);

  for (int t = 0; t < TT; t++) {
    const bf16* xt = xin + (size_t)t * NN * QX;
    const bf16* xdt = (C == 2) ? (xd + (size_t)t * NN * QX) : xd;
    bf16* xo = xout + (size_t)t * NN * 32 * HHID;
    if (t > 0) {
      const bf16* sbp = xout + (size_t)(t - 1) * NN * 32 * HHID;
      if constexpr (C == 64) {
        if (bid < 256)
          diffuse_tileP<64>(apre, sbp, sdiff, 2048, (bid >> 5) * 64,
                            (bid & 31) * 64, dsm, tid);
        else
          diffuse_tileP<64>(apre, xt, xd, 2048, ((bid & 255) >> 5) * 64,
                            (bid & 31) * 64, dsm, tid);
      } else {
        int cs = (bid & 31) | ((bid >> 8) << 5);
        diffuse_tileP<32>(apre, sbp, sdiff, 2048, ((bid & 255) >> 5) * 64,
                          cs * 32, dsm, tid);
      }
      gbar(bar, bcnt);
    }
    // ---- P2 stage ----
    if constexpr (C == 64) {
      *(uint4*)&xinb[r2 * PIT + ch * 8] = vxt;
      uint4 v1 = llc_load4(xdt + (size_t)(bid * 32 + r2) * 64 + ch * 8);
      uint4 v2;
      if (t > 0) v2 = llc_load4(sdiff + (size_t)(bid * 32 + r2) * 64 + ch * 8);
      wait_vmcnt<0>();
      *(uint4*)&xinb[r2 * PIT + 128 + ch * 8] = v1;
      if (t > 0) *(uint4*)&xinb[r2 * PIT + 192 + ch * 8] = v2;
    } else {
      if (tid < 32) *(unsigned*)&xinb[tid * PIT] = sxt;
      if (t == 0) {
        if (tid < 32) {
          unsigned v = llc_load1(xdt + (size_t)(bid * 32 + tid) * 2);
          wait_vmcnt<0>();
          *(unsigned*)&xinb[tid * PIT + 66] = v;
        }
      } else {
        if (tid >= 32 && tid < 64) *(unsigned*)&xinb[(tid - 32) * PIT + 66] = sxd;
        int r2a = tid >> 4, c4 = tid & 15;
        uint2 va = llc_load2(sdiff + (size_t)(bid * 32 + r2a) * 64 + c4 * 4);
        uint2 vb = llc_load2(sdiff + (size_t)(bid * 32 + 16 + r2a) * 64 + c4 * 4);
        wait_vmcnt<0>();
        *(uint2*)&xinb[r2a * PIT + 68 + c4 * 4] = va;
        *(uint2*)&xinb[(16 + r2a) * PIT + 68 + c4 * 4] = vb;
      }
    }
    __syncthreads();
    // ---- P2 gate MFMA ----
    {
      f32x4 acc[2][2];
#pragma unroll
      for (int i = 0; i < 2; i++)
#pragma unroll
        for (int mt = 0; mt < 2; mt++) acc[i][mt] = (f32x4){0.f, 0.f, 0.f, 0.f};
#pragma unroll
      for (int kk = 0; kk < NK; kk++) {
        int ko = kk * 32 + quad * 8;
        bf16x8 a0 = *(const bf16x8*)&xinb[col * PIT + ko];
        bf16x8 a1 = *(const bf16x8*)&xinb[(16 + col) * PIT + ko];
#pragma unroll
        for (int i = 0; i < 2; i++) {
          acc[i][0] = __builtin_amdgcn_mfma_f32_16x16x32_bf16(a0, fg[i * NK + kk], acc[i][0], 0, 0, 0);
          acc[i][1] = __builtin_amdgcn_mfma_f32_16x16x32_bf16(a1, fg[i * NK + kk], acc[i][1], 0, 0, 0);
        }
      }
      __syncthreads();
#pragma unroll
      for (int mt = 0; mt < 2; mt++)
#pragma unroll
        for (int r4 = 0; r4 < 4; r4++) {
          int m = mt * 16 + quad * 4 + r4;
          float z = 1.0f / (1.0f + expf(-(acc[0][mt][r4] + gbv0)));
          float rv = 1.0f / (1.0f + expf(-(acc[1][mt][r4] + gbv1)));
          rr_[mt][r4] = rv;
          bf16 zb = __float2bfloat16(z * st[mt][r4]);
          xinb[m * PIT + C + w * 16 + col] = *(unsigned short*)&zb;
          llc_store_bf(zs + (size_t)(bid * 32 + m) * 64 + w * 16 + col,
                       *(unsigned short*)&zb);
        }
    }
    if (t > 0) {
      gbar(bar, bcnt);
      {
        int cs = (bid & 31) | ((bid >> 8) << 5);
        diffuse_tileP<32>(apre, zs, zsdiff, 2048, ((bid & 255) >> 5) * 64,
                          cs * 32, dsm, tid);
      }
      gbar(bar, bcnt);
      if constexpr (C == 64) {
        uint4 v = llc_load4(zsdiff + (size_t)(bid * 32 + r2) * 64 + ch * 8);
        wait_vmcnt<0>();
        *(uint4*)&xinb[r2 * PIT + 192 + ch * 8] = v;
      } else {
        int r2a = tid >> 4, c4 = tid & 15;
        uint2 va = llc_load2(zsdiff + (size_t)(bid * 32 + r2a) * 64 + c4 * 4);
        uint2 vb = llc_load2(zsdiff + (size_t)(bid * 32 + 16 + r2a) * 64 + c4 * 4);
        wait_vmcnt<0>();
        *(uint2*)&xinb[r2a * PIT + 68 + c4 * 4] = va;
        *(uint2*)&xinb[(16 + r2a) * PIT + 68 + c4 * 4] = vb;
      }
    }
    __syncthreads();
    // ---- P4 update MFMA ----
    {
      f32x4 acc[2];
      acc[0] = (f32x4){0.f, 0.f, 0.f, 0.f};
      acc[1] = (f32x4){0.f, 0.f, 0.f, 0.f};
#pragma unroll
      for (int kk = 0; kk < NK; kk++) {
        int ko = kk * 32 + quad * 8;
        bf16x8 a0 = *(const bf16x8*)&xinb[col * PIT + ko];
        bf16x8 a1 = *(const bf16x8*)&xinb[(16 + col) * PIT + ko];
        acc[0] = __builtin_amdgcn_mfma_f32_16x16x32_bf16(a0, fu[kk], acc[0], 0, 0, 0);
        acc[1] = __builtin_amdgcn_mfma_f32_16x16x32_bf16(a1, fu[kk], acc[1], 0, 0, 0);
      }
      __syncthreads();
      if (t + 1 < TT) {
        if constexpr (C == 64) {
          vxt = *(const uint4*)(xin + (size_t)(t + 1) * NN * QX +
                                (size_t)(bid * 32 + r2) * 64 + ch * 8);
        } else {
          if (tid < 32)
            sxt = *(const unsigned*)(xin + (size_t)(t + 1) * NN * QX +
                                     (size_t)(bid * 32 + tid) * 2);
          else if (tid < 64)
            sxd = *(const unsigned*)(xd + (size_t)(t + 1) * NN * QX +
                                     (size_t)(bid * 32 + (tid - 32)) * 2);
        }
      }
#pragma unroll
      for (int mt = 0; mt < 2; mt++)
#pragma unroll
        for (int r4 = 0; r4 < 4; r4++) {
          int m = mt * 16 + quad * 4 + r4;
          float hc = tanhf(acc[mt][r4] + ubv);
          float rv = rr_[mt][r4];
          float h = rv * st[mt][r4] + (1.0f - rv) * hc;
          st[mt][r4] = h;
          bf16 hb = __float2bfloat16(h);
          xinb[m * PIT + C + w * 16 + col] = *(unsigned short*)&hb;
          llc_store_bf(xo + (size_t)(bid * 32 + m) * 64 + w * 16 + col,
                       *(unsigned short*)&hb);
        }
    }
    gbar(bar, bcnt);
  }
}

// ---------------- fallback per-phase kernels (same math) ----------------

__global__ __launch_bounds__(256, 2) void diffuse0_kernel(const bf16* __restrict__ adjb,
                                                          const bf16* __restrict__ X,
                                                          bf16* __restrict__ Y) {
  __shared__ __align__(16) char smraw[2 * DBUF * 2];
  int bid = blockIdx.x, tid = threadIdx.x;  // 96
  int t = bid >> 3, n0 = (bid & 7) * 64;
  int w = tid >> 6, lane = tid & 63, col = lane & 15, quad = lane >> 4;
  bf16x8 ap[16];
  const bf16* ar = adjb + (size_t)(n0 + w * 16 + col) * NN;
#pragma unroll
  for (int c = 0; c < 8; c++)
#pragma unroll
    for (int ki = 0; ki < 2; ki++)
      ap[c * 2 + ki] = *(const bf16x8*)(ar + c * 64 + ki * 32 + quad * 8);
  diffuse_tileP<64>(ap, X + (size_t)t * NN * 64, Y + (size_t)t * NN * 64,
                    64, n0, 0, smraw, tid);
}

__global__ __launch_bounds__(256, 2) void diffuse1_kernel(const bf16* __restrict__ adjb,
                                                          const bf16* __restrict__ X,
                                                          bf16* __restrict__ Y) {
  __shared__ __align__(16) char smraw[2 * DBUF * 2];
  int bid = blockIdx.x, tid = threadIdx.x;  // 256
  int n0 = (bid >> 5) * 64;
  int w = tid >> 6, lane = tid & 63, col = lane & 15, quad = lane >> 4;
  bf16x8 ap[16];
  const bf16* ar = adjb + (size_t)(n0 + w * 16 + col) * NN;
#pragma unroll
  for (int c = 0; c < 8; c++)
#pragma unroll
    for (int ki = 0; ki < 2; ki++)
      ap[c * 2 + ki] = *(const bf16x8*)(ar + c * 64 + ki * 32 + quad * 8);
  diffuse_tileP<64>(ap, X, Y, 2048, n0, (bid & 31) * 64, smraw, tid);
}

template <int C>
__global__ __launch_bounds__(256, 2) void gate_wrap(
    const bf16* xt, const bf16* xdt, const bf16* sa, const bf16* sad,
    const bf16* gWt, const float* gb, const float* state, bf16* zs, bf16* rbuf) {
  constexpr int KC = 2 * (C + HHID), KCP = (KC + 31) & ~31, PIT = KCP + 8;
  __shared__ __align__(16) unsigned short xinb[32 * PIT];
  stage_A<C>(blockIdx.x, threadIdx.x, xinb, xt, xdt, sa, sad);
  gate_mfma<C>(blockIdx.x, threadIdx.x, xinb, gWt, gb, state, zs, rbuf);
}

template <int C>
__global__ __launch_bounds__(256, 2) void upd_wrap(
    const bf16* xt, const bf16* xdt, const bf16* sa, const bf16* sad,
    const bf16* uWt, const float* ub, float* state, bf16* sb,
    const bf16* rbuf, bf16* xo) {
  constexpr int KC = 2 * (C + HHID), KCP = (KC + 31) & ~31, PIT = KCP + 8;
  __shared__ __align__(16) unsigned short xinb[32 * PIT];
  stage_A<C>(blockIdx.x, threadIdx.x, xinb, xt, xdt, sa, sad);
  upd_mfma<C>(blockIdx.x, threadIdx.x, xinb, uWt, ub, state, sb, rbuf, xo);
}

// ---------------- epilogue kernels: MFMA attention + FFN -------------------

#define TP 68  // padded fp32 row stride (conflict-free)
#define WS 72  // padded bf16 weight-row stride (36 dwords, conflict-light)

__global__ __launch_bounds__(256, 4) void attn1_kernel(
    const bf16* __restrict__ x1, const float* __restrict__ fsb,
    const float* __restrict__ Wq, const float* __restrict__ bq,
    const float* __restrict__ Wk, const float* __restrict__ bk,
    const float* __restrict__ Wv, const float* __restrict__ bv,
    const float* __restrict__ ln1g, const float* __restrict__ ln1b,
    bf16* __restrict__ val) {
  __shared__ bf16 WqT[WS * 64], WkT[WS * 64];  // [h_out][h_in] padded
  __shared__ bf16 Wv_s[4096];                  // [h_in][h_out]
  __shared__ bf16 Xb[16 * 72];                 // [t][h] bf16, rows 12..15 zero
  __shared__ float qs[TT * TP], ks[TT * TP];
  __shared__ float A[2 * TT * TT];
  __shared__ float ovv[64], fss[TT];
  __shared__ float bqs[64], bks[64], bvs[64], g1s[64], b1s[64];
  int tid = threadIdx.x;
  int w = tid >> 6, lane = tid & 63, col = lane & 15, quad = lane >> 4;
#pragma unroll
  for (int i = 0; i < 16; i++) {
    int e = tid * 16 + i;
    int hi = e >> 6, ho = e & 63;
    WqT[ho * WS + hi] = __float2bfloat16(Wq[e]);
    WkT[ho * WS + hi] = __float2bfloat16(Wk[e]);
  }
  for (int i = tid; i < 4096; i += 256) Wv_s[i] = __float2bfloat16(Wv[i]);
  for (int i = tid; i < 16 * 72; i += 256) Xb[i] = __float2bfloat16(0.f);
  if (tid < 64) {
    bqs[tid] = bq[tid]; bks[tid] = bk[tid]; bvs[tid] = bv[tid];
    g1s[tid] = ln1g[tid]; b1s[tid] = ln1b[tid];
  }
  __syncthreads();
  for (int g = 0; g < 8; g++) {
    int p = blockIdx.x * 8 + g;
    int b = p >> 9, n = p & 511;
    for (int i = tid; i < TT * 64; i += 256) {
      int t = i >> 6, j = i & 63;
      Xb[t * 72 + j] = x1[(((size_t)t * NN + n) * BBATCH + b) * HHID + j];
    }
    if (tid < TT) fss[tid] = fsb[n * TT + tid];
    __syncthreads();
    // q/k projections via MFMA: [16x64] @ [64x64], wave w owns col-tile w
    {
      f32x4 aq = (f32x4){0.f, 0.f, 0.f, 0.f};
      f32x4 ak = (f32x4){0.f, 0.f, 0.f, 0.f};
#pragma unroll
      for (int ki = 0; ki < 2; ki++) {
        bf16x8 af = *(const bf16x8*)&Xb[col * 72 + ki * 32 + quad * 8];
        bf16x8 bqf = *(const bf16x8*)&WqT[(w * 16 + col) * WS + ki * 32 + quad * 8];
        bf16x8 bkf = *(const bf16x8*)&WkT[(w * 16 + col) * WS + ki * 32 + quad * 8];
        aq = __builtin_amdgcn_mfma_f32_16x16x32_bf16(af, bqf, aq, 0, 0, 0);
        ak = __builtin_amdgcn_mfma_f32_16x16x32_bf16(af, bkf, ak, 0, 0, 0);
      }
#pragma unroll
      for (int r = 0; r < 4; r++) {
        int t = quad * 4 + r;
        if (t < TT) {
          int h = w * 16 + col;
          qs[t * TP + h] = aq[r] + bqs[h];
          ks[t * TP + h] = ak[r] + bks[h];
        }
      }
    }
    if (tid < 64) {  // v projection: only last hidden row matters
      float s = 0.f;
#pragma unroll 8
      for (int j = 0; j < 64; j++)
        s += B2F(Xb[11 * 72 + j]) * B2F(Wv_s[j * 64 + tid]);
      ovv[tid] = s;
    }
    __syncthreads();
    for (int i = tid; i < 2 * TT * TT; i += 256) {
      int hd = i / (TT * TT), ts = i % (TT * TT), t = ts / TT, s = ts % TT;
      float acc = 0.f;
#pragma unroll
      for (int d = 0; d < 32; d++) acc += qs[t * TP + hd * 32 + d] * ks[s * TP + hd * 32 + d];
      A[i] = acc * 0.17677669529663687f;
    }
    __syncthreads();
    if (tid < 2 * TT) {
      int hd = tid / TT, t = tid % TT;
      float* row = &A[hd * TT * TT + t * TT];
      float m = row[0];
      for (int s = 1; s < TT; s++) m = fmaxf(m, row[s]);
      float sm = 0.f;
      for (int s = 0; s < TT; s++) { float e = expf(row[s] - m); row[s] = e; sm += e; }
      float inv = 1.0f / sm;
      for (int s = 0; s < TT; s++) row[s] *= inv;
    }
    __syncthreads();
#pragma unroll
    for (int it = 0; it < 3; it++) {
      int i = it * 256 + tid;
      int t = i >> 6, h = i & 63, hd = h >> 5;
      float afs = 0.f;
#pragma unroll
      for (int s = 0; s < TT; s++) afs += A[hd * TT * TT + t * TT + s] * fss[s];
      float o = ovv[h] * afs + bvs[h];
      float x = o + B2F(Xb[t * 72 + h]);
      float mu = wsum(x) * (1.0f / 64.0f);
      float d = x - mu;
      float var = wsum(d * d) * (1.0f / 64.0f);
      float v = d * rsqrtf(var + 1e-5f) * g1s[h] + b1s[h];
      val[((size_t)(b * TT + t) * NN + n) * HHID + h] = __float2bfloat16(v);
    }
    __syncthreads();
  }
}

__global__ __launch_bounds__(256, 4) void ffn_kernel(
    const bf16* __restrict__ val, const float* __restrict__ W1, const float* __restrict__ b1,
    const float* __restrict__ W2, const float* __restrict__ b2,
    const float* __restrict__ ln2g, const float* __restrict__ ln2b,
    const float* __restrict__ fcW, const float* __restrict__ fcb,
    float* __restrict__ out, int rows_per_block) {
  __shared__ bf16 W1T[WS * 64], W2T[WS * 64];  // [h_out][h_in] padded
  __shared__ bf16 Ab[16 * 72];
  __shared__ bf16 Hh[16 * 72], Hl[16 * 72];
  __shared__ float fout[16 * 68];
  __shared__ float b1s[64], b2s[64], g2s[64], bb2[64], fcs[64];
  int tid = threadIdx.x;
  int w = tid >> 6, lane = tid & 63, col = lane & 15, quad = lane >> 4;
#pragma unroll
  for (int i = 0; i < 16; i++) {
    int e = tid * 16 + i;
    int hi = e >> 6, ho = e & 63;
    W1T[ho * WS + hi] = __float2bfloat16(W1[e]);
    W2T[ho * WS + hi] = __float2bfloat16(W2[e]);
  }
  if (tid < 64) {
    b1s[tid] = b1[tid]; b2s[tid] = b2[tid];
    g2s[tid] = ln2g[tid]; bb2[tid] = ln2b[tid]; fcs[tid] = fcW[tid];
  }
  __syncthreads();
  float fcbv = fcb[0];
  for (int c0 = 0; c0 < rows_per_block; c0 += 16) {
    size_t r0 = (size_t)blockIdx.x * rows_per_block + c0;
    for (int i = tid; i < 1024; i += 256) {
      int rr = i >> 6, j = i & 63;
      Ab[rr * 72 + j] = val[(r0 + rr) * 64 + j];
    }
    __syncthreads();
    {
      f32x4 a1 = (f32x4){0.f, 0.f, 0.f, 0.f};
#pragma unroll
      for (int ki = 0; ki < 2; ki++) {
        bf16x8 af = *(const bf16x8*)&Ab[col * 72 + ki * 32 + quad * 8];
        bf16x8 bf1 = *(const bf16x8*)&W1T[(w * 16 + col) * WS + ki * 32 + quad * 8];
        a1 = __builtin_amdgcn_mfma_f32_16x16x32_bf16(af, bf1, a1, 0, 0, 0);
      }
#pragma unroll
      for (int r = 0; r < 4; r++) {
        int m = quad * 4 + r, h = w * 16 + col;
        float hv = fmaxf(a1[r] + b1s[h], 0.0f);
        bf16 hb = __float2bfloat16(hv);
        float lo = hv - B2F(hb);
        Hh[m * 72 + h] = hb;
        Hl[m * 72 + h] = __float2bfloat16(lo);
      }
    }
    __syncthreads();
    {
      f32x4 a2 = (f32x4){0.f, 0.f, 0.f, 0.f};
#pragma unroll
      for (int ki = 0; ki < 2; ki++) {
        bf16x8 ah = *(const bf16x8*)&Hh[col * 72 + ki * 32 + quad * 8];
        bf16x8 al = *(const bf16x8*)&Hl[col * 72 + ki * 32 + quad * 8];
        bf16x8 bf2 = *(const bf16x8*)&W2T[(w * 16 + col) * WS + ki * 32 + quad * 8];
        a2 = __builtin_amdgcn_mfma_f32_16x16x32_bf16(ah, bf2, a2, 0, 0, 0);
        a2 = __builtin_amdgcn_mfma_f32_16x16x32_bf16(al, bf2, a2, 0, 0, 0);
      }
#pragma unroll
      for (int r = 0; r < 4; r++) {
        int m = quad * 4 + r, h = w * 16 + col;
        fout[m * 68 + h] = a2[r] + b2s[h] + B2F(Ab[m * 72 + h]);
      }
    }
    __syncthreads();
#pragma unroll
    for (int p4 = 0; p4 < 4; p4++) {
      int m = p4 * 4 + w;
      float y = fout[m * 68 + lane];
      float mu = wsum(y) * (1.0f / 64.0f);
      float d = y - mu;
      float var = wsum(d * d) * (1.0f / 64.0f);
      float oh = d * rsqrtf(var + 1e-5f) * g2s[lane] + bb2[lane];
      float contrib = wsum(oh * fcs[lane]);
      if (lane == 0) out[r0 + m] = contrib + fcbv;
    }
    __syncthreads();
  }
}

extern "C" void kernel_launch(void* const* d_in, const int* in_sizes, int n_in,
                              void* d_out, int out_size, void* d_ws, size_t ws_size,
                              hipStream_t stream) {
  const float* src = (const float*)d_in[0];
  const float* emb = (const float*)d_in[2];
  const float* gwp[2] = {(const float*)d_in[3], (const float*)d_in[7]};
  const float* gbp[2] = {(const float*)d_in[4], (const float*)d_in[8]};
  const float* uwp[2] = {(const float*)d_in[5], (const float*)d_in[9]};
  const float* ubp[2] = {(const float*)d_in[6], (const float*)d_in[10]};
  const float* hypW = (const float*)d_in[11];
  const float* hypb = (const float*)d_in[12];
  const float *Wq, *Wk, *Wv, *ffW1, *ffW2, *bq, *bk, *bv, *ffb1, *ffb2;
  const float *ln1g, *ln1b, *ln2g, *ln2b, *fcW, *fcb;
  if (in_sizes[14] == 4096) {
    Wq = (const float*)d_in[13]; Wk = (const float*)d_in[14]; Wv = (const float*)d_in[15];
    ffW1 = (const float*)d_in[16]; ffW2 = (const float*)d_in[17];
    bq = (const float*)d_in[18]; bk = (const float*)d_in[19]; bv = (const float*)d_in[20];
    ffb1 = (const float*)d_in[21]; ffb2 = (const float*)d_in[22];
    ln1g = (const float*)d_in[23]; ln1b = (const float*)d_in[24];
    ln2g = (const float*)d_in[25]; ln2b = (const float*)d_in[26];
    fcW = (const float*)d_in[27]; fcb = (const float*)d_in[28];
  } else {
    Wq = (const float*)d_in[13]; bq = (const float*)d_in[14];
    Wk = (const float*)d_in[15]; bk = (const float*)d_in[16];
    Wv = (const float*)d_in[17]; bv = (const float*)d_in[18];
    ln1g = (const float*)d_in[19]; ln1b = (const float*)d_in[20];
    ffW1 = (const float*)d_in[21]; ffb1 = (const float*)d_in[22];
    ffW2 = (const float*)d_in[23]; ffb2 = (const float*)d_in[24];
    ln2g = (const float*)d_in[25]; ln2b = (const float*)d_in[26];
    fcW = (const float*)d_in[27]; fcb = (const float*)d_in[28];
  }
  float* outp = (float*)d_out;

  char* ws = (char*)d_ws;
  size_t off = 0;
  auto alloc = [&](size_t bytes) {
    void* p = ws + off;
    off += (bytes + 255) & ~(size_t)255;
    return p;
  };
  bf16* adjb = (bf16*)alloc((size_t)512 * 512 * 2);
  bf16* gWb = (bf16*)alloc((size_t)512 * 32768 * 2);
  bf16* uWb = (bf16*)alloc((size_t)512 * 16384 * 2);
  float* gb = (float*)alloc((size_t)512 * 128 * 4);
  float* ub = (float*)alloc((size_t)512 * 64 * 4);
  bf16* xin0 = (bf16*)alloc((size_t)12 * 512 * 32 * 2 * 2);
  bf16* x0 = (bf16*)alloc((size_t)12 * 512 * 32 * 64 * 2);
  bf16* xd0 = (bf16*)alloc((size_t)12 * 512 * 32 * 2 * 2);
  bf16* xdL1 = (bf16*)alloc((size_t)512 * 32 * 64 * 2);
  float* state = (float*)alloc((size_t)512 * 32 * 64 * 4);
  bf16* sb = (bf16*)alloc((size_t)512 * 32 * 64 * 2);
  bf16* sdiff = (bf16*)alloc((size_t)512 * 32 * 64 * 2);
  bf16* zs = (bf16*)alloc((size_t)512 * 32 * 64 * 2);
  bf16* zsdiff = (bf16*)alloc((size_t)512 * 32 * 64 * 2);
  bf16* rbuf = (bf16*)alloc((size_t)512 * 32 * 64 * 2);
  float* PW = (float*)alloc((size_t)16 * 48 * 4);
  float* fsb = (float*)alloc((size_t)512 * 12 * 4);
  unsigned* bar = (unsigned*)alloc((size_t)544 * 4);
  float* hypWT = (float*)alloc((size_t)48 * 16384 * 4);
  bf16* val = gWb;

  adj_kernel<<<512, 256, 0, stream>>>(emb, adjb);
  hypwT_kernel<<<512, 256, 0, stream>>>(hypW, hypWT);
  pw_kernel<<<dim3(48, 16), 256, 0, stream>>>(uwp[1], hypWT, PW);
  fs_kernel<<<24, 256, 0, stream>>>(emb, PW, hypb, fsb);
  cvt_src_kernel<<<1536, 256, 0, stream>>>(src, xin0);

  int occ0 = 0, occ1 = 0;
  hipOccupancyMaxActiveBlocksPerMultiprocessor(&occ0, recur_kernel<2>, 256, 0);
  hipOccupancyMaxActiveBlocksPerMultiprocessor(&occ1, recur_kernel<64>, 256, 0);

  for (int l = 0; l < 2; l++) {
    int C = (l == 0) ? 2 : 64;
    int KC = 2 * (C + 64);
    int KCP = (KC + 31) & ~31;  // 160 or 256
    int JG = KC * 128, JU = KC * 64;
    wgen_t_kernel<<<dim3(KCP * 128 / 256, 4), 256, 0, stream>>>(
        gwp[l], emb, gWb, JG, 128, KCP, KC);
    wgen_t_kernel<<<dim3(KCP * 64 / 256, 4), 256, 0, stream>>>(
        uwp[l], emb, uWb, JU, 64, KCP, KC);
    wgen_kernel<<<dim3(1, 4), 256, 0, stream>>>(gbp[l], emb, gb, 128);
    wgen_kernel<<<dim3(1, 4), 256, 0, stream>>>(ubp[l], emb, ub, 64);
    zero_f32_kernel<<<3, 256, 0, stream>>>((float*)bar, 544);

    const bf16* xin = (l == 0) ? xin0 : x0;
    bf16* xd = (l == 0) ? xd0 : xdL1;
    int occ = (l == 0) ? occ0 : occ1;
    if (occ >= 2) {
      if (l == 0)
        recur_kernel<2><<<512, 256, 0, stream>>>(adjb, xin, gWb, gb, uWb, ub,
                                                 zs, sdiff, zsdiff, xd, x0, bar);
      else
        recur_kernel<64><<<512, 256, 0, stream>>>(adjb, xin, gWb, gb, uWb, ub,
                                                  zs, sdiff, zsdiff, xd, x0, bar);
    } else {
      zero_f32_kernel<<<4096, 256, 0, stream>>>(state, 512 * 32 * 64);
      zero_f32_kernel<<<2048, 256, 0, stream>>>((float*)sb, 512 * 32 * 64 / 2);
      if (l == 0) diffuse0_kernel<<<96, 256, 0, stream>>>(adjb, xin, xd);
      for (int t = 0; t < 12; t++) {
        const bf16* xt = xin + (size_t)t * 512 * 32 * C;
        const bf16* xdt = (l == 0) ? (xd + (size_t)t * 512 * 32 * C) : xd;
        bf16* xo = x0 + (size_t)t * 512 * 32 * 64;
        if (l == 1) diffuse1_kernel<<<256, 256, 0, stream>>>(adjb, xt, xd);
        diffuse1_kernel<<<256, 256, 0, stream>>>(adjb, sb, sdiff);
        if (l == 0)
          gate_wrap<2><<<512, 256, 0, stream>>>(xt, xdt, sb, sdiff, gWb, gb, state, zs, rbuf);
        else
          gate_wrap<64><<<512, 256, 0, stream>>>(xt, xdt, sb, sdiff, gWb, gb, state, zs, rbuf);
        diffuse1_kernel<<<256, 256, 0, stream>>>(adjb, zs, zsdiff);
        if (l == 0)
          upd_wrap<2><<<512, 256, 0, stream>>>(xt, xdt, zs, zsdiff, uWb, ub, state, sb, rbuf, xo);
        else
          upd_wrap<64><<<512, 256, 0, stream>>>(xt, xdt, zs, zsdiff, uWb, ub, state, sb, rbuf, xo);
      }
    }
  }

  attn1_kernel<<<2048, 256, 0, stream>>>(x0, fsb, Wq, bq, Wk, bk, Wv, bv, ln1g, ln1b, val);
  ffn_kernel<<<2048, 256, 0, stream>>>(val, ffW1, ffb1, ffW2, ffb2, ln2g, ln2b, fcW, fcb,
                                       outp, 96);
}